// Round 1
// baseline (4687.527 us; speedup 1.0000x reference)
//
#include <hip/hip_runtime.h>

// Problem constants (fixed by the reference)
constexpr int Gn  = 5000;     // genes
constexpr int Bn  = 32;       // batch graphs
constexpr int Pn  = 5000;     // perts
constexpr int Nn  = Bn * Gn;  // 160000
constexpr int ECO = 1600000;
constexpr int EGG = 100000;

// ---- workspace layout (float offsets) ----
// stats region [0,2048): S1@0(128) S2@128 S3@256 S4@384(256) S5@640 SG@768 SP1@896 SP2@1024
constexpr int oS1 = 0, oS2 = 128, oS3 = 256, oS4 = 384, oS5 = 640, oSG = 768, oSP1 = 896, oSP2 = 1024;
constexpr int oA1 = 2048, oB1 = 2112, oA2 = 2176, oB2 = 2240;
constexpr int oA4 = 2304, oB4 = 2432;            // 128 each
constexpr int oA5 = 2560, oB5 = 2624;
constexpr int oAG = 2688, oBG = 2752;
constexpr int oAP1 = 2816, oBP1 = 2880, oAP2 = 2944, oBP2 = 3008;
constexpr int oAvec = 3072, oCvec = 3136, oCcP = 3200;
constexpr int oM  = 4096, oM1 = 8192, oM2 = 12288;
constexpr int oE2 = 16384, oEMB = 18432, oCGRAW = 20480, oCG2 = 22528;
constexpr int oRG  = 24576;
constexpr int oRP  = oRG  + Gn * 64;      // 344576
constexpr int oQ   = oRP  + Gn * 64;      // 664576
constexpr int oRGO = oQ   + Gn * 64;      // 984576
constexpr int oRBG = oRGO + Pn * 64;      // 1304576
constexpr int oAGO = oRBG + Pn * 64;      // 1624576
constexpr int oABG = oAGO + Pn * 64;      // 1944576
constexpr int oM1B = oABG + Pn * 64;      // m1 buffer 2264576
constexpr int oM2B = oM1B + Pn * 64;      // 2584576
constexpr int oDGO = oM2B + Pn * 64;      // 2904576
constexpr int oDBG = oDGO + Pn;           // 2909576
constexpr int oDEG = oDBG + Pn;           // 2914576
constexpr int oW1  = oDEG + Nn;           // 3074576
constexpr int oBUF0 = oW1 + Nn;           // 3234576
constexpr int oBUF1 = oBUF0 + Nn * 64;    // 13474576
constexpr size_t WS_FLOATS = (size_t)oBUF1 + (size_t)Nn * 64;  // 23714576 (~95 MB)

__global__ __launch_bounds__(256) void kzero(float* p, int n) {
  int i = blockIdx.x * 256 + threadIdx.x;
  if (i < n) p[i] = 0.f;
}

__global__ __launch_bounds__(256) void kfill(float* p, float v, int n) {
  int i = blockIdx.x * 256 + threadIdx.x;
  if (i < n) p[i] = v;
}

// row-wise L2 renorm (norm clipped to <=1); optional column stats of the output
__global__ __launch_bounds__(256) void krenorm(const float* __restrict__ in, float* __restrict__ out,
                                               float* __restrict__ stats, int rows) {
  int lane = threadIdx.x & 63, wv = threadIdx.x >> 6;
  int gw = blockIdx.x * 4 + wv, nw = gridDim.x * 4;
  float ps = 0.f, pq = 0.f;
  for (int r = gw; r < rows; r += nw) {
    float v = in[r * 64 + lane];
    float sq = v * v;
    for (int off = 32; off; off >>= 1) sq += __shfl_xor(sq, off, 64);
    float nn = sqrtf(sq);
    float s = fminf(1.f, 1.f / fmaxf(nn, 1e-12f));
    float o = v * s;
    out[r * 64 + lane] = o;
    ps += o; pq += o * o;
  }
  if (!stats) return;
  __shared__ float red[4][64], red2[4][64];
  red[wv][lane] = ps; red2[wv][lane] = pq;
  __syncthreads();
  if (wv == 0) {
    float s = red[0][lane] + red[1][lane] + red[2][lane] + red[3][lane];
    float q = red2[0][lane] + red2[1][lane] + red2[2][lane] + red2[3][lane];
    atomicAdd(&stats[lane], s);
    atomicAdd(&stats[64 + lane], q);
  }
}

// finalize BN: a = g*rsqrt(var+eps), b = bt - mean*a   (stats: sums[0:cols], sumsq[cols:2cols])
__global__ void kfin(const float* __restrict__ stats, const float* __restrict__ g,
                     const float* __restrict__ bt, float* __restrict__ a, float* __restrict__ b,
                     int cols, float invn) {
  int c = blockIdx.x * 64 + threadIdx.x;
  if (c >= cols) return;
  float mean = stats[c] * invn;
  float var = stats[cols + c] * invn - mean * mean;
  float sc = g[c] * rsqrtf(var + 1e-5f);
  a[c] = sc;
  b[c] = bt[c] - mean * sc;
}

// Mout = alpha * A @ Bm  (64x64 each); optional cvec = bias + beta * A @ (bv1+bv2)
__global__ __launch_bounds__(256) void ksmallmat(const float* __restrict__ A, const float* __restrict__ Bm,
                                                 float alpha, const float* __restrict__ bias,
                                                 const float* __restrict__ bv1, const float* __restrict__ bv2,
                                                 float beta, float* __restrict__ Mout, float* __restrict__ cvec) {
  __shared__ float As[4096], Bs[4096];
  int t = threadIdx.x;
  for (int m = 0; m < 16; m++) { As[m * 256 + t] = A[m * 256 + t]; Bs[m * 256 + t] = Bm[m * 256 + t]; }
  __syncthreads();
  int j = t & 63, ig = t >> 6;
  for (int ii = 0; ii < 16; ii++) {
    int i = ig * 16 + ii;
    float acc = 0.f;
    for (int k = 0; k < 64; k++) acc += As[i * 64 + k] * Bs[k * 64 + j];
    Mout[i * 64 + j] = alpha * acc;
  }
  if (cvec && t < 64) {
    float acc = bias ? bias[t] : 0.f;
    for (int k = 0; k < 64; k++) {
      float bb = (bv1 ? bv1[k] : 0.f) + (bv2 ? bv2[k] : 0.f);
      acc += beta * As[t * 64 + k] * bb;
    }
    cvec[t] = acc;
  }
}

__global__ __launch_bounds__(256) void kdegedge(const int* __restrict__ dst, const float* __restrict__ w,
                                                float* __restrict__ deg, int E) {
  int e = blockIdx.x * 256 + threadIdx.x;
  if (e < E) atomicAdd(&deg[dst[e]], w[e]);
}

__global__ __launch_bounds__(256) void kdinv(float* deg, int n) {
  int i = blockIdx.x * 256 + threadIdx.x;
  if (i < n) { float d = deg[i]; deg[i] = d > 0.f ? rsqrtf(d) : 0.f; }
}

// agg[i][c] = dinv[i]^2 * tab[(i % tabrows)*64 + c]   (self-loop term)
__global__ __launch_bounds__(256) void kagginit(float* __restrict__ agg, const float* __restrict__ dinv,
                                                const float* __restrict__ tab, int rows, int tabrows) {
  int idx = blockIdx.x * 256 + threadIdx.x;
  if (idx >= rows * 64) return;
  int i = idx >> 6, c = idx & 63;
  float dv = dinv[i];
  agg[idx] = dv * dv * tab[(i % tabrows) * 64 + c];
}

// edge scatter: 16 threads per edge, float4 each, 4 fp32 atomics
__global__ __launch_bounds__(256) void kaggedge(const int* __restrict__ src, const int* __restrict__ dst,
                                                const float* __restrict__ w, const float* __restrict__ dinv,
                                                const float* __restrict__ tab, float* __restrict__ agg,
                                                int E, int tabrows) {
  int t = blockIdx.x * 256 + threadIdx.x;
  int e = t >> 4, j = t & 15;
  if (e >= E) return;
  int s = src[e], d = dst[e];
  float coef = dinv[s] * w[e] * dinv[d];
  float4 v = ((const float4*)tab)[(s % tabrows) * 16 + j];
  int base = d * 64 + j * 4;
  atomicAdd(&agg[base + 0], coef * v.x);
  atomicAdd(&agg[base + 1], coef * v.y);
  atomicAdd(&agg[base + 2], coef * v.z);
  atomicAdd(&agg[base + 3], coef * v.w);
}

// Generic 64->64 row-tile GEMM: Y = [pre(X)]@W^T (+ second input pair) + bias (+ per-gene add); optional stats
template <bool TWO, bool PRE, bool PRELU, bool PERG, bool STATS>
__global__ __launch_bounds__(256) void gemm64k(
    const float* __restrict__ X, const float* __restrict__ Xb,
    const float* __restrict__ Wm, const float* __restrict__ Wb,
    const float* __restrict__ bias,
    const float* __restrict__ pa, const float* __restrict__ pb,
    const float* __restrict__ perg, int tabrows,
    float* __restrict__ Y, float* __restrict__ stats, int rows) {
  __shared__ float xs[4096];
  __shared__ float red[4][64], red2[4][64];
  int t = threadIdx.x, lane = t & 63, wv = t >> 6;
  int ntiles = (rows + 63) >> 6;
  float psum = 0.f, psq = 0.f;
  float bv = bias ? bias[lane] : 0.f;
  for (int tile = blockIdx.x; tile < ntiles; tile += gridDim.x) {
    int base = tile * 64;
    float acc[16];
#pragma unroll
    for (int j = 0; j < 16; j++) acc[j] = bv;
    for (int pass = 0; pass < (TWO ? 2 : 1); pass++) {
      const float* Xp = pass ? Xb : X;
      const float* Wp = pass ? Wb : Wm;
      __syncthreads();
#pragma unroll
      for (int m = 0; m < 16; m++) {
        int fl = m * 256 + t;
        int r = fl >> 6, c = fl & 63;
        int gr = base + r;
        float v = (gr < rows) ? Xp[gr * 64 + c] : 0.f;
        if (PRE) { v = pa[c] * v + pb[c]; if (PRELU) v = fmaxf(v, 0.f); }
        xs[fl] = v;
      }
      __syncthreads();
      float Wreg[64];
#pragma unroll
      for (int k = 0; k < 64; k++) Wreg[k] = Wp[lane * 64 + k];
#pragma unroll
      for (int j = 0; j < 16; j++) {
        int r = wv * 16 + j;
        const float4* xr = (const float4*)&xs[r * 64];
        float a = acc[j];
#pragma unroll
        for (int kk = 0; kk < 16; kk++) {
          float4 xv = xr[kk];
          a = fmaf(xv.x, Wreg[4 * kk + 0], a);
          a = fmaf(xv.y, Wreg[4 * kk + 1], a);
          a = fmaf(xv.z, Wreg[4 * kk + 2], a);
          a = fmaf(xv.w, Wreg[4 * kk + 3], a);
        }
        acc[j] = a;
      }
    }
#pragma unroll
    for (int j = 0; j < 16; j++) {
      int gr = base + wv * 16 + j;
      if (gr < rows) {
        float v = acc[j];
        if (PERG) v += perg[(gr % tabrows) * 64 + lane];
        Y[gr * 64 + lane] = v;
        if (STATS) { psum += v; psq += v * v; }
      }
    }
  }
  if (STATS) {
    __syncthreads();
    red[wv][lane] = psum; red2[wv][lane] = psq;
    __syncthreads();
    if (wv == 0) {
      float s = red[0][lane] + red[1][lane] + red[2][lane] + red[3][lane];
      float q = red2[0][lane] + red2[1][lane] + red2[2][lane] + red2[3][lane];
      atomicAdd(&stats[lane], s);
      atomicAdd(&stats[64 + lane], q);
    }
  }
}

// stats of u = a2*T2 + b2 + emb[row/G]  (no store)
__global__ __launch_bounds__(256) void k7_kernel(const float* __restrict__ T2, const float* __restrict__ a2,
                                                 const float* __restrict__ b2, const float* __restrict__ emb,
                                                 float* __restrict__ stats, int rows, int rowsPerB) {
  int lane = threadIdx.x & 63, wv = threadIdx.x >> 6;
  __shared__ float red[4][64], red2[4][64];
  float ps = 0.f, pq = 0.f;
  int total = rows * 64;
  int stride = gridDim.x * 256;
  for (int idx = blockIdx.x * 256 + threadIdx.x; idx < total; idx += stride) {
    int i = idx >> 6, c = idx & 63;
    int b = i / rowsPerB;
    float v = a2[c] * T2[idx] + b2[c] + emb[b * 64 + c];
    ps += v; pq += v * v;
  }
  red[wv][lane] = ps; red2[wv][lane] = pq;
  __syncthreads();
  if (wv == 0) {
    float s = red[0][lane] + red[1][lane] + red[2][lane] + red[3][lane];
    float q = red2[0][lane] + red2[1][lane] + red2[2][lane] + red2[3][lane];
    atomicAdd(&stats[lane], s);
    atomicAdd(&stats[64 + lane], q);
  }
}

// finalize S3 and build folded vectors: Avec = a3*a2, e2[b] = a3*(b2+emb[b]) + b3
__global__ __launch_bounds__(256) void kfinS3e2(const float* __restrict__ stats, const float* __restrict__ g,
                                                const float* __restrict__ bt, const float* __restrict__ a2,
                                                const float* __restrict__ b2, const float* __restrict__ emb,
                                                float* __restrict__ Avec, float* __restrict__ e2, float invn) {
  __shared__ float a3s[64], b3s[64];
  int t = threadIdx.x;
  if (t < 64) {
    float mean = stats[t] * invn;
    float var = stats[64 + t] * invn - mean * mean;
    float sc = g[t] * rsqrtf(var + 1e-5f);
    float sh = bt[t] - mean * sc;
    a3s[t] = sc; b3s[t] = sh;
    Avec[t] = sc * a2[t];
  }
  __syncthreads();
  for (int idx = t; idx < 2048; idx += 256) {
    int c = idx & 63;
    e2[idx] = a3s[c] * (b2[c] + emb[idx]) + b3s[c];
  }
}

// base2 = relu(Avec*T2 + e2[b]) stored; stats of r1 = base2@rec_W1^T + b1 (128 cols, two halves)
__global__ __launch_bounds__(256) void k9_kernel(const float* __restrict__ T2, const float* __restrict__ Avec,
                                                 const float* __restrict__ e2, const float* __restrict__ W1,
                                                 const float* __restrict__ b1, float* __restrict__ base2out,
                                                 float* __restrict__ stats, int rows, int rowsPerB) {
  __shared__ float xs[4096];
  __shared__ float red[4][64], red2[4][64];
  int t = threadIdx.x, lane = t & 63, wv = t >> 6;
  int ntiles = (rows + 63) >> 6;
  float psum[2] = {0.f, 0.f}, psq[2] = {0.f, 0.f};
  for (int tile = blockIdx.x; tile < ntiles; tile += gridDim.x) {
    int base = tile * 64;
    __syncthreads();
#pragma unroll
    for (int m = 0; m < 16; m++) {
      int fl = m * 256 + t;
      int r = fl >> 6, c = fl & 63;
      int gr = base + r;
      float v = 0.f;
      if (gr < rows) {
        int b = gr / rowsPerB;
        v = fmaxf(Avec[c] * T2[gr * 64 + c] + e2[b * 64 + c], 0.f);
        base2out[gr * 64 + c] = v;
      }
      xs[fl] = v;
    }
    __syncthreads();
    for (int h = 0; h < 2; h++) {
      int oc = h * 64 + lane;
      float Wreg[64];
#pragma unroll
      for (int k = 0; k < 64; k++) Wreg[k] = W1[oc * 64 + k];
      float bb = b1[oc];
#pragma unroll
      for (int j = 0; j < 16; j++) {
        int r = wv * 16 + j;
        int gr = base + r;
        const float4* xr = (const float4*)&xs[r * 64];
        float a = bb;
#pragma unroll
        for (int kk = 0; kk < 16; kk++) {
          float4 xv = xr[kk];
          a = fmaf(xv.x, Wreg[4 * kk + 0], a);
          a = fmaf(xv.y, Wreg[4 * kk + 1], a);
          a = fmaf(xv.z, Wreg[4 * kk + 2], a);
          a = fmaf(xv.w, Wreg[4 * kk + 3], a);
        }
        if (gr < rows) { psum[h] += a; psq[h] += a * a; }
      }
    }
  }
  for (int h = 0; h < 2; h++) {
    __syncthreads();
    red[wv][lane] = psum[h]; red2[wv][lane] = psq[h];
    __syncthreads();
    if (wv == 0) {
      float s = red[0][lane] + red[1][lane] + red[2][lane] + red[3][lane];
      float q = red2[0][lane] + red2[1][lane] + red2[2][lane] + red2[3][lane];
      atomicAdd(&stats[h * 64 + lane], s);
      atomicAdd(&stats[128 + h * 64 + lane], q);
    }
  }
}

// r2 = relu(a4*(base2@W1^T+b1)+b4) @ W2^T + b2v, with 128-dim split into two 64-halves via LDS transpose
__global__ __launch_bounds__(256) void k11_kernel(const float* __restrict__ B2, const float* __restrict__ W1,
                                                  const float* __restrict__ b1, const float* __restrict__ a4,
                                                  const float* __restrict__ b4, const float* __restrict__ W2,
                                                  const float* __restrict__ b2v, float* __restrict__ R2,
                                                  float* __restrict__ stats, int rows) {
  __shared__ float xs[4096];
  __shared__ float as[4096];
  __shared__ float red[4][64], red2[4][64];
  int t = threadIdx.x, lane = t & 63, wv = t >> 6;
  int ntiles = (rows + 63) >> 6;
  float psum = 0.f, psq = 0.f;
  float bb2 = b2v[lane];
  for (int tile = blockIdx.x; tile < ntiles; tile += gridDim.x) {
    int base = tile * 64;
    __syncthreads();
#pragma unroll
    for (int m = 0; m < 16; m++) {
      int fl = m * 256 + t;
      int r = fl >> 6, c = fl & 63;
      int gr = base + r;
      xs[fl] = (gr < rows) ? B2[gr * 64 + c] : 0.f;
    }
    float acc2[16];
#pragma unroll
    for (int j = 0; j < 16; j++) acc2[j] = bb2;
    for (int h = 0; h < 2; h++) {
      int oc = h * 64 + lane;
      float Wreg[64];
#pragma unroll
      for (int k = 0; k < 64; k++) Wreg[k] = W1[oc * 64 + k];
      float bb = b1[oc], aa4 = a4[oc], bb4 = b4[oc];
      __syncthreads();  // xs staged (h=0) / previous 'as' consumed (h=1)
#pragma unroll
      for (int j = 0; j < 16; j++) {
        int r = wv * 16 + j;
        const float4* xr = (const float4*)&xs[r * 64];
        float a = bb;
#pragma unroll
        for (int kk = 0; kk < 16; kk++) {
          float4 xv = xr[kk];
          a = fmaf(xv.x, Wreg[4 * kk + 0], a);
          a = fmaf(xv.y, Wreg[4 * kk + 1], a);
          a = fmaf(xv.z, Wreg[4 * kk + 2], a);
          a = fmaf(xv.w, Wreg[4 * kk + 3], a);
        }
        as[r * 64 + lane] = fmaxf(aa4 * a + bb4, 0.f);
      }
      __syncthreads();
#pragma unroll
      for (int k = 0; k < 64; k++) Wreg[k] = W2[lane * 128 + h * 64 + k];
#pragma unroll
      for (int j = 0; j < 16; j++) {
        int r = wv * 16 + j;
        const float4* ar = (const float4*)&as[r * 64];
        float a = acc2[j];
#pragma unroll
        for (int kk = 0; kk < 16; kk++) {
          float4 av = ar[kk];
          a = fmaf(av.x, Wreg[4 * kk + 0], a);
          a = fmaf(av.y, Wreg[4 * kk + 1], a);
          a = fmaf(av.z, Wreg[4 * kk + 2], a);
          a = fmaf(av.w, Wreg[4 * kk + 3], a);
        }
        acc2[j] = a;
      }
    }
#pragma unroll
    for (int j = 0; j < 16; j++) {
      int gr = base + wv * 16 + j;
      if (gr < rows) {
        float v = acc2[j];
        R2[gr * 64 + lane] = v;
        psum += v; psq += v * v;
      }
    }
  }
  __syncthreads();
  red[wv][lane] = psum; red2[wv][lane] = psq;
  __syncthreads();
  if (wv == 0) {
    float s = red[0][lane] + red[1][lane] + red[2][lane] + red[3][lane];
    float q = red2[0][lane] + red2[1][lane] + red2[2][lane] + red2[3][lane];
    atomicAdd(&stats[lane], s);
    atomicAdd(&stats[64 + lane], q);
  }
}

// w1[i] = dot(a5*R2[i]+b5, indv_w1[i%G]) + indv_b1[i%G]; 16 lanes per row, float4 each
__global__ __launch_bounds__(256) void k13_kernel(const float* __restrict__ R2, const float* __restrict__ a5,
                                                  const float* __restrict__ b5, const float* __restrict__ iw1,
                                                  const float* __restrict__ ib1, float* __restrict__ w1out,
                                                  int rows, int tabrows) {
  int t = blockIdx.x * 256 + threadIdx.x;
  int i = t >> 4, j = t & 15;
  if (i >= rows) return;
  int g = i % tabrows;
  float4 r = ((const float4*)R2)[i * 16 + j];
  float4 a = ((const float4*)a5)[j];
  float4 b = ((const float4*)b5)[j];
  float4 w = ((const float4*)iw1)[g * 16 + j];
  float p = (a.x * r.x + b.x) * w.x + (a.y * r.y + b.y) * w.y +
            (a.z * r.z + b.z) * w.z + (a.w * r.w + b.w) * w.w;
  for (int off = 8; off; off >>= 1) p += __shfl_xor(p, off, 64);
  if (j == 0) w1out[i] = p + ib1[g];
}

// cgraw[b][col] = sum_g w1[b][g]*cgW1[col][g] + cgb1[col]; one block per b, wave per column
__global__ __launch_bounds__(256) void kcg1(const float* __restrict__ w1, const float* __restrict__ cgW1,
                                            const float* __restrict__ cgb1, float* __restrict__ cgraw) {
  __shared__ float ws[Gn];
  int b = blockIdx.x, t = threadIdx.x, lane = t & 63, wv = t >> 6;
  for (int g = t; g < Gn; g += 256) ws[g] = w1[b * Gn + g];
  __syncthreads();
  for (int col = wv; col < 64; col += 4) {
    float p = 0.f;
    for (int g = lane; g < Gn; g += 64) p += ws[g] * cgW1[col * Gn + g];
    for (int off = 32; off; off >>= 1) p += __shfl_xor(p, off, 64);
    if (lane == 0) cgraw[b * 64 + col] = p + cgb1[col];
  }
}

// single-block: cg2 = bn2(relu(bn1(cgraw)) @ W2^T + b2)   (BN over 32 rows)
__global__ __launch_bounds__(256) void kcg2(const float* __restrict__ cgraw, const float* __restrict__ g1,
                                            const float* __restrict__ bt1, const float* __restrict__ W2,
                                            const float* __restrict__ b2, const float* __restrict__ g2,
                                            const float* __restrict__ bt2, float* __restrict__ cg2out) {
  int t = threadIdx.x, c = t & 63, bg = t >> 6;
  __shared__ float hmid[2048], sred[4][64], qred[4][64], asc[64], bsh[64];
  float y[8];
  float ps = 0.f, pq = 0.f;
  for (int jb = 0; jb < 8; jb++) {
    int b = bg * 8 + jb;
    float v = cgraw[b * 64 + c];
    y[jb] = v; ps += v; pq += v * v;
  }
  sred[bg][c] = ps; qred[bg][c] = pq;
  __syncthreads();
  if (t < 64) {
    float s = sred[0][t] + sred[1][t] + sred[2][t] + sred[3][t];
    float q = qred[0][t] + qred[1][t] + qred[2][t] + qred[3][t];
    float mean = s * (1.f / 32.f), var = q * (1.f / 32.f) - mean * mean;
    float sc = g1[t] * rsqrtf(var + 1e-5f);
    asc[t] = sc; bsh[t] = bt1[t] - mean * sc;
  }
  __syncthreads();
  for (int jb = 0; jb < 8; jb++) { int b = bg * 8 + jb; hmid[b * 64 + c] = fmaxf(asc[c] * y[jb] + bsh[c], 0.f); }
  __syncthreads();
  ps = 0.f; pq = 0.f;
  for (int jb = 0; jb < 8; jb++) {
    int b = bg * 8 + jb;
    float a = b2[c];
    for (int k = 0; k < 64; k++) a += hmid[b * 64 + k] * W2[c * 64 + k];
    y[jb] = a; ps += a; pq += a * a;
  }
  sred[bg][c] = ps; qred[bg][c] = pq;
  __syncthreads();
  if (t < 64) {
    float s = sred[0][t] + sred[1][t] + sred[2][t] + sred[3][t];
    float q = qred[0][t] + qred[1][t] + qred[2][t] + qred[3][t];
    float mean = s * (1.f / 32.f), var = q * (1.f / 32.f) - mean * mean;
    float sc = g2[t] * rsqrtf(var + 1e-5f);
    asc[t] = sc; bsh[t] = bt2[t] - mean * sc;
  }
  __syncthreads();
  for (int jb = 0; jb < 8; jb++) { int b = bg * 8 + jb; cg2out[b * 64 + c] = asc[c] * y[jb] + bsh[c]; }
}

// single-block: emb = mlp3(pglob[pert_idx]) with BN over 32 rows
__global__ __launch_bounds__(256) void kemb(const float* __restrict__ m2, const float* __restrict__ aP2,
                                            const float* __restrict__ bP2, const int* __restrict__ pidx,
                                            const float* __restrict__ Wm, const float* __restrict__ bv,
                                            const float* __restrict__ gg, const float* __restrict__ btv,
                                            float* __restrict__ emb) {
  int t = threadIdx.x, c = t & 63, bg = t >> 6;
  __shared__ float xin[2048], hmid[2048], sred[4][64], qred[4][64], asc[64], bsh[64];
  for (int idx = t; idx < 2048; idx += 256) {
    int b = idx >> 6, cc = idx & 63;
    xin[idx] = aP2[cc] * m2[pidx[b] * 64 + cc] + bP2[cc];
  }
  __syncthreads();
  float y[8];
  float ps = 0.f, pq = 0.f;
  for (int jb = 0; jb < 8; jb++) {
    int b = bg * 8 + jb;
    float a = bv[c];
    for (int k = 0; k < 64; k++) a += xin[b * 64 + k] * Wm[c * 64 + k];
    y[jb] = a; ps += a; pq += a * a;
  }
  sred[bg][c] = ps; qred[bg][c] = pq;
  __syncthreads();
  if (t < 64) {
    float s = sred[0][t] + sred[1][t] + sred[2][t] + sred[3][t];
    float q = qred[0][t] + qred[1][t] + qred[2][t] + qred[3][t];
    float mean = s * (1.f / 32.f), var = q * (1.f / 32.f) - mean * mean;
    float sc = gg[t] * rsqrtf(var + 1e-5f);
    asc[t] = sc; bsh[t] = btv[t] - mean * sc;
  }
  __syncthreads();
  for (int jb = 0; jb < 8; jb++) { int b = bg * 8 + jb; hmid[b * 64 + c] = fmaxf(asc[c] * y[jb] + bsh[c], 0.f); }
  __syncthreads();
  ps = 0.f; pq = 0.f;
  for (int jb = 0; jb < 8; jb++) {
    int b = bg * 8 + jb;
    float a = bv[64 + c];
    for (int k = 0; k < 64; k++) a += hmid[b * 64 + k] * Wm[4096 + c * 64 + k];
    y[jb] = a; ps += a; pq += a * a;
  }
  sred[bg][c] = ps; qred[bg][c] = pq;
  __syncthreads();
  if (t < 64) {
    float s = sred[0][t] + sred[1][t] + sred[2][t] + sred[3][t];
    float q = qred[0][t] + qred[1][t] + qred[2][t] + qred[3][t];
    float mean = s * (1.f / 32.f), var = q * (1.f / 32.f) - mean * mean;
    float sc = gg[64 + t] * rsqrtf(var + 1e-5f);
    asc[t] = sc; bsh[t] = btv[64 + t] - mean * sc;
  }
  __syncthreads();
  for (int jb = 0; jb < 8; jb++) { int b = bg * 8 + jb; emb[b * 64 + c] = asc[c] * y[jb] + bsh[c]; }
}

// final: out[b][g] = w1*iw2[g][0] + dot(cg2[b], iw2[g][1:65]) + ib2[g] + x[b][g]; 64 genes per block
__global__ __launch_bounds__(256) void kfinal(const float* __restrict__ w1, const float* __restrict__ cg2,
                                              const float* __restrict__ iw2, const float* __restrict__ ib2,
                                              const float* __restrict__ x, float* __restrict__ out) {
  __shared__ float iws[64 * 65], cgs[2048];
  int t = threadIdx.x;
  int g0 = blockIdx.x * 64;
  for (int idx = t; idx < 64 * 65; idx += 256) {
    int gi = g0 * 65 + idx;
    iws[idx] = (gi < Gn * 65) ? iw2[gi] : 0.f;
  }
  for (int idx = t; idx < 2048; idx += 256) cgs[idx] = cg2[idx];
  __syncthreads();
  int gl = t & 63, bg = t >> 6;
  int g = g0 + gl;
  if (g >= Gn) return;
  float bias = ib2[g];
  for (int jb = 0; jb < 8; jb++) {
    int b = bg * 8 + jb;
    float acc = w1[b * Gn + g] * iws[gl * 65] + bias;
    for (int k = 0; k < 64; k++) acc += cgs[b * 64 + k] * iws[gl * 65 + 1 + k];
    out[b * Gn + g] = acc + x[b * Gn + g];
  }
}

extern "C" void kernel_launch(void* const* d_in, const int* in_sizes, int n_in,
                              void* d_out, int out_size, void* d_ws, size_t ws_size,
                              hipStream_t stream) {
  (void)in_sizes; (void)n_in; (void)out_size;
  if (ws_size < WS_FLOATS * sizeof(float)) return;  // workspace too small; bail

  const float* x        = (const float*)d_in[0];
  const int*   pert_idx = (const int*)d_in[1];
  const int*   ei_co    = (const int*)d_in[2];
  const float* w_co     = (const float*)d_in[3];
  const int*   ei_go    = (const int*)d_in[4];
  const float* w_go     = (const float*)d_in[5];
  const int*   ei_bg    = (const int*)d_in[6];
  const float* w_bg     = (const float*)d_in[7];
  const float* gene_tab = (const float*)d_in[8];
  const float* pos_tab  = (const float*)d_in[9];
  const float* go_tab   = (const float*)d_in[10];
  const float* bg_tab   = (const float*)d_in[11];
  const float* bn_g     = (const float*)d_in[12];
  const float* bn_b     = (const float*)d_in[13];
  const float* sg_W     = (const float*)d_in[14];
  const float* sg_b     = (const float*)d_in[15];
  const float* mlp_W    = (const float*)d_in[16];
  const float* mlp_b    = (const float*)d_in[17];
  const float* mlp_g    = (const float*)d_in[18];
  const float* mlp_bt   = (const float*)d_in[19];
  const float* rec_W1   = (const float*)d_in[20];
  const float* rec_b1   = (const float*)d_in[21];
  const float* rec_g1   = (const float*)d_in[22];
  const float* rec_bt1  = (const float*)d_in[23];
  const float* rec_W2   = (const float*)d_in[24];
  const float* rec_b2   = (const float*)d_in[25];
  const float* rec_g2   = (const float*)d_in[26];
  const float* rec_bt2  = (const float*)d_in[27];
  const float* indv_w1  = (const float*)d_in[28];
  const float* indv_b1  = (const float*)d_in[29];
  const float* cg_W1    = (const float*)d_in[30];
  const float* cg_b1    = (const float*)d_in[31];
  const float* cg_g1    = (const float*)d_in[32];
  const float* cg_bt1   = (const float*)d_in[33];
  const float* cg_W2    = (const float*)d_in[34];
  const float* cg_b2    = (const float*)d_in[35];
  const float* cg_g2    = (const float*)d_in[36];
  const float* cg_bt2   = (const float*)d_in[37];
  const float* indv_w2  = (const float*)d_in[38];
  const float* indv_b2  = (const float*)d_in[39];

  float* W = (float*)d_ws;
  float* buf0 = W + oBUF0;
  float* buf1 = W + oBUF1;

  // --- phase 0: zero stats, renorm tables, fold small matrices ---
  kzero<<<8, 256, 0, stream>>>(W, 2048);
  krenorm<<<160, 256, 0, stream>>>(gene_tab, W + oRG, W + oSG, Gn);
  krenorm<<<160, 256, 0, stream>>>(pos_tab, W + oRP, nullptr, Gn);
  krenorm<<<160, 256, 0, stream>>>(go_tab, W + oRGO, nullptr, Pn);
  krenorm<<<160, 256, 0, stream>>>(bg_tab, W + oRBG, nullptr, Pn);
  kfin<<<1, 64, 0, stream>>>(W + oSG, bn_g, bn_b, W + oAG, W + oBG, 64, 1.f / Gn);
  // M = 0.2*W10@sgW0; cvec = b10 + 0.2*W10@sgb0
  ksmallmat<<<1, 256, 0, stream>>>(mlp_W + 8192, sg_W, 0.2f, mlp_b + 128, sg_b, nullptr, 0.2f, W + oM, W + oCvec);
  // M1 = W00@sgW1
  ksmallmat<<<1, 256, 0, stream>>>(mlp_W, sg_W + 4096, 1.f, nullptr, nullptr, nullptr, 0.f, W + oM1, nullptr);
  // M2 = W00@sgW2; ccP = b00 + W00@(sgb1+sgb2)
  ksmallmat<<<1, 256, 0, stream>>>(mlp_W, sg_W + 8192, 1.f, mlp_b, sg_b + 64, sg_b + 128, 1.f, W + oM2, W + oCcP);
  // Q = relu(aG*rg+bG) @ W10^T + cvec
  gemm64k<false, true, true, false, false><<<79, 256, 0, stream>>>(
      W + oRG, nullptr, mlp_W + 8192, nullptr, W + oCvec, W + oAG, W + oBG, nullptr, 0, W + oQ, nullptr, Gn);

  // --- co graph sgconv (N nodes) ---
  kfill<<<(Nn + 255) / 256, 256, 0, stream>>>(W + oDEG, 1.f, Nn);
  kdegedge<<<(ECO + 255) / 256, 256, 0, stream>>>(ei_co + ECO, w_co, W + oDEG, ECO);
  kdinv<<<(Nn + 255) / 256, 256, 0, stream>>>(W + oDEG, Nn);
  kagginit<<<(Nn * 64 + 255) / 256, 256, 0, stream>>>(buf0, W + oDEG, W + oRP, Nn, Gn);
  kaggedge<<<(ECO * 16 + 255) / 256, 256, 0, stream>>>(ei_co, ei_co + ECO, w_co, W + oDEG, W + oRP, buf0, ECO, Gn);

  // --- pert graphs (P nodes) ---
  kfill<<<(Pn + 255) / 256, 256, 0, stream>>>(W + oDGO, 1.f, Pn);
  kdegedge<<<(EGG + 255) / 256, 256, 0, stream>>>(ei_go + EGG, w_go, W + oDGO, EGG);
  kdinv<<<(Pn + 255) / 256, 256, 0, stream>>>(W + oDGO, Pn);
  kagginit<<<(Pn * 64 + 255) / 256, 256, 0, stream>>>(W + oAGO, W + oDGO, W + oRGO, Pn, Pn);
  kaggedge<<<(EGG * 16 + 255) / 256, 256, 0, stream>>>(ei_go, ei_go + EGG, w_go, W + oDGO, W + oRGO, W + oAGO, EGG, Pn);

  kfill<<<(Pn + 255) / 256, 256, 0, stream>>>(W + oDBG, 1.f, Pn);
  kdegedge<<<(EGG + 255) / 256, 256, 0, stream>>>(ei_bg + EGG, w_bg, W + oDBG, EGG);
  kdinv<<<(Pn + 255) / 256, 256, 0, stream>>>(W + oDBG, Pn);
  kagginit<<<(Pn * 64 + 255) / 256, 256, 0, stream>>>(W + oABG, W + oDBG, W + oRBG, Pn, Pn);
  kaggedge<<<(EGG * 16 + 255) / 256, 256, 0, stream>>>(ei_bg, ei_bg + EGG, w_bg, W + oDBG, W + oRBG, W + oABG, EGG, Pn);

  // m1 = agg_go@M1^T + agg_bg@M2^T + ccP ; stats SP1
  gemm64k<true, false, false, false, true><<<79, 256, 0, stream>>>(
      W + oAGO, W + oABG, W + oM1, W + oM2, W + oCcP, nullptr, nullptr, nullptr, 0, W + oM1B, W + oSP1, Pn);
  kfin<<<1, 64, 0, stream>>>(W + oSP1, mlp_g, mlp_bt, W + oAP1, W + oBP1, 64, 1.f / Pn);
  // m2 = relu(aP1*m1+bP1)@W01^T + b01 ; stats SP2
  gemm64k<false, true, true, false, true><<<79, 256, 0, stream>>>(
      W + oM1B, nullptr, mlp_W + 4096, nullptr, mlp_b + 64, W + oAP1, W + oBP1, nullptr, 0, W + oM2B, W + oSP2, Pn);
  kfin<<<1, 64, 0, stream>>>(W + oSP2, mlp_g + 64, mlp_bt + 64, W + oAP2, W + oBP2, 64, 1.f / Pn);
  // emb_total
  kemb<<<1, 256, 0, stream>>>(W + oM2B, W + oAP2, W + oBP2, pert_idx,
                              mlp_W + 16384, mlp_b + 256, mlp_g + 256, mlp_bt + 256, W + oEMB);

  // --- main N pipeline ---
  // t1 = agg@M^T + Q[g] ; stats S1
  gemm64k<false, false, false, true, true><<<512, 256, 0, stream>>>(
      buf0, nullptr, W + oM, nullptr, nullptr, nullptr, nullptr, W + oQ, Gn, buf1, W + oS1, Nn);
  kfin<<<1, 64, 0, stream>>>(W + oS1, mlp_g + 128, mlp_bt + 128, W + oA1, W + oB1, 64, 1.f / Nn);
  // t2 = relu(a1*t1+b1)@W11^T + b11 ; stats S2
  gemm64k<false, true, true, false, true><<<512, 256, 0, stream>>>(
      buf1, nullptr, mlp_W + 12288, nullptr, mlp_b + 192, W + oA1, W + oB1, nullptr, 0, buf0, W + oS2, Nn);
  kfin<<<1, 64, 0, stream>>>(W + oS2, mlp_g + 192, mlp_bt + 192, W + oA2, W + oB2, 64, 1.f / Nn);
  // stats of u = a2*t2+b2+emb[b]
  k7_kernel<<<512, 256, 0, stream>>>(buf0, W + oA2, W + oB2, W + oEMB, W + oS3, Nn, Gn);
  kfinS3e2<<<1, 256, 0, stream>>>(W + oS3, bn_g + 64, bn_b + 64, W + oA2, W + oB2, W + oEMB,
                                  W + oAvec, W + oE2, 1.f / Nn);
  // base2 stored + r1 stats (128)
  k9_kernel<<<512, 256, 0, stream>>>(buf0, W + oAvec, W + oE2, rec_W1, rec_b1, buf1, W + oS4, Nn, Gn);
  kfin<<<2, 64, 0, stream>>>(W + oS4, rec_g1, rec_bt1, W + oA4, W + oB4, 128, 1.f / Nn);
  // r2 + stats S5
  k11_kernel<<<512, 256, 0, stream>>>(buf1, rec_W1, rec_b1, W + oA4, W + oB4, rec_W2, rec_b2, buf0, W + oS5, Nn);
  kfin<<<1, 64, 0, stream>>>(W + oS5, rec_g2, rec_bt2, W + oA5, W + oB5, 64, 1.f / Nn);
  // w1
  k13_kernel<<<(Nn * 16 + 255) / 256, 256, 0, stream>>>(buf0, W + oA5, W + oB5, indv_w1, indv_b1, W + oW1, Nn, Gn);
  // cross-gene state
  kcg1<<<32, 256, 0, stream>>>(W + oW1, cg_W1, cg_b1, W + oCGRAW);
  kcg2<<<1, 256, 0, stream>>>(W + oCGRAW, cg_g1, cg_bt1, cg_W2, cg_b2, cg_g2, cg_bt2, W + oCG2);
  // final
  kfinal<<<(Gn + 63) / 64, 256, 0, stream>>>(W + oW1, W + oCG2, indv_w2, indv_b2, x, (float*)d_out);
}

// Round 2
// 1641.833 us; speedup vs baseline: 2.8551x; 2.8551x over previous
//
#include <hip/hip_runtime.h>

typedef unsigned int u32;
typedef unsigned short u16;

// Problem constants (fixed by the reference)
constexpr int Gn  = 5000;     // genes
constexpr int Bn  = 32;       // batch graphs
constexpr int Pn  = 5000;     // perts
constexpr int Nn  = Bn * Gn;  // 160000
constexpr int ECO = 1600000;
constexpr int EGG = 100000;
constexpr int NTILES = Nn / 128;  // 1250, exact

// ---- workspace layout (float offsets) ----
constexpr int oS1 = 0, oS2 = 128, oS3 = 256, oS4 = 384, oS5 = 640, oSG = 768, oSP1 = 896, oSP2 = 1024;
constexpr int oZERO = 1536;  // stays zero (bias for t1)
constexpr int oA1 = 2048, oB1 = 2112, oA2 = 2176, oB2 = 2240;
constexpr int oA4 = 2304, oB4 = 2432;            // 128 each
constexpr int oA5 = 2560, oB5 = 2624;
constexpr int oAG = 2688, oBG = 2752;
constexpr int oAP1 = 2816, oBP1 = 2880, oAP2 = 2944, oBP2 = 3008;
constexpr int oAvec = 3072, oCvec = 3136, oCcP = 3200;
constexpr int oM  = 4096, oM1 = 8192, oM2 = 12288;
constexpr int oE2 = 16384, oEMB = 18432, oCGRAW = 20480, oCG2 = 22528;
constexpr int oRG  = 24576;
constexpr int oRP  = oRG  + Gn * 64;
constexpr int oQ   = oRP  + Gn * 64;
constexpr int oRGO = oQ   + Gn * 64;
constexpr int oRBG = oRGO + Pn * 64;
constexpr int oAGO = oRBG + Pn * 64;
constexpr int oABG = oAGO + Pn * 64;
constexpr int oM1B = oABG + Pn * 64;
constexpr int oM2B = oM1B + Pn * 64;
constexpr int oDGO = oM2B + Pn * 64;
constexpr int oDBG = oDGO + Pn;
constexpr int oDEG = oDBG + Pn;
constexpr int oW1  = oDEG + Nn;
constexpr int oBUF0 = oW1 + Nn;
constexpr int oBUF1 = oBUF0 + Nn * 64;
constexpr size_t WS_FLOATS = (size_t)oBUF1 + (size_t)Nn * 64;  // ~95 MB (proven available in R1)

__device__ inline u16 f2bf(float f) {
  u32 u = __float_as_uint(f);
  u = (u + 0x7fffu + ((u >> 16) & 1u)) >> 16;
  return (u16)u;
}
__device__ inline float bflo(u32 v) { return __uint_as_float(v << 16); }
__device__ inline float bfhi(u32 v) { return __uint_as_float(v & 0xffff0000u); }

#define XC(v, kk) ((kk) == 0 ? (v).x : (kk) == 1 ? (v).y : (kk) == 2 ? (v).z : (v).w)

__global__ __launch_bounds__(256) void kzero(float* p, int n) {
  int i = blockIdx.x * 256 + threadIdx.x;
  if (i < n) p[i] = 0.f;
}

__global__ __launch_bounds__(256) void kfill(float* p, float v, int n) {
  int i = blockIdx.x * 256 + threadIdx.x;
  if (i < n) p[i] = v;
}

// row-wise L2 renorm (norm clipped to <=1); optional column stats of the output
__global__ __launch_bounds__(256) void krenorm(const float* __restrict__ in, float* __restrict__ out,
                                               float* __restrict__ stats, int rows) {
  int lane = threadIdx.x & 63, wv = threadIdx.x >> 6;
  int gw = blockIdx.x * 4 + wv, nw = gridDim.x * 4;
  float ps = 0.f, pq = 0.f;
  for (int r = gw; r < rows; r += nw) {
    float v = in[r * 64 + lane];
    float sq = v * v;
    for (int off = 32; off; off >>= 1) sq += __shfl_xor(sq, off, 64);
    float nn = sqrtf(sq);
    float s = fminf(1.f, 1.f / fmaxf(nn, 1e-12f));
    float o = v * s;
    out[r * 64 + lane] = o;
    ps += o; pq += o * o;
  }
  if (!stats) return;
  __shared__ float red[4][64], red2[4][64];
  red[wv][lane] = ps; red2[wv][lane] = pq;
  __syncthreads();
  if (wv == 0) {
    float s = red[0][lane] + red[1][lane] + red[2][lane] + red[3][lane];
    float q = red2[0][lane] + red2[1][lane] + red2[2][lane] + red2[3][lane];
    atomicAdd(&stats[lane], s);
    atomicAdd(&stats[64 + lane], q);
  }
}

// finalize BN: a = g*rsqrt(var+eps), b = bt - mean*a
__global__ void kfin(const float* __restrict__ stats, const float* __restrict__ g,
                     const float* __restrict__ bt, float* __restrict__ a, float* __restrict__ b,
                     int cols, float invn) {
  int c = blockIdx.x * 64 + threadIdx.x;
  if (c >= cols) return;
  float mean = stats[c] * invn;
  float var = stats[cols + c] * invn - mean * mean;
  float sc = g[c] * rsqrtf(var + 1e-5f);
  a[c] = sc;
  b[c] = bt[c] - mean * sc;
}

// Mout = alpha * A @ Bm  (64x64 each); optional cvec = bias + beta * A @ (bv1+bv2)
__global__ __launch_bounds__(256) void ksmallmat(const float* __restrict__ A, const float* __restrict__ Bm,
                                                 float alpha, const float* __restrict__ bias,
                                                 const float* __restrict__ bv1, const float* __restrict__ bv2,
                                                 float beta, float* __restrict__ Mout, float* __restrict__ cvec) {
  __shared__ float As[4096], Bs[4096];
  int t = threadIdx.x;
  for (int m = 0; m < 16; m++) { As[m * 256 + t] = A[m * 256 + t]; Bs[m * 256 + t] = Bm[m * 256 + t]; }
  __syncthreads();
  int j = t & 63, ig = t >> 6;
  for (int ii = 0; ii < 16; ii++) {
    int i = ig * 16 + ii;
    float acc = 0.f;
    for (int k = 0; k < 64; k++) acc += As[i * 64 + k] * Bs[k * 64 + j];
    Mout[i * 64 + j] = alpha * acc;
  }
  if (cvec && t < 64) {
    float acc = bias ? bias[t] : 0.f;
    for (int k = 0; k < 64; k++) {
      float bb = (bv1 ? bv1[k] : 0.f) + (bv2 ? bv2[k] : 0.f);
      acc += beta * As[t * 64 + k] * bb;
    }
    cvec[t] = acc;
  }
}

__global__ __launch_bounds__(256) void khistdeg(const int* __restrict__ dst, const float* __restrict__ w,
                                                int* __restrict__ cnt, float* __restrict__ deg, int E) {
  int e = blockIdx.x * 256 + threadIdx.x;
  if (e < E) {
    int d = dst[e];
    atomicAdd(&cnt[d], 1);
    atomicAdd(&deg[d], w[e]);
  }
}

__global__ __launch_bounds__(256) void kdinv(float* deg, int n) {
  int i = blockIdx.x * 256 + threadIdx.x;
  if (i < n) { float d = deg[i]; deg[i] = d > 0.f ? rsqrtf(d) : 0.f; }
}

// ---- block scan (1024 elems/block) ----
__global__ __launch_bounds__(256) void kscan1(const int* __restrict__ cnt, int* __restrict__ bsum, int n) {
  __shared__ int sh[256];
  int b = blockIdx.x, t = threadIdx.x;
  int base = b * 1024 + t * 4;
  int s = 0;
#pragma unroll
  for (int j = 0; j < 4; j++) { int i = base + j; if (i < n) s += cnt[i]; }
  sh[t] = s; __syncthreads();
  for (int d = 128; d; d >>= 1) { if (t < d) sh[t] += sh[t + d]; __syncthreads(); }
  if (t == 0) bsum[b] = sh[0];
}
__global__ void kscan2(int* bsum, int nb, int* off_n) {
  if (threadIdx.x == 0 && blockIdx.x == 0) {
    int run = 0;
    for (int b = 0; b < nb; b++) { int v = bsum[b]; bsum[b] = run; run += v; }
    *off_n = run;
  }
}
__global__ __launch_bounds__(256) void kscan3(int* __restrict__ cnt, const int* __restrict__ bsum, int n) {
  __shared__ int sh[256];
  int b = blockIdx.x, t = threadIdx.x;
  int base = b * 1024 + t * 4;
  int c0 = (base + 0 < n) ? cnt[base + 0] : 0;
  int c1 = (base + 1 < n) ? cnt[base + 1] : 0;
  int c2 = (base + 2 < n) ? cnt[base + 2] : 0;
  int c3 = (base + 3 < n) ? cnt[base + 3] : 0;
  int tot = c0 + c1 + c2 + c3;
  sh[t] = tot; __syncthreads();
  for (int d = 1; d < 256; d <<= 1) {
    int v = (t >= d) ? sh[t - d] : 0;
    __syncthreads();
    sh[t] += v;
    __syncthreads();
  }
  int excl = sh[t] - tot + bsum[b];
  if (base + 0 < n) cnt[base + 0] = excl;
  if (base + 1 < n) cnt[base + 1] = excl + c0;
  if (base + 2 < n) cnt[base + 2] = excl + c0 + c1;
  if (base + 3 < n) cnt[base + 3] = excl + c0 + c1 + c2;
}

__global__ __launch_bounds__(256) void kfillcsr(const int* __restrict__ src, const int* __restrict__ dst,
                                                const float* __restrict__ w, const float* __restrict__ dinv,
                                                const int* __restrict__ off, int* __restrict__ fill,
                                                float2* __restrict__ pack, int E, int tabrows) {
  int e = blockIdx.x * 256 + threadIdx.x;
  if (e >= E) return;
  int s = src[e], d = dst[e];
  float coef = dinv[s] * w[e] * dinv[d];
  int pos = off[d] + atomicAdd(&fill[d], 1);
  pack[pos] = make_float2(coef, __int_as_float(s % tabrows));
}

// wave-per-row CSR gather: agg[i] = dinv[i]^2*tab[i%tabrows] + sum_j coef_j*tab[src_j]
__global__ __launch_bounds__(256) void kgather(const int* __restrict__ off, const float2* __restrict__ pack,
                                               const float* __restrict__ dinv, const float* __restrict__ tab,
                                               float* __restrict__ agg, int n, int tabrows) {
  int lane = threadIdx.x & 63;
  int wv = blockIdx.x * 4 + (threadIdx.x >> 6);
  int nw = gridDim.x * 4;
  for (int i = wv; i < n; i += nw) {
    int b0 = off[i], b1 = off[i + 1];
    float dv = dinv[i];
    float acc = dv * dv * tab[(i % tabrows) * 64 + lane];
    int j = b0;
    for (; j + 1 < b1; j += 2) {
      float2 p0 = pack[j], p1 = pack[j + 1];
      acc += p0.x * tab[__float_as_int(p0.y) * 64 + lane];
      acc += p1.x * tab[__float_as_int(p1.y) * 64 + lane];
    }
    if (j < b1) {
      float2 p = pack[j];
      acc += p.x * tab[__float_as_int(p.y) * 64 + lane];
    }
    agg[i * 64 + lane] = acc;
  }
}

// ===================== big-N tiled GEMM (128 rows x 64 cols, K=64) =====================
// microtile 4 rows x 8 cols per thread; thread grid 32 rowgroups x 8 colgroups
template <bool PRE, bool EB, bool PERG, bool BF16>
__global__ __launch_bounds__(256, 3) void gemm_big(
    const float* __restrict__ X, const float* __restrict__ Wg,
    const float* __restrict__ bias, const float* __restrict__ pa, const float* __restrict__ pb,
    const float* __restrict__ perg, float* __restrict__ Yf, u16* __restrict__ Ybf,
    float* __restrict__ stats, int sqoff) {
  __shared__ float xs[128 * 68];
  __shared__ float wt[64 * 68];
  __shared__ float sstat[128];
  int t = threadIdx.x, cg = t & 7, rg = t >> 3;
  // stage W^T: wt[k*68+oc] = Wg[oc*64+k]
  for (int idx = t; idx < 4096; idx += 256) {
    int oc = idx >> 6, k = idx & 63;
    wt[k * 68 + oc] = Wg[idx];
  }
  float sS[8], sQ[8];
#pragma unroll
  for (int j = 0; j < 8; j++) { sS[j] = 0.f; sQ[j] = 0.f; }
  float bb[8];
  {
    float4 b0 = *(const float4*)&bias[cg * 8];
    float4 b1 = *(const float4*)&bias[cg * 8 + 4];
    bb[0] = b0.x; bb[1] = b0.y; bb[2] = b0.z; bb[3] = b0.w;
    bb[4] = b1.x; bb[5] = b1.y; bb[6] = b1.z; bb[7] = b1.w;
  }
  for (int tile = blockIdx.x; tile < NTILES; tile += gridDim.x) {
    int R0 = tile * 128;
    __syncthreads();
#pragma unroll
    for (int m = 0; m < 8; m++) {
      int f = m * 256 + t;
      int r = f >> 4, c4 = (f & 15) * 4;
      float4 v = *(const float4*)&X[(size_t)(R0 + r) * 64 + c4];
      if (PRE) {
        float4 A = *(const float4*)&pa[c4];
        float4 Bv;
        if (EB) { int b = (R0 + r) / Gn; Bv = *(const float4*)&pb[b * 64 + c4]; }
        else Bv = *(const float4*)&pb[c4];
        v.x = fmaxf(fmaf(A.x, v.x, Bv.x), 0.f);
        v.y = fmaxf(fmaf(A.y, v.y, Bv.y), 0.f);
        v.z = fmaxf(fmaf(A.z, v.z, Bv.z), 0.f);
        v.w = fmaxf(fmaf(A.w, v.w, Bv.w), 0.f);
      }
      *(float4*)&xs[r * 68 + c4] = v;
    }
    __syncthreads();
    float acc[4][8];
#pragma unroll
    for (int i = 0; i < 4; i++)
#pragma unroll
      for (int j = 0; j < 8; j++) acc[i][j] = 0.f;
#pragma unroll
    for (int kc = 0; kc < 16; kc++) {
      float4 x0 = *(const float4*)&xs[(rg * 4 + 0) * 68 + kc * 4];
      float4 x1 = *(const float4*)&xs[(rg * 4 + 1) * 68 + kc * 4];
      float4 x2 = *(const float4*)&xs[(rg * 4 + 2) * 68 + kc * 4];
      float4 x3 = *(const float4*)&xs[(rg * 4 + 3) * 68 + kc * 4];
#pragma unroll
      for (int kk = 0; kk < 4; kk++) {
        const float* wr = &wt[(kc * 4 + kk) * 68 + cg * 8];
        float4 w0 = *(const float4*)wr;
        float4 w1 = *(const float4*)(wr + 4);
        float wv[8] = {w0.x, w0.y, w0.z, w0.w, w1.x, w1.y, w1.z, w1.w};
        float a0 = XC(x0, kk), a1 = XC(x1, kk), a2 = XC(x2, kk), a3 = XC(x3, kk);
#pragma unroll
        for (int j = 0; j < 8; j++) {
          acc[0][j] = fmaf(a0, wv[j], acc[0][j]);
          acc[1][j] = fmaf(a1, wv[j], acc[1][j]);
          acc[2][j] = fmaf(a2, wv[j], acc[2][j]);
          acc[3][j] = fmaf(a3, wv[j], acc[3][j]);
        }
      }
    }
    // epilogue
#pragma unroll
    for (int i = 0; i < 4; i++) {
      int grow = R0 + rg * 4 + i;
      float v[8];
#pragma unroll
      for (int j = 0; j < 8; j++) v[j] = acc[i][j] + bb[j];
      if (PERG) {
        int qr = grow % Gn;
        float4 q0 = *(const float4*)&perg[(size_t)qr * 64 + cg * 8];
        float4 q1 = *(const float4*)&perg[(size_t)qr * 64 + cg * 8 + 4];
        v[0] += q0.x; v[1] += q0.y; v[2] += q0.z; v[3] += q0.w;
        v[4] += q1.x; v[5] += q1.y; v[6] += q1.z; v[7] += q1.w;
      }
#pragma unroll
      for (int j = 0; j < 8; j++) { sS[j] += v[j]; sQ[j] += v[j] * v[j]; }
      if (BF16) {
        uint4 o;
        o.x = (u32)f2bf(v[0]) | ((u32)f2bf(v[1]) << 16);
        o.y = (u32)f2bf(v[2]) | ((u32)f2bf(v[3]) << 16);
        o.z = (u32)f2bf(v[4]) | ((u32)f2bf(v[5]) << 16);
        o.w = (u32)f2bf(v[6]) | ((u32)f2bf(v[7]) << 16);
        *(uint4*)&Ybf[(size_t)grow * 128 + cg * 8] = o;
      } else {
        float4 o0 = make_float4(v[0], v[1], v[2], v[3]);
        float4 o1 = make_float4(v[4], v[5], v[6], v[7]);
        *(float4*)&Yf[(size_t)grow * 64 + cg * 8] = o0;
        *(float4*)&Yf[(size_t)grow * 64 + cg * 8 + 4] = o1;
      }
    }
  }
  // stats reduction
  __syncthreads();
  for (int idx = t; idx < 128; idx += 256) sstat[idx] = 0.f;
  __syncthreads();
#pragma unroll
  for (int j = 0; j < 8; j++) {
    atomicAdd(&sstat[cg * 8 + j], sS[j]);
    atomicAdd(&sstat[64 + cg * 8 + j], sQ[j]);
  }
  __syncthreads();
  for (int idx = t; idx < 64; idx += 256) {
    atomicAdd(&stats[idx], sstat[idx]);
    atomicAdd(&stats[sqoff + idx], sstat[64 + idx]);
  }
}

// k11: r2 = relu(a4*r1+b4) @ W2^T + b2 ; K=128 (two staged halves), r1 in bf16 pitch 128
__global__ __launch_bounds__(256, 3) void gemm_k11(
    const u16* __restrict__ Xbf, const float* __restrict__ W2,
    const float* __restrict__ bias, const float* __restrict__ a4, const float* __restrict__ b4,
    float* __restrict__ Y, float* __restrict__ stats) {
  __shared__ float xs[128 * 68];
  __shared__ float wt[64 * 68];
  __shared__ float sstat[128];
  int t = threadIdx.x, cg = t & 7, rg = t >> 3;
  float sS[8], sQ[8];
#pragma unroll
  for (int j = 0; j < 8; j++) { sS[j] = 0.f; sQ[j] = 0.f; }
  float bb[8];
  {
    float4 b0 = *(const float4*)&bias[cg * 8];
    float4 b1 = *(const float4*)&bias[cg * 8 + 4];
    bb[0] = b0.x; bb[1] = b0.y; bb[2] = b0.z; bb[3] = b0.w;
    bb[4] = b1.x; bb[5] = b1.y; bb[6] = b1.z; bb[7] = b1.w;
  }
  for (int tile = blockIdx.x; tile < NTILES; tile += gridDim.x) {
    int R0 = tile * 128;
    float acc[4][8];
#pragma unroll
    for (int i = 0; i < 4; i++)
#pragma unroll
      for (int j = 0; j < 8; j++) acc[i][j] = 0.f;
    for (int hh = 0; hh < 2; hh++) {
      __syncthreads();
      // stage wt half: wt[kl*68+oc] = W2[oc*128 + hh*64 + kl]
      for (int idx = t; idx < 4096; idx += 256) {
        int oc = idx >> 6, kl = idx & 63;
        wt[kl * 68 + oc] = W2[oc * 128 + hh * 64 + kl];
      }
      // stage xs half (bf16 -> fp32, apply relu(a4*x+b4))
#pragma unroll
      for (int m = 0; m < 4; m++) {
        int f = m * 256 + t;
        int r = f >> 3, ch = f & 7;
        const uint4* p = (const uint4*)&Xbf[(size_t)(R0 + r) * 128 + hh * 64 + ch * 8];
        uint4 u = *p;
        int kb = hh * 64 + ch * 8;
        float4 A0 = *(const float4*)&a4[kb];
        float4 A1 = *(const float4*)&a4[kb + 4];
        float4 B0 = *(const float4*)&b4[kb];
        float4 B1 = *(const float4*)&b4[kb + 4];
        float4 v0, v1;
        v0.x = fmaxf(fmaf(A0.x, bflo(u.x), B0.x), 0.f);
        v0.y = fmaxf(fmaf(A0.y, bfhi(u.x), B0.y), 0.f);
        v0.z = fmaxf(fmaf(A0.z, bflo(u.y), B0.z), 0.f);
        v0.w = fmaxf(fmaf(A0.w, bfhi(u.y), B0.w), 0.f);
        v1.x = fmaxf(fmaf(A1.x, bflo(u.z), B1.x), 0.f);
        v1.y = fmaxf(fmaf(A1.y, bfhi(u.z), B1.y), 0.f);
        v1.z = fmaxf(fmaf(A1.z, bflo(u.w), B1.z), 0.f);
        v1.w = fmaxf(fmaf(A1.w, bfhi(u.w), B1.w), 0.f);
        *(float4*)&xs[r * 68 + ch * 8] = v0;
        *(float4*)&xs[r * 68 + ch * 8 + 4] = v1;
      }
      __syncthreads();
#pragma unroll
      for (int kc = 0; kc < 16; kc++) {
        float4 x0 = *(const float4*)&xs[(rg * 4 + 0) * 68 + kc * 4];
        float4 x1 = *(const float4*)&xs[(rg * 4 + 1) * 68 + kc * 4];
        float4 x2 = *(const float4*)&xs[(rg * 4 + 2) * 68 + kc * 4];
        float4 x3 = *(const float4*)&xs[(rg * 4 + 3) * 68 + kc * 4];
#pragma unroll
        for (int kk = 0; kk < 4; kk++) {
          const float* wr = &wt[(kc * 4 + kk) * 68 + cg * 8];
          float4 w0 = *(const float4*)wr;
          float4 w1 = *(const float4*)(wr + 4);
          float wv[8] = {w0.x, w0.y, w0.z, w0.w, w1.x, w1.y, w1.z, w1.w};
          float a0 = XC(x0, kk), a1 = XC(x1, kk), a2 = XC(x2, kk), a3 = XC(x3, kk);
#pragma unroll
          for (int j = 0; j < 8; j++) {
            acc[0][j] = fmaf(a0, wv[j], acc[0][j]);
            acc[1][j] = fmaf(a1, wv[j], acc[1][j]);
            acc[2][j] = fmaf(a2, wv[j], acc[2][j]);
            acc[3][j] = fmaf(a3, wv[j], acc[3][j]);
          }
        }
      }
    }
#pragma unroll
    for (int i = 0; i < 4; i++) {
      int grow = R0 + rg * 4 + i;
      float v[8];
#pragma unroll
      for (int j = 0; j < 8; j++) {
        v[j] = acc[i][j] + bb[j];
        sS[j] += v[j]; sQ[j] += v[j] * v[j];
      }
      *(float4*)&Y[(size_t)grow * 64 + cg * 8] = make_float4(v[0], v[1], v[2], v[3]);
      *(float4*)&Y[(size_t)grow * 64 + cg * 8 + 4] = make_float4(v[4], v[5], v[6], v[7]);
    }
  }
  __syncthreads();
  for (int idx = t; idx < 128; idx += 256) sstat[idx] = 0.f;
  __syncthreads();
#pragma unroll
  for (int j = 0; j < 8; j++) {
    atomicAdd(&sstat[cg * 8 + j], sS[j]);
    atomicAdd(&sstat[64 + cg * 8 + j], sQ[j]);
  }
  __syncthreads();
  for (int idx = t; idx < 128; idx += 256) atomicAdd(&stats[idx], sstat[idx]);
}

// ===================== old small-size GEMM (kept for Pn/Gn paths) =====================
template <bool TWO, bool PRE, bool PRELU, bool PERG, bool STATS>
__global__ __launch_bounds__(256) void gemm64k(
    const float* __restrict__ X, const float* __restrict__ Xb,
    const float* __restrict__ Wm, const float* __restrict__ Wb,
    const float* __restrict__ bias,
    const float* __restrict__ pa, const float* __restrict__ pb,
    const float* __restrict__ perg, int tabrows,
    float* __restrict__ Y, float* __restrict__ stats, int rows) {
  __shared__ float xs[4096];
  __shared__ float red[4][64], red2[4][64];
  int t = threadIdx.x, lane = t & 63, wv = t >> 6;
  int ntiles = (rows + 63) >> 6;
  float psum = 0.f, psq = 0.f;
  float bv = bias ? bias[lane] : 0.f;
  for (int tile = blockIdx.x; tile < ntiles; tile += gridDim.x) {
    int base = tile * 64;
    float acc[16];
#pragma unroll
    for (int j = 0; j < 16; j++) acc[j] = bv;
    for (int pass = 0; pass < (TWO ? 2 : 1); pass++) {
      const float* Xp = pass ? Xb : X;
      const float* Wp = pass ? Wb : Wm;
      __syncthreads();
#pragma unroll
      for (int m = 0; m < 16; m++) {
        int fl = m * 256 + t;
        int r = fl >> 6, c = fl & 63;
        int gr = base + r;
        float v = (gr < rows) ? Xp[gr * 64 + c] : 0.f;
        if (PRE) { v = pa[c] * v + pb[c]; if (PRELU) v = fmaxf(v, 0.f); }
        xs[fl] = v;
      }
      __syncthreads();
      float Wreg[64];
#pragma unroll
      for (int k = 0; k < 64; k++) Wreg[k] = Wp[lane * 64 + k];
#pragma unroll
      for (int j = 0; j < 16; j++) {
        int r = wv * 16 + j;
        const float4* xr = (const float4*)&xs[r * 64];
        float a = acc[j];
#pragma unroll
        for (int kk = 0; kk < 16; kk++) {
          float4 xv = xr[kk];
          a = fmaf(xv.x, Wreg[4 * kk + 0], a);
          a = fmaf(xv.y, Wreg[4 * kk + 1], a);
          a = fmaf(xv.z, Wreg[4 * kk + 2], a);
          a = fmaf(xv.w, Wreg[4 * kk + 3], a);
        }
        acc[j] = a;
      }
    }
#pragma unroll
    for (int j = 0; j < 16; j++) {
      int gr = base + wv * 16 + j;
      if (gr < rows) {
        float v = acc[j];
        if (PERG) v += perg[(gr % tabrows) * 64 + lane];
        Y[gr * 64 + lane] = v;
        if (STATS) { psum += v; psq += v * v; }
      }
    }
  }
  if (STATS) {
    __syncthreads();
    red[wv][lane] = psum; red2[wv][lane] = psq;
    __syncthreads();
    if (wv == 0) {
      float s = red[0][lane] + red[1][lane] + red[2][lane] + red[3][lane];
      float q = red2[0][lane] + red2[1][lane] + red2[2][lane] + red2[3][lane];
      atomicAdd(&stats[lane], s);
      atomicAdd(&stats[64 + lane], q);
    }
  }
}

// stats of u = a2*T2 + b2 + emb[row/G]  (no store)
__global__ __launch_bounds__(256) void k7_kernel(const float* __restrict__ T2, const float* __restrict__ a2,
                                                 const float* __restrict__ b2, const float* __restrict__ emb,
                                                 float* __restrict__ stats, int rows, int rowsPerB) {
  int lane = threadIdx.x & 63, wv = threadIdx.x >> 6;
  __shared__ float red[4][64], red2[4][64];
  float ps = 0.f, pq = 0.f;
  int total = rows * 64;
  int stride = gridDim.x * 256;
  for (int idx = blockIdx.x * 256 + threadIdx.x; idx < total; idx += stride) {
    int i = idx >> 6, c = idx & 63;
    int b = i / rowsPerB;
    float v = a2[c] * T2[idx] + b2[c] + emb[b * 64 + c];
    ps += v; pq += v * v;
  }
  red[wv][lane] = ps; red2[wv][lane] = pq;
  __syncthreads();
  if (wv == 0) {
    float s = red[0][lane] + red[1][lane] + red[2][lane] + red[3][lane];
    float q = red2[0][lane] + red2[1][lane] + red2[2][lane] + red2[3][lane];
    atomicAdd(&stats[lane], s);
    atomicAdd(&stats[64 + lane], q);
  }
}

// finalize S3 and build folded vectors: Avec = a3*a2, e2[b] = a3*(b2+emb[b]) + b3
__global__ __launch_bounds__(256) void kfinS3e2(const float* __restrict__ stats, const float* __restrict__ g,
                                                const float* __restrict__ bt, const float* __restrict__ a2,
                                                const float* __restrict__ b2, const float* __restrict__ emb,
                                                float* __restrict__ Avec, float* __restrict__ e2, float invn) {
  __shared__ float a3s[64], b3s[64];
  int t = threadIdx.x;
  if (t < 64) {
    float mean = stats[t] * invn;
    float var = stats[64 + t] * invn - mean * mean;
    float sc = g[t] * rsqrtf(var + 1e-5f);
    float sh = bt[t] - mean * sc;
    a3s[t] = sc; b3s[t] = sh;
    Avec[t] = sc * a2[t];
  }
  __syncthreads();
  for (int idx = t; idx < 2048; idx += 256) {
    int c = idx & 63;
    e2[idx] = a3s[c] * (b2[c] + emb[idx]) + b3s[c];
  }
}

// w1[i] = dot(a5*R2[i]+b5, indv_w1[i%G]) + indv_b1[i%G]
__global__ __launch_bounds__(256) void k13_kernel(const float* __restrict__ R2, const float* __restrict__ a5,
                                                  const float* __restrict__ b5, const float* __restrict__ iw1,
                                                  const float* __restrict__ ib1, float* __restrict__ w1out,
                                                  int rows, int tabrows) {
  int t = blockIdx.x * 256 + threadIdx.x;
  int i = t >> 4, j = t & 15;
  if (i >= rows) return;
  int g = i % tabrows;
  float4 r = ((const float4*)R2)[i * 16 + j];
  float4 a = ((const float4*)a5)[j];
  float4 b = ((const float4*)b5)[j];
  float4 w = ((const float4*)iw1)[g * 16 + j];
  float p = (a.x * r.x + b.x) * w.x + (a.y * r.y + b.y) * w.y +
            (a.z * r.z + b.z) * w.z + (a.w * r.w + b.w) * w.w;
  for (int off = 8; off; off >>= 1) p += __shfl_xor(p, off, 64);
  if (j == 0) w1out[i] = p + ib1[g];
}

// cgraw[b][col] = sum_g w1[b][g]*cgW1[col][g] + cgb1[col]
__global__ __launch_bounds__(256) void kcg1(const float* __restrict__ w1, const float* __restrict__ cgW1,
                                            const float* __restrict__ cgb1, float* __restrict__ cgraw) {
  __shared__ float ws[Gn];
  int b = blockIdx.x, t = threadIdx.x, lane = t & 63, wv = t >> 6;
  for (int g = t; g < Gn; g += 256) ws[g] = w1[b * Gn + g];
  __syncthreads();
  for (int col = wv; col < 64; col += 4) {
    float p = 0.f;
    for (int g = lane; g < Gn; g += 64) p += ws[g] * cgW1[col * Gn + g];
    for (int off = 32; off; off >>= 1) p += __shfl_xor(p, off, 64);
    if (lane == 0) cgraw[b * 64 + col] = p + cgb1[col];
  }
}

// single-block: cg2 = bn2(relu(bn1(cgraw)) @ W2^T + b2)   (BN over 32 rows)
__global__ __launch_bounds__(256) void kcg2(const float* __restrict__ cgraw, const float* __restrict__ g1,
                                            const float* __restrict__ bt1, const float* __restrict__ W2,
                                            const float* __restrict__ b2, const float* __restrict__ g2,
                                            const float* __restrict__ bt2, float* __restrict__ cg2out) {
  int t = threadIdx.x, c = t & 63, bg = t >> 6;
  __shared__ float hmid[2048], sred[4][64], qred[4][64], asc[64], bsh[64];
  float y[8];
  float ps = 0.f, pq = 0.f;
  for (int jb = 0; jb < 8; jb++) {
    int b = bg * 8 + jb;
    float v = cgraw[b * 64 + c];
    y[jb] = v; ps += v; pq += v * v;
  }
  sred[bg][c] = ps; qred[bg][c] = pq;
  __syncthreads();
  if (t < 64) {
    float s = sred[0][t] + sred[1][t] + sred[2][t] + sred[3][t];
    float q = qred[0][t] + qred[1][t] + qred[2][t] + qred[3][t];
    float mean = s * (1.f / 32.f), var = q * (1.f / 32.f) - mean * mean;
    float sc = g1[t] * rsqrtf(var + 1e-5f);
    asc[t] = sc; bsh[t] = bt1[t] - mean * sc;
  }
  __syncthreads();
  for (int jb = 0; jb < 8; jb++) { int b = bg * 8 + jb; hmid[b * 64 + c] = fmaxf(asc[c] * y[jb] + bsh[c], 0.f); }
  __syncthreads();
  ps = 0.f; pq = 0.f;
  for (int jb = 0; jb < 8; jb++) {
    int b = bg * 8 + jb;
    float a = b2[c];
    for (int k = 0; k < 64; k++) a += hmid[b * 64 + k] * W2[c * 64 + k];
    y[jb] = a; ps += a; pq += a * a;
  }
  sred[bg][c] = ps; qred[bg][c] = pq;
  __syncthreads();
  if (t < 64) {
    float s = sred[0][t] + sred[1][t] + sred[2][t] + sred[3][t];
    float q = qred[0][t] + qred[1][t] + qred[2][t] + qred[3][t];
    float mean = s * (1.f / 32.f), var = q * (1.f / 32.f) - mean * mean;
    float sc = g2[t] * rsqrtf(var + 1e-5f);
    asc[t] = sc; bsh[t] = bt2[t] - mean * sc;
  }
  __syncthreads();
  for (int jb = 0; jb < 8; jb++) { int b = bg * 8 + jb; cg2out[b * 64 + c] = asc[c] * y[jb] + bsh[c]; }
}

// single-block: emb = mlp3(pglob[pert_idx]) with BN over 32 rows
__global__ __launch_bounds__(256) void kemb(const float* __restrict__ m2, const float* __restrict__ aP2,
                                            const float* __restrict__ bP2, const int* __restrict__ pidx,
                                            const float* __restrict__ Wm, const float* __restrict__ bv,
                                            const float* __restrict__ gg, const float* __restrict__ btv,
                                            float* __restrict__ emb) {
  int t = threadIdx.x, c = t & 63, bg = t >> 6;
  __shared__ float xin[2048], hmid[2048], sred[4][64], qred[4][64], asc[64], bsh[64];
  for (int idx = t; idx < 2048; idx += 256) {
    int b = idx >> 6, cc = idx & 63;
    xin[idx] = aP2[cc] * m2[pidx[b] * 64 + cc] + bP2[cc];
  }
  __syncthreads();
  float y[8];
  float ps = 0.f, pq = 0.f;
  for (int jb = 0; jb < 8; jb++) {
    int b = bg * 8 + jb;
    float a = bv[c];
    for (int k = 0; k < 64; k++) a += xin[b * 64 + k] * Wm[c * 64 + k];
    y[jb] = a; ps += a; pq += a * a;
  }
  sred[bg][c] = ps; qred[bg][c] = pq;
  __syncthreads();
  if (t < 64) {
    float s = sred[0][t] + sred[1][t] + sred[2][t] + sred[3][t];
    float q = qred[0][t] + qred[1][t] + qred[2][t] + qred[3][t];
    float mean = s * (1.f / 32.f), var = q * (1.f / 32.f) - mean * mean;
    float sc = gg[t] * rsqrtf(var + 1e-5f);
    asc[t] = sc; bsh[t] = btv[t] - mean * sc;
  }
  __syncthreads();
  for (int jb = 0; jb < 8; jb++) { int b = bg * 8 + jb; hmid[b * 64 + c] = fmaxf(asc[c] * y[jb] + bsh[c], 0.f); }
  __syncthreads();
  ps = 0.f; pq = 0.f;
  for (int jb = 0; jb < 8; jb++) {
    int b = bg * 8 + jb;
    float a = bv[64 + c];
    for (int k = 0; k < 64; k++) a += hmid[b * 64 + k] * Wm[4096 + c * 64 + k];
    y[jb] = a; ps += a; pq += a * a;
  }
  sred[bg][c] = ps; qred[bg][c] = pq;
  __syncthreads();
  if (t < 64) {
    float s = sred[0][t] + sred[1][t] + sred[2][t] + sred[3][t];
    float q = qred[0][t] + qred[1][t] + qred[2][t] + qred[3][t];
    float mean = s * (1.f / 32.f), var = q * (1.f / 32.f) - mean * mean;
    float sc = gg[64 + t] * rsqrtf(var + 1e-5f);
    asc[t] = sc; bsh[t] = btv[64 + t] - mean * sc;
  }
  __syncthreads();
  for (int jb = 0; jb < 8; jb++) { int b = bg * 8 + jb; emb[b * 64 + c] = asc[c] * y[jb] + bsh[c]; }
}

// final: out[b][g] = w1*iw2[g][0] + dot(cg2[b], iw2[g][1:65]) + ib2[g] + x[b][g]
__global__ __launch_bounds__(256) void kfinal(const float* __restrict__ w1, const float* __restrict__ cg2,
                                              const float* __restrict__ iw2, const float* __restrict__ ib2,
                                              const float* __restrict__ x, float* __restrict__ out) {
  __shared__ float iws[64 * 65], cgs[2048];
  int t = threadIdx.x;
  int g0 = blockIdx.x * 64;
  for (int idx = t; idx < 64 * 65; idx += 256) {
    int gi = g0 * 65 + idx;
    iws[idx] = (gi < Gn * 65) ? iw2[gi] : 0.f;
  }
  for (int idx = t; idx < 2048; idx += 256) cgs[idx] = cg2[idx];
  __syncthreads();
  int gl = t & 63, bg = t >> 6;
  int g = g0 + gl;
  if (g >= Gn) return;
  float bias = ib2[g];
  for (int jb = 0; jb < 8; jb++) {
    int b = bg * 8 + jb;
    float acc = w1[b * Gn + g] * iws[gl * 65] + bias;
    for (int k = 0; k < 64; k++) acc += cgs[b * 64 + k] * iws[gl * 65 + 1 + k];
    out[b * Gn + g] = acc + x[b * Gn + g];
  }
}

extern "C" void kernel_launch(void* const* d_in, const int* in_sizes, int n_in,
                              void* d_out, int out_size, void* d_ws, size_t ws_size,
                              hipStream_t stream) {
  (void)in_sizes; (void)n_in; (void)out_size;
  if (ws_size < WS_FLOATS * sizeof(float)) return;

  const float* x        = (const float*)d_in[0];
  const int*   pert_idx = (const int*)d_in[1];
  const int*   ei_co    = (const int*)d_in[2];
  const float* w_co     = (const float*)d_in[3];
  const int*   ei_go    = (const int*)d_in[4];
  const float* w_go     = (const float*)d_in[5];
  const int*   ei_bg    = (const int*)d_in[6];
  const float* w_bg     = (const float*)d_in[7];
  const float* gene_tab = (const float*)d_in[8];
  const float* pos_tab  = (const float*)d_in[9];
  const float* go_tab   = (const float*)d_in[10];
  const float* bg_tab   = (const float*)d_in[11];
  const float* bn_g     = (const float*)d_in[12];
  const float* bn_b     = (const float*)d_in[13];
  const float* sg_W     = (const float*)d_in[14];
  const float* sg_b     = (const float*)d_in[15];
  const float* mlp_W    = (const float*)d_in[16];
  const float* mlp_b    = (const float*)d_in[17];
  const float* mlp_g    = (const float*)d_in[18];
  const float* mlp_bt   = (const float*)d_in[19];
  const float* rec_W1   = (const float*)d_in[20];
  const float* rec_b1   = (const float*)d_in[21];
  const float* rec_g1   = (const float*)d_in[22];
  const float* rec_bt1  = (const float*)d_in[23];
  const float* rec_W2   = (const float*)d_in[24];
  const float* rec_b2   = (const float*)d_in[25];
  const float* rec_g2   = (const float*)d_in[26];
  const float* rec_bt2  = (const float*)d_in[27];
  const float* indv_w1  = (const float*)d_in[28];
  const float* indv_b1  = (const float*)d_in[29];
  const float* cg_W1    = (const float*)d_in[30];
  const float* cg_b1    = (const float*)d_in[31];
  const float* cg_g1    = (const float*)d_in[32];
  const float* cg_bt1   = (const float*)d_in[33];
  const float* cg_W2    = (const float*)d_in[34];
  const float* cg_b2    = (const float*)d_in[35];
  const float* cg_g2    = (const float*)d_in[36];
  const float* cg_bt2   = (const float*)d_in[37];
  const float* indv_w2  = (const float*)d_in[38];
  const float* indv_b2  = (const float*)d_in[39];

  float* W = (float*)d_ws;
  float* buf0 = W + oBUF0;
  float* buf1 = W + oBUF1;

  // CSR scratch lives in buf1 (consumed before t1 writes buf1)
  int*    co_cnt  = (int*)(buf1);                    // 160001
  int*    co_fill = (int*)(buf1 + 160064);
  int*    sbsum   = (int*)(buf1 + 320128);           // <=157 block sums
  float2* co_pack = (float2*)(buf1 + 400000);        // 1.6M float2
  int*    go_cnt  = (int*)(buf1 + 3700000);
  int*    go_fill = (int*)(buf1 + 3710000);
  float2* go_pack = (float2*)(buf1 + 3720000);
  int*    bg_cnt  = (int*)(buf1 + 4000000);
  int*    bg_fill = (int*)(buf1 + 4010000);
  float2* bg_pack = (float2*)(buf1 + 4020000);

  // --- phase 0: zero stats, renorm tables, fold small matrices ---
  kzero<<<8, 256, 0, stream>>>(W, 2048);
  krenorm<<<160, 256, 0, stream>>>(gene_tab, W + oRG, W + oSG, Gn);
  krenorm<<<160, 256, 0, stream>>>(pos_tab, W + oRP, nullptr, Gn);
  krenorm<<<160, 256, 0, stream>>>(go_tab, W + oRGO, nullptr, Pn);
  krenorm<<<160, 256, 0, stream>>>(bg_tab, W + oRBG, nullptr, Pn);
  kfin<<<1, 64, 0, stream>>>(W + oSG, bn_g, bn_b, W + oAG, W + oBG, 64, 1.f / Gn);
  ksmallmat<<<1, 256, 0, stream>>>(mlp_W + 8192, sg_W, 0.2f, mlp_b + 128, sg_b, nullptr, 0.2f, W + oM, W + oCvec);
  ksmallmat<<<1, 256, 0, stream>>>(mlp_W, sg_W + 4096, 1.f, nullptr, nullptr, nullptr, 0.f, W + oM1, nullptr);
  ksmallmat<<<1, 256, 0, stream>>>(mlp_W, sg_W + 8192, 1.f, mlp_b, sg_b + 64, sg_b + 128, 1.f, W + oM2, W + oCcP);
  gemm64k<false, true, true, false, false><<<79, 256, 0, stream>>>(
      W + oRG, nullptr, mlp_W + 8192, nullptr, W + oCvec, W + oAG, W + oBG, nullptr, 0, W + oQ, nullptr, Gn);

  // --- co graph: CSR build + gather ---
  kfill<<<(Nn + 255) / 256, 256, 0, stream>>>(W + oDEG, 1.f, Nn);
  kzero<<<(160001 + 255) / 256, 256, 0, stream>>>((float*)co_cnt, 160001);
  khistdeg<<<(ECO + 255) / 256, 256, 0, stream>>>(ei_co + ECO, w_co, co_cnt, W + oDEG, ECO);
  kdinv<<<(Nn + 255) / 256, 256, 0, stream>>>(W + oDEG, Nn);
  kscan1<<<157, 256, 0, stream>>>(co_cnt, sbsum, Nn);
  kscan2<<<1, 64, 0, stream>>>(sbsum, 157, co_cnt + Nn);
  kscan3<<<157, 256, 0, stream>>>(co_cnt, sbsum, Nn);
  kzero<<<(Nn + 255) / 256, 256, 0, stream>>>((float*)co_fill, Nn);
  kfillcsr<<<(ECO + 255) / 256, 256, 0, stream>>>(ei_co, ei_co + ECO, w_co, W + oDEG,
                                                  co_cnt, co_fill, co_pack, ECO, Gn);
  kgather<<<2048, 256, 0, stream>>>(co_cnt, co_pack, W + oDEG, W + oRP, buf0, Nn, Gn);

  // --- go graph ---
  kfill<<<(Pn + 255) / 256, 256, 0, stream>>>(W + oDGO, 1.f, Pn);
  kzero<<<(5001 + 255) / 256, 256, 0, stream>>>((float*)go_cnt, 5001);
  khistdeg<<<(EGG + 255) / 256, 256, 0, stream>>>(ei_go + EGG, w_go, go_cnt, W + oDGO, EGG);
  kdinv<<<(Pn + 255) / 256, 256, 0, stream>>>(W + oDGO, Pn);
  kscan1<<<5, 256, 0, stream>>>(go_cnt, sbsum, Pn);
  kscan2<<<1, 64, 0, stream>>>(sbsum, 5, go_cnt + Pn);
  kscan3<<<5, 256, 0, stream>>>(go_cnt, sbsum, Pn);
  kzero<<<(Pn + 255) / 256, 256, 0, stream>>>((float*)go_fill, Pn);
  kfillcsr<<<(EGG + 255) / 256, 256, 0, stream>>>(ei_go, ei_go + EGG, w_go, W + oDGO,
                                                  go_cnt, go_fill, go_pack, EGG, Pn);
  kgather<<<512, 256, 0, stream>>>(go_cnt, go_pack, W + oDGO, W + oRGO, W + oAGO, Pn, Pn);

  // --- bg graph ---
  kfill<<<(Pn + 255) / 256, 256, 0, stream>>>(W + oDBG, 1.f, Pn);
  kzero<<<(5001 + 255) / 256, 256, 0, stream>>>((float*)bg_cnt, 5001);
  khistdeg<<<(EGG + 255) / 256, 256, 0, stream>>>(ei_bg + EGG, w_bg, bg_cnt, W + oDBG, EGG);
  kdinv<<<(Pn + 255) / 256, 256, 0, stream>>>(W + oDBG, Pn);
  kscan1<<<5, 256, 0, stream>>>(bg_cnt, sbsum, Pn);
  kscan2<<<1, 64, 0, stream>>>(sbsum, 5, bg_cnt + Pn);
  kscan3<<<5, 256, 0, stream>>>(bg_cnt, sbsum, Pn);
  kzero<<<(Pn + 255) / 256, 256, 0, stream>>>((float*)bg_fill, Pn);
  kfillcsr<<<(EGG + 255) / 256, 256, 0, stream>>>(ei_bg, ei_bg + EGG, w_bg, W + oDBG,
                                                  bg_cnt, bg_fill, bg_pack, EGG, Pn);
  kgather<<<512, 256, 0, stream>>>(bg_cnt, bg_pack, W + oDBG, W + oRBG, W + oABG, Pn, Pn);

  // --- pert path (Pn rows, old kernel) ---
  gemm64k<true, false, false, false, true><<<79, 256, 0, stream>>>(
      W + oAGO, W + oABG, W + oM1, W + oM2, W + oCcP, nullptr, nullptr, nullptr, 0, W + oM1B, W + oSP1, Pn);
  kfin<<<1, 64, 0, stream>>>(W + oSP1, mlp_g, mlp_bt, W + oAP1, W + oBP1, 64, 1.f / Pn);
  gemm64k<false, true, true, false, true><<<79, 256, 0, stream>>>(
      W + oM1B, nullptr, mlp_W + 4096, nullptr, mlp_b + 64, W + oAP1, W + oBP1, nullptr, 0, W + oM2B, W + oSP2, Pn);
  kfin<<<1, 64, 0, stream>>>(W + oSP2, mlp_g + 64, mlp_bt + 64, W + oAP2, W + oBP2, 64, 1.f / Pn);
  kemb<<<1, 256, 0, stream>>>(W + oM2B, W + oAP2, W + oBP2, pert_idx,
                              mlp_W + 16384, mlp_b + 256, mlp_g + 256, mlp_bt + 256, W + oEMB);

  // --- main N pipeline (new tiled GEMMs) ---
  // t1 = agg@M^T + Q[g]; stats S1
  gemm_big<false, false, true, false><<<512, 256, 0, stream>>>(
      buf0, W + oM, W + oZERO, nullptr, nullptr, W + oQ, buf1, nullptr, W + oS1, 64);
  kfin<<<1, 64, 0, stream>>>(W + oS1, mlp_g + 128, mlp_bt + 128, W + oA1, W + oB1, 64, 1.f / Nn);
  // t2 = relu(a1*t1+b1)@W11^T + b11; stats S2
  gemm_big<true, false, false, false><<<512, 256, 0, stream>>>(
      buf1, mlp_W + 12288, mlp_b + 192, W + oA1, W + oB1, nullptr, buf0, nullptr, W + oS2, 64);
  kfin<<<1, 64, 0, stream>>>(W + oS2, mlp_g + 192, mlp_bt + 192, W + oA2, W + oB2, 64, 1.f / Nn);
  // stats of u = a2*t2+b2+emb[b]
  k7_kernel<<<512, 256, 0, stream>>>(buf0, W + oA2, W + oB2, W + oEMB, W + oS3, Nn, Gn);
  kfinS3e2<<<1, 256, 0, stream>>>(W + oS3, bn_g + 64, bn_b + 64, W + oA2, W + oB2, W + oEMB,
                                  W + oAvec, W + oE2, 1.f / Nn);
  // r1 (two 64-col halves): base2 = relu(Avec*t2+e2[b]) in LDS, r1 = base2@W1h^T + b1h, bf16 out
  gemm_big<true, true, false, true><<<512, 256, 0, stream>>>(
      buf0, rec_W1, rec_b1, W + oAvec, W + oE2, nullptr, nullptr, (u16*)buf1, W + oS4, 128);
  gemm_big<true, true, false, true><<<512, 256, 0, stream>>>(
      buf0, rec_W1 + 4096, rec_b1 + 64, W + oAvec, W + oE2, nullptr, nullptr, (u16*)buf1 + 64, W + oS4 + 64, 128);
  kfin<<<2, 64, 0, stream>>>(W + oS4, rec_g1, rec_bt1, W + oA4, W + oB4, 128, 1.f / Nn);
  // r2 = relu(a4*r1+b4)@W2^T + b2; stats S5
  gemm_k11<<<512, 256, 0, stream>>>((const u16*)buf1, rec_W2, rec_b2, W + oA4, W + oB4, buf0, W + oS5);
  kfin<<<1, 64, 0, stream>>>(W + oS5, rec_g2, rec_bt2, W + oA5, W + oB5, 64, 1.f / Nn);
  // w1, cross-gene state, final
  k13_kernel<<<(Nn * 16 + 255) / 256, 256, 0, stream>>>(buf0, W + oA5, W + oB5, indv_w1, indv_b1, W + oW1, Nn, Gn);
  kcg1<<<32, 256, 0, stream>>>(W + oW1, cg_W1, cg_b1, W + oCGRAW);
  kcg2<<<1, 256, 0, stream>>>(W + oCGRAW, cg_g1, cg_bt1, cg_W2, cg_b2, cg_g2, cg_bt2, W + oCG2);
  kfinal<<<(Gn + 63) / 64, 256, 0, stream>>>(W + oW1, W + oCG2, indv_w2, indv_b2, x, (float*)d_out);
}

// Round 3
// 1202.382 us; speedup vs baseline: 3.8985x; 1.3655x over previous
//
#include <hip/hip_runtime.h>

typedef unsigned int u32;
typedef unsigned short u16;

// Problem constants (fixed by the reference)
constexpr int Gn  = 5000;     // genes
constexpr int Bn  = 32;       // batch graphs
constexpr int Pn  = 5000;     // perts
constexpr int Nn  = Bn * Gn;  // 160000
constexpr int ECO = 1600000;
constexpr int EGG = 100000;
constexpr int NTILES = Nn / 128;  // 1250, exact

// ---- workspace layout (float offsets) ----
constexpr int oS1 = 0, oS2 = 128, oS3 = 256, oS4 = 384, oS5 = 640, oSG = 768, oSP1 = 896, oSP2 = 1024;
constexpr int oZERO = 1536;  // stays zero (bias for t1)
constexpr int oA1 = 2048, oB1 = 2112, oA2 = 2176, oB2 = 2240;
constexpr int oA4 = 2304, oB4 = 2432;            // 128 each
constexpr int oA5 = 2560, oB5 = 2624;
constexpr int oAG = 2688, oBG = 2752;
constexpr int oAP1 = 2816, oBP1 = 2880, oAP2 = 2944, oBP2 = 3008;
constexpr int oAvec = 3072, oCvec = 3136, oCcP = 3200;
constexpr int oM  = 4096, oM1 = 8192, oM2 = 12288;
constexpr int oE2 = 16384, oEMB = 18432, oCGRAW = 20480, oCG2 = 22528;
constexpr int oRG  = 24576;
constexpr int oRP  = oRG  + Gn * 64;
constexpr int oQ   = oRP  + Gn * 64;
constexpr int oRGO = oQ   + Gn * 64;
constexpr int oRBG = oRGO + Pn * 64;
constexpr int oAGO = oRBG + Pn * 64;
constexpr int oABG = oAGO + Pn * 64;
constexpr int oM1B = oABG + Pn * 64;
constexpr int oM2B = oM1B + Pn * 64;
constexpr int oDGO = oM2B + Pn * 64;
constexpr int oDBG = oDGO + Pn;
constexpr int oDEG = oDBG + Pn;
constexpr int oW1  = oDEG + Nn;
constexpr int oBUF0 = oW1 + Nn;
constexpr int oBUF1 = oBUF0 + Nn * 64;
constexpr size_t WS_FLOATS = (size_t)oBUF1 + (size_t)Nn * 64;  // ~95 MB

__device__ inline u16 f2bf(float f) {
  u32 u = __float_as_uint(f);
  u = (u + 0x7fffu + ((u >> 16) & 1u)) >> 16;
  return (u16)u;
}
__device__ inline float bflo(u32 v) { return __uint_as_float(v << 16); }
__device__ inline float bfhi(u32 v) { return __uint_as_float(v & 0xffff0000u); }

#define XC(v, kk) ((kk) == 0 ? (v).x : (kk) == 1 ? (v).y : (kk) == 2 ? (v).z : (v).w)

__global__ __launch_bounds__(256) void kzero(float* p, int n) {
  int i = blockIdx.x * 256 + threadIdx.x;
  if (i < n) p[i] = 0.f;
}

__global__ __launch_bounds__(256) void kfill(float* p, float v, int n) {
  int i = blockIdx.x * 256 + threadIdx.x;
  if (i < n) p[i] = v;
}

// row-wise L2 renorm (norm clipped to <=1); optional column stats of the output
__global__ __launch_bounds__(256) void krenorm(const float* __restrict__ in, float* __restrict__ out,
                                               float* __restrict__ stats, int rows) {
  int lane = threadIdx.x & 63, wv = threadIdx.x >> 6;
  int gw = blockIdx.x * 4 + wv, nw = gridDim.x * 4;
  float ps = 0.f, pq = 0.f;
  for (int r = gw; r < rows; r += nw) {
    float v = in[r * 64 + lane];
    float sq = v * v;
    for (int off = 32; off; off >>= 1) sq += __shfl_xor(sq, off, 64);
    float nn = sqrtf(sq);
    float s = fminf(1.f, 1.f / fmaxf(nn, 1e-12f));
    float o = v * s;
    out[r * 64 + lane] = o;
    ps += o; pq += o * o;
  }
  if (!stats) return;
  __shared__ float red[4][64], red2[4][64];
  red[wv][lane] = ps; red2[wv][lane] = pq;
  __syncthreads();
  if (wv == 0) {
    float s = red[0][lane] + red[1][lane] + red[2][lane] + red[3][lane];
    float q = red2[0][lane] + red2[1][lane] + red2[2][lane] + red2[3][lane];
    atomicAdd(&stats[lane], s);
    atomicAdd(&stats[64 + lane], q);
  }
}

// finalize BN: a = g*rsqrt(var+eps), b = bt - mean*a
__global__ void kfin(const float* __restrict__ stats, const float* __restrict__ g,
                     const float* __restrict__ bt, float* __restrict__ a, float* __restrict__ b,
                     int cols, float invn) {
  int c = blockIdx.x * 64 + threadIdx.x;
  if (c >= cols) return;
  float mean = stats[c] * invn;
  float var = stats[cols + c] * invn - mean * mean;
  float sc = g[c] * rsqrtf(var + 1e-5f);
  a[c] = sc;
  b[c] = bt[c] - mean * sc;
}

// Mout = alpha * A @ Bm  (64x64 each); optional cvec = bias + beta * A @ (bv1+bv2)
__global__ __launch_bounds__(256) void ksmallmat(const float* __restrict__ A, const float* __restrict__ Bm,
                                                 float alpha, const float* __restrict__ bias,
                                                 const float* __restrict__ bv1, const float* __restrict__ bv2,
                                                 float beta, float* __restrict__ Mout, float* __restrict__ cvec) {
  __shared__ float As[4096], Bs[4096];
  int t = threadIdx.x;
  for (int m = 0; m < 16; m++) { As[m * 256 + t] = A[m * 256 + t]; Bs[m * 256 + t] = Bm[m * 256 + t]; }
  __syncthreads();
  int j = t & 63, ig = t >> 6;
  for (int ii = 0; ii < 16; ii++) {
    int i = ig * 16 + ii;
    float acc = 0.f;
    for (int k = 0; k < 64; k++) acc += As[i * 64 + k] * Bs[k * 64 + j];
    Mout[i * 64 + j] = alpha * acc;
  }
  if (cvec && t < 64) {
    float acc = bias ? bias[t] : 0.f;
    for (int k = 0; k < 64; k++) {
      float bb = (bv1 ? bv1[k] : 0.f) + (bv2 ? bv2[k] : 0.f);
      acc += beta * As[t * 64 + k] * bb;
    }
    cvec[t] = acc;
  }
}

__global__ __launch_bounds__(256) void khistdeg(const int* __restrict__ dst, const float* __restrict__ w,
                                                int* __restrict__ cnt, float* __restrict__ deg, int E) {
  int e = blockIdx.x * 256 + threadIdx.x;
  if (e < E) {
    int d = dst[e];
    atomicAdd(&cnt[d], 1);
    atomicAdd(&deg[d], w[e]);
  }
}

__global__ __launch_bounds__(256) void kdinv(float* deg, int n) {
  int i = blockIdx.x * 256 + threadIdx.x;
  if (i < n) { float d = deg[i]; deg[i] = d > 0.f ? rsqrtf(d) : 0.f; }
}

// ---- block scan (1024 elems/block) ----
__global__ __launch_bounds__(256) void kscan1(const int* __restrict__ cnt, int* __restrict__ bsum, int n) {
  __shared__ int sh[256];
  int b = blockIdx.x, t = threadIdx.x;
  int base = b * 1024 + t * 4;
  int s = 0;
#pragma unroll
  for (int j = 0; j < 4; j++) { int i = base + j; if (i < n) s += cnt[i]; }
  sh[t] = s; __syncthreads();
  for (int d = 128; d; d >>= 1) { if (t < d) sh[t] += sh[t + d]; __syncthreads(); }
  if (t == 0) bsum[b] = sh[0];
}
// parallel exclusive scan over nb (<=256) block sums; single block of 256
__global__ __launch_bounds__(256) void kscan2(int* bsum, int nb, int* off_n) {
  __shared__ int sh[256];
  int t = threadIdx.x;
  int v = (t < nb) ? bsum[t] : 0;
  sh[t] = v;
  __syncthreads();
  for (int d = 1; d < 256; d <<= 1) {
    int u = (t >= d) ? sh[t - d] : 0;
    __syncthreads();
    sh[t] += u;
    __syncthreads();
  }
  if (t < nb) bsum[t] = sh[t] - v;  // exclusive
  if (t == nb - 1 && off_n) *off_n = sh[t];
}
__global__ __launch_bounds__(256) void kscan3(int* __restrict__ cnt, const int* __restrict__ bsum, int n) {
  __shared__ int sh[256];
  int b = blockIdx.x, t = threadIdx.x;
  int base = b * 1024 + t * 4;
  int c0 = (base + 0 < n) ? cnt[base + 0] : 0;
  int c1 = (base + 1 < n) ? cnt[base + 1] : 0;
  int c2 = (base + 2 < n) ? cnt[base + 2] : 0;
  int c3 = (base + 3 < n) ? cnt[base + 3] : 0;
  int tot = c0 + c1 + c2 + c3;
  sh[t] = tot; __syncthreads();
  for (int d = 1; d < 256; d <<= 1) {
    int v = (t >= d) ? sh[t - d] : 0;
    __syncthreads();
    sh[t] += v;
    __syncthreads();
  }
  int excl = sh[t] - tot + bsum[b];
  if (base + 0 < n) cnt[base + 0] = excl;
  if (base + 1 < n) cnt[base + 1] = excl + c0;
  if (base + 2 < n) cnt[base + 2] = excl + c0 + c1;
  if (base + 3 < n) cnt[base + 3] = excl + c0 + c1 + c2;
}

__global__ __launch_bounds__(256) void kfillcsr(const int* __restrict__ src, const int* __restrict__ dst,
                                                const float* __restrict__ w, const float* __restrict__ dinv,
                                                const int* __restrict__ off, int* __restrict__ fill,
                                                float2* __restrict__ pack, int E, int tabrows) {
  int e = blockIdx.x * 256 + threadIdx.x;
  if (e >= E) return;
  int s = src[e], d = dst[e];
  float coef = dinv[s] * w[e] * dinv[d];
  int pos = off[d] + atomicAdd(&fill[d], 1);
  pack[pos] = make_float2(coef, __int_as_float(s % tabrows));
}

// wave-per-row CSR gather: agg[i] = dinv[i]^2*tab[i%tabrows] + sum_j coef_j*tab[src_j]
__global__ __launch_bounds__(256) void kgather(const int* __restrict__ off, const float2* __restrict__ pack,
                                               const float* __restrict__ dinv, const float* __restrict__ tab,
                                               float* __restrict__ agg, int n, int tabrows) {
  int lane = threadIdx.x & 63;
  int wv = blockIdx.x * 4 + (threadIdx.x >> 6);
  int nw = gridDim.x * 4;
  for (int i = wv; i < n; i += nw) {
    int b0 = off[i], b1 = off[i + 1];
    float dv = dinv[i];
    float acc = dv * dv * tab[(i % tabrows) * 64 + lane];
    int j = b0;
    for (; j + 1 < b1; j += 2) {
      float2 p0 = pack[j], p1 = pack[j + 1];
      acc += p0.x * tab[__float_as_int(p0.y) * 64 + lane];
      acc += p1.x * tab[__float_as_int(p1.y) * 64 + lane];
    }
    if (j < b1) {
      float2 p = pack[j];
      acc += p.x * tab[__float_as_int(p.y) * 64 + lane];
    }
    agg[i * 64 + lane] = acc;
  }
}

// ===================== big-N tiled GEMM (128 rows x 64 cols, K=64) =====================
template <bool PRE, bool EB, bool PERG, bool BF16>
__global__ __launch_bounds__(256, 3) void gemm_big(
    const float* __restrict__ X, const float* __restrict__ Wg,
    const float* __restrict__ bias, const float* __restrict__ pa, const float* __restrict__ pb,
    const float* __restrict__ perg, float* __restrict__ Yf, u16* __restrict__ Ybf,
    float* __restrict__ stats, int sqoff) {
  __shared__ float xs[128 * 68];
  __shared__ float wt[64 * 68];
  __shared__ float sstat[128];
  int t = threadIdx.x, cg = t & 7, rg = t >> 3;
  for (int idx = t; idx < 4096; idx += 256) {
    int oc = idx >> 6, k = idx & 63;
    wt[k * 68 + oc] = Wg[idx];
  }
  float sS[8], sQ[8];
#pragma unroll
  for (int j = 0; j < 8; j++) { sS[j] = 0.f; sQ[j] = 0.f; }
  float bb[8];
  {
    float4 b0 = *(const float4*)&bias[cg * 8];
    float4 b1 = *(const float4*)&bias[cg * 8 + 4];
    bb[0] = b0.x; bb[1] = b0.y; bb[2] = b0.z; bb[3] = b0.w;
    bb[4] = b1.x; bb[5] = b1.y; bb[6] = b1.z; bb[7] = b1.w;
  }
  for (int tile = blockIdx.x; tile < NTILES; tile += gridDim.x) {
    int R0 = tile * 128;
    __syncthreads();
#pragma unroll
    for (int m = 0; m < 8; m++) {
      int f = m * 256 + t;
      int r = f >> 4, c4 = (f & 15) * 4;
      float4 v = *(const float4*)&X[(size_t)(R0 + r) * 64 + c4];
      if (PRE) {
        float4 A = *(const float4*)&pa[c4];
        float4 Bv;
        if (EB) { int b = (R0 + r) / Gn; Bv = *(const float4*)&pb[b * 64 + c4]; }
        else Bv = *(const float4*)&pb[c4];
        v.x = fmaxf(fmaf(A.x, v.x, Bv.x), 0.f);
        v.y = fmaxf(fmaf(A.y, v.y, Bv.y), 0.f);
        v.z = fmaxf(fmaf(A.z, v.z, Bv.z), 0.f);
        v.w = fmaxf(fmaf(A.w, v.w, Bv.w), 0.f);
      }
      *(float4*)&xs[r * 68 + c4] = v;
    }
    __syncthreads();
    float acc[4][8];
#pragma unroll
    for (int i = 0; i < 4; i++)
#pragma unroll
      for (int j = 0; j < 8; j++) acc[i][j] = 0.f;
#pragma unroll
    for (int kc = 0; kc < 16; kc++) {
      float4 x0 = *(const float4*)&xs[(rg * 4 + 0) * 68 + kc * 4];
      float4 x1 = *(const float4*)&xs[(rg * 4 + 1) * 68 + kc * 4];
      float4 x2 = *(const float4*)&xs[(rg * 4 + 2) * 68 + kc * 4];
      float4 x3 = *(const float4*)&xs[(rg * 4 + 3) * 68 + kc * 4];
#pragma unroll
      for (int kk = 0; kk < 4; kk++) {
        const float* wr = &wt[(kc * 4 + kk) * 68 + cg * 8];
        float4 w0 = *(const float4*)wr;
        float4 w1 = *(const float4*)(wr + 4);
        float wv[8] = {w0.x, w0.y, w0.z, w0.w, w1.x, w1.y, w1.z, w1.w};
        float a0 = XC(x0, kk), a1 = XC(x1, kk), a2 = XC(x2, kk), a3 = XC(x3, kk);
#pragma unroll
        for (int j = 0; j < 8; j++) {
          acc[0][j] = fmaf(a0, wv[j], acc[0][j]);
          acc[1][j] = fmaf(a1, wv[j], acc[1][j]);
          acc[2][j] = fmaf(a2, wv[j], acc[2][j]);
          acc[3][j] = fmaf(a3, wv[j], acc[3][j]);
        }
      }
    }
#pragma unroll
    for (int i = 0; i < 4; i++) {
      int grow = R0 + rg * 4 + i;
      float v[8];
#pragma unroll
      for (int j = 0; j < 8; j++) v[j] = acc[i][j] + bb[j];
      if (PERG) {
        int qr = grow % Gn;
        float4 q0 = *(const float4*)&perg[(size_t)qr * 64 + cg * 8];
        float4 q1 = *(const float4*)&perg[(size_t)qr * 64 + cg * 8 + 4];
        v[0] += q0.x; v[1] += q0.y; v[2] += q0.z; v[3] += q0.w;
        v[4] += q1.x; v[5] += q1.y; v[6] += q1.z; v[7] += q1.w;
      }
#pragma unroll
      for (int j = 0; j < 8; j++) { sS[j] += v[j]; sQ[j] += v[j] * v[j]; }
      if (BF16) {
        uint4 o;
        o.x = (u32)f2bf(v[0]) | ((u32)f2bf(v[1]) << 16);
        o.y = (u32)f2bf(v[2]) | ((u32)f2bf(v[3]) << 16);
        o.z = (u32)f2bf(v[4]) | ((u32)f2bf(v[5]) << 16);
        o.w = (u32)f2bf(v[6]) | ((u32)f2bf(v[7]) << 16);
        *(uint4*)&Ybf[(size_t)grow * 128 + cg * 8] = o;
      } else {
        float4 o0 = make_float4(v[0], v[1], v[2], v[3]);
        float4 o1 = make_float4(v[4], v[5], v[6], v[7]);
        *(float4*)&Yf[(size_t)grow * 64 + cg * 8] = o0;
        *(float4*)&Yf[(size_t)grow * 64 + cg * 8 + 4] = o1;
      }
    }
  }
  __syncthreads();
  for (int idx = t; idx < 128; idx += 256) sstat[idx] = 0.f;
  __syncthreads();
#pragma unroll
  for (int j = 0; j < 8; j++) {
    atomicAdd(&sstat[cg * 8 + j], sS[j]);
    atomicAdd(&sstat[64 + cg * 8 + j], sQ[j]);
  }
  __syncthreads();
  for (int idx = t; idx < 64; idx += 256) {
    atomicAdd(&stats[idx], sstat[idx]);
    atomicAdd(&stats[sqoff + idx], sstat[64 + idx]);
  }
}

// k11: r2 = relu(a4*r1+b4) @ W2^T + b2 ; K=128 (two staged halves), r1 in bf16 pitch 128
__global__ __launch_bounds__(256, 3) void gemm_k11(
    const u16* __restrict__ Xbf, const float* __restrict__ W2,
    const float* __restrict__ bias, const float* __restrict__ a4, const float* __restrict__ b4,
    float* __restrict__ Y, float* __restrict__ stats) {
  __shared__ float xs[128 * 68];
  __shared__ float wt[64 * 68];
  __shared__ float sstat[128];
  int t = threadIdx.x, cg = t & 7, rg = t >> 3;
  float sS[8], sQ[8];
#pragma unroll
  for (int j = 0; j < 8; j++) { sS[j] = 0.f; sQ[j] = 0.f; }
  float bb[8];
  {
    float4 b0 = *(const float4*)&bias[cg * 8];
    float4 b1 = *(const float4*)&bias[cg * 8 + 4];
    bb[0] = b0.x; bb[1] = b0.y; bb[2] = b0.z; bb[3] = b0.w;
    bb[4] = b1.x; bb[5] = b1.y; bb[6] = b1.z; bb[7] = b1.w;
  }
  for (int tile = blockIdx.x; tile < NTILES; tile += gridDim.x) {
    int R0 = tile * 128;
    float acc[4][8];
#pragma unroll
    for (int i = 0; i < 4; i++)
#pragma unroll
      for (int j = 0; j < 8; j++) acc[i][j] = 0.f;
    for (int hh = 0; hh < 2; hh++) {
      __syncthreads();
      for (int idx = t; idx < 4096; idx += 256) {
        int oc = idx >> 6, kl = idx & 63;
        wt[kl * 68 + oc] = W2[oc * 128 + hh * 64 + kl];
      }
#pragma unroll
      for (int m = 0; m < 4; m++) {
        int f = m * 256 + t;
        int r = f >> 3, ch = f & 7;
        const uint4* p = (const uint4*)&Xbf[(size_t)(R0 + r) * 128 + hh * 64 + ch * 8];
        uint4 u = *p;
        int kb = hh * 64 + ch * 8;
        float4 A0 = *(const float4*)&a4[kb];
        float4 A1 = *(const float4*)&a4[kb + 4];
        float4 B0 = *(const float4*)&b4[kb];
        float4 B1 = *(const float4*)&b4[kb + 4];
        float4 v0, v1;
        v0.x = fmaxf(fmaf(A0.x, bflo(u.x), B0.x), 0.f);
        v0.y = fmaxf(fmaf(A0.y, bfhi(u.x), B0.y), 0.f);
        v0.z = fmaxf(fmaf(A0.z, bflo(u.y), B0.z), 0.f);
        v0.w = fmaxf(fmaf(A0.w, bfhi(u.y), B0.w), 0.f);
        v1.x = fmaxf(fmaf(A1.x, bflo(u.z), B1.x), 0.f);
        v1.y = fmaxf(fmaf(A1.y, bfhi(u.z), B1.y), 0.f);
        v1.z = fmaxf(fmaf(A1.z, bflo(u.w), B1.z), 0.f);
        v1.w = fmaxf(fmaf(A1.w, bfhi(u.w), B1.w), 0.f);
        *(float4*)&xs[r * 68 + ch * 8] = v0;
        *(float4*)&xs[r * 68 + ch * 8 + 4] = v1;
      }
      __syncthreads();
#pragma unroll
      for (int kc = 0; kc < 16; kc++) {
        float4 x0 = *(const float4*)&xs[(rg * 4 + 0) * 68 + kc * 4];
        float4 x1 = *(const float4*)&xs[(rg * 4 + 1) * 68 + kc * 4];
        float4 x2 = *(const float4*)&xs[(rg * 4 + 2) * 68 + kc * 4];
        float4 x3 = *(const float4*)&xs[(rg * 4 + 3) * 68 + kc * 4];
#pragma unroll
        for (int kk = 0; kk < 4; kk++) {
          const float* wr = &wt[(kc * 4 + kk) * 68 + cg * 8];
          float4 w0 = *(const float4*)wr;
          float4 w1 = *(const float4*)(wr + 4);
          float wv[8] = {w0.x, w0.y, w0.z, w0.w, w1.x, w1.y, w1.z, w1.w};
          float a0 = XC(x0, kk), a1 = XC(x1, kk), a2 = XC(x2, kk), a3 = XC(x3, kk);
#pragma unroll
          for (int j = 0; j < 8; j++) {
            acc[0][j] = fmaf(a0, wv[j], acc[0][j]);
            acc[1][j] = fmaf(a1, wv[j], acc[1][j]);
            acc[2][j] = fmaf(a2, wv[j], acc[2][j]);
            acc[3][j] = fmaf(a3, wv[j], acc[3][j]);
          }
        }
      }
    }
#pragma unroll
    for (int i = 0; i < 4; i++) {
      int grow = R0 + rg * 4 + i;
      float v[8];
#pragma unroll
      for (int j = 0; j < 8; j++) {
        v[j] = acc[i][j] + bb[j];
        sS[j] += v[j]; sQ[j] += v[j] * v[j];
      }
      *(float4*)&Y[(size_t)grow * 64 + cg * 8] = make_float4(v[0], v[1], v[2], v[3]);
      *(float4*)&Y[(size_t)grow * 64 + cg * 8 + 4] = make_float4(v[4], v[5], v[6], v[7]);
    }
  }
  __syncthreads();
  for (int idx = t; idx < 128; idx += 256) sstat[idx] = 0.f;
  __syncthreads();
#pragma unroll
  for (int j = 0; j < 8; j++) {
    atomicAdd(&sstat[cg * 8 + j], sS[j]);
    atomicAdd(&sstat[64 + cg * 8 + j], sQ[j]);
  }
  __syncthreads();
  for (int idx = t; idx < 128; idx += 256) atomicAdd(&stats[idx], sstat[idx]);
}

// ===================== old small-size GEMM (kept for Pn/Gn paths) =====================
template <bool TWO, bool PRE, bool PRELU, bool PERG, bool STATS>
__global__ __launch_bounds__(256) void gemm64k(
    const float* __restrict__ X, const float* __restrict__ Xb,
    const float* __restrict__ Wm, const float* __restrict__ Wb,
    const float* __restrict__ bias,
    const float* __restrict__ pa, const float* __restrict__ pb,
    const float* __restrict__ perg, int tabrows,
    float* __restrict__ Y, float* __restrict__ stats, int rows) {
  __shared__ float xs[4096];
  __shared__ float red[4][64], red2[4][64];
  int t = threadIdx.x, lane = t & 63, wv = t >> 6;
  int ntiles = (rows + 63) >> 6;
  float psum = 0.f, psq = 0.f;
  float bv = bias ? bias[lane] : 0.f;
  for (int tile = blockIdx.x; tile < ntiles; tile += gridDim.x) {
    int base = tile * 64;
    float acc[16];
#pragma unroll
    for (int j = 0; j < 16; j++) acc[j] = bv;
    for (int pass = 0; pass < (TWO ? 2 : 1); pass++) {
      const float* Xp = pass ? Xb : X;
      const float* Wp = pass ? Wb : Wm;
      __syncthreads();
#pragma unroll
      for (int m = 0; m < 16; m++) {
        int fl = m * 256 + t;
        int r = fl >> 6, c = fl & 63;
        int gr = base + r;
        float v = (gr < rows) ? Xp[gr * 64 + c] : 0.f;
        if (PRE) { v = pa[c] * v + pb[c]; if (PRELU) v = fmaxf(v, 0.f); }
        xs[fl] = v;
      }
      __syncthreads();
      float Wreg[64];
#pragma unroll
      for (int k = 0; k < 64; k++) Wreg[k] = Wp[lane * 64 + k];
#pragma unroll
      for (int j = 0; j < 16; j++) {
        int r = wv * 16 + j;
        const float4* xr = (const float4*)&xs[r * 64];
        float a = acc[j];
#pragma unroll
        for (int kk = 0; kk < 16; kk++) {
          float4 xv = xr[kk];
          a = fmaf(xv.x, Wreg[4 * kk + 0], a);
          a = fmaf(xv.y, Wreg[4 * kk + 1], a);
          a = fmaf(xv.z, Wreg[4 * kk + 2], a);
          a = fmaf(xv.w, Wreg[4 * kk + 3], a);
        }
        acc[j] = a;
      }
    }
#pragma unroll
    for (int j = 0; j < 16; j++) {
      int gr = base + wv * 16 + j;
      if (gr < rows) {
        float v = acc[j];
        if (PERG) v += perg[(gr % tabrows) * 64 + lane];
        Y[gr * 64 + lane] = v;
        if (STATS) { psum += v; psq += v * v; }
      }
    }
  }
  if (STATS) {
    __syncthreads();
    red[wv][lane] = psum; red2[wv][lane] = psq;
    __syncthreads();
    if (wv == 0) {
      float s = red[0][lane] + red[1][lane] + red[2][lane] + red[3][lane];
      float q = red2[0][lane] + red2[1][lane] + red2[2][lane] + red2[3][lane];
      atomicAdd(&stats[lane], s);
      atomicAdd(&stats[64 + lane], q);
    }
  }
}

// stats of u = a2*T2 + b2 + emb[row/G]  (no store)
__global__ __launch_bounds__(256) void k7_kernel(const float* __restrict__ T2, const float* __restrict__ a2,
                                                 const float* __restrict__ b2, const float* __restrict__ emb,
                                                 float* __restrict__ stats, int rows, int rowsPerB) {
  int lane = threadIdx.x & 63, wv = threadIdx.x >> 6;
  __shared__ float red[4][64], red2[4][64];
  float ps = 0.f, pq = 0.f;
  int total = rows * 64;
  int stride = gridDim.x * 256;
  for (int idx = blockIdx.x * 256 + threadIdx.x; idx < total; idx += stride) {
    int i = idx >> 6, c = idx & 63;
    int b = i / rowsPerB;
    float v = a2[c] * T2[idx] + b2[c] + emb[b * 64 + c];
    ps += v; pq += v * v;
  }
  red[wv][lane] = ps; red2[wv][lane] = pq;
  __syncthreads();
  if (wv == 0) {
    float s = red[0][lane] + red[1][lane] + red[2][lane] + red[3][lane];
    float q = red2[0][lane] + red2[1][lane] + red2[2][lane] + red2[3][lane];
    atomicAdd(&stats[lane], s);
    atomicAdd(&stats[64 + lane], q);
  }
}

// finalize S3 and build folded vectors: Avec = a3*a2, e2[b] = a3*(b2+emb[b]) + b3
__global__ __launch_bounds__(256) void kfinS3e2(const float* __restrict__ stats, const float* __restrict__ g,
                                                const float* __restrict__ bt, const float* __restrict__ a2,
                                                const float* __restrict__ b2, const float* __restrict__ emb,
                                                float* __restrict__ Avec, float* __restrict__ e2, float invn) {
  __shared__ float a3s[64], b3s[64];
  int t = threadIdx.x;
  if (t < 64) {
    float mean = stats[t] * invn;
    float var = stats[64 + t] * invn - mean * mean;
    float sc = g[t] * rsqrtf(var + 1e-5f);
    float sh = bt[t] - mean * sc;
    a3s[t] = sc; b3s[t] = sh;
    Avec[t] = sc * a2[t];
  }
  __syncthreads();
  for (int idx = t; idx < 2048; idx += 256) {
    int c = idx & 63;
    e2[idx] = a3s[c] * (b2[c] + emb[idx]) + b3s[c];
  }
}

// w1[i] = dot(a5*R2[i]+b5, indv_w1[i%G]) + indv_b1[i%G]
__global__ __launch_bounds__(256) void k13_kernel(const float* __restrict__ R2, const float* __restrict__ a5,
                                                  const float* __restrict__ b5, const float* __restrict__ iw1,
                                                  const float* __restrict__ ib1, float* __restrict__ w1out,
                                                  int rows, int tabrows) {
  int t = blockIdx.x * 256 + threadIdx.x;
  int i = t >> 4, j = t & 15;
  if (i >= rows) return;
  int g = i % tabrows;
  float4 r = ((const float4*)R2)[i * 16 + j];
  float4 a = ((const float4*)a5)[j];
  float4 b = ((const float4*)b5)[j];
  float4 w = ((const float4*)iw1)[g * 16 + j];
  float p = (a.x * r.x + b.x) * w.x + (a.y * r.y + b.y) * w.y +
            (a.z * r.z + b.z) * w.z + (a.w * r.w + b.w) * w.w;
  for (int off = 8; off; off >>= 1) p += __shfl_xor(p, off, 64);
  if (j == 0) w1out[i] = p + ib1[g];
}

// init cgraw with bias
__global__ __launch_bounds__(256) void kinitcg(const float* __restrict__ cgb1, float* __restrict__ cgraw) {
  int idx = blockIdx.x * 256 + threadIdx.x;
  if (idx < Bn * 64) cgraw[idx] = cgb1[idx & 63];
}

// split-K GEMM: cgraw[b][col] += sum_{k in chunk} w1[b][k]*cgW1[col][k]
// grid = ceil(Gn/64) blocks; per-block K-chunk of 64
__global__ __launch_bounds__(256) void kcg1s(const float* __restrict__ w1, const float* __restrict__ cgW1,
                                             float* __restrict__ cgraw) {
  __shared__ float w1s[64 * 36];    // [k][row], pitch 36
  __shared__ float cgs[64 * 65];    // [k][col], pitch 65
  int t = threadIdx.x;
  int k0 = blockIdx.x * 64;
  int kmax = Gn - k0; if (kmax > 64) kmax = 64;
  // stage w1 chunk: idx over 32 rows x 64 k
  for (int idx = t; idx < 2048; idx += 256) {
    int row = idx >> 6, k = idx & 63;
    w1s[k * 36 + row] = (k < kmax) ? w1[row * Gn + k0 + k] : 0.f;
  }
  // stage cgW1 chunk: idx over 64 cols x 64 k
  for (int idx = t; idx < 4096; idx += 256) {
    int col = idx >> 6, k = idx & 63;
    cgs[k * 65 + col] = (k < kmax) ? cgW1[col * Gn + k0 + k] : 0.f;
  }
  __syncthreads();
  int col = t & 63, rg = t >> 6;  // 4 rowgroups x 8 rows
  float acc[8];
#pragma unroll
  for (int i = 0; i < 8; i++) acc[i] = 0.f;
  for (int k = 0; k < 64; k++) {
    float wk = cgs[k * 65 + col];
    const float* wr = &w1s[k * 36 + rg * 8];
    float4 r0 = *(const float4*)wr;       // broadcast reads (wave-uniform addr)
    float4 r1 = *(const float4*)(wr + 4);
    acc[0] = fmaf(r0.x, wk, acc[0]);
    acc[1] = fmaf(r0.y, wk, acc[1]);
    acc[2] = fmaf(r0.z, wk, acc[2]);
    acc[3] = fmaf(r0.w, wk, acc[3]);
    acc[4] = fmaf(r1.x, wk, acc[4]);
    acc[5] = fmaf(r1.y, wk, acc[5]);
    acc[6] = fmaf(r1.z, wk, acc[6]);
    acc[7] = fmaf(r1.w, wk, acc[7]);
  }
#pragma unroll
  for (int i = 0; i < 8; i++) atomicAdd(&cgraw[(rg * 8 + i) * 64 + col], acc[i]);
}

// single-block: cg2 = bn2(relu(bn1(cgraw)) @ W2^T + b2)   (BN over 32 rows)
__global__ __launch_bounds__(256) void kcg2(const float* __restrict__ cgraw, const float* __restrict__ g1,
                                            const float* __restrict__ bt1, const float* __restrict__ W2,
                                            const float* __restrict__ b2, const float* __restrict__ g2,
                                            const float* __restrict__ bt2, float* __restrict__ cg2out) {
  int t = threadIdx.x, c = t & 63, bg = t >> 6;
  __shared__ float hmid[2048], sred[4][64], qred[4][64], asc[64], bsh[64];
  float y[8];
  float ps = 0.f, pq = 0.f;
  for (int jb = 0; jb < 8; jb++) {
    int b = bg * 8 + jb;
    float v = cgraw[b * 64 + c];
    y[jb] = v; ps += v; pq += v * v;
  }
  sred[bg][c] = ps; qred[bg][c] = pq;
  __syncthreads();
  if (t < 64) {
    float s = sred[0][t] + sred[1][t] + sred[2][t] + sred[3][t];
    float q = qred[0][t] + qred[1][t] + qred[2][t] + qred[3][t];
    float mean = s * (1.f / 32.f), var = q * (1.f / 32.f) - mean * mean;
    float sc = g1[t] * rsqrtf(var + 1e-5f);
    asc[t] = sc; bsh[t] = bt1[t] - mean * sc;
  }
  __syncthreads();
  for (int jb = 0; jb < 8; jb++) { int b = bg * 8 + jb; hmid[b * 64 + c] = fmaxf(asc[c] * y[jb] + bsh[c], 0.f); }
  __syncthreads();
  ps = 0.f; pq = 0.f;
  for (int jb = 0; jb < 8; jb++) {
    int b = bg * 8 + jb;
    float a = b2[c];
    for (int k = 0; k < 64; k++) a += hmid[b * 64 + k] * W2[c * 64 + k];
    y[jb] = a; ps += a; pq += a * a;
  }
  sred[bg][c] = ps; qred[bg][c] = pq;
  __syncthreads();
  if (t < 64) {
    float s = sred[0][t] + sred[1][t] + sred[2][t] + sred[3][t];
    float q = qred[0][t] + qred[1][t] + qred[2][t] + qred[3][t];
    float mean = s * (1.f / 32.f), var = q * (1.f / 32.f) - mean * mean;
    float sc = g2[t] * rsqrtf(var + 1e-5f);
    asc[t] = sc; bsh[t] = bt2[t] - mean * sc;
  }
  __syncthreads();
  for (int jb = 0; jb < 8; jb++) { int b = bg * 8 + jb; cg2out[b * 64 + c] = asc[c] * y[jb] + bsh[c]; }
}

// single-block: emb = mlp3(pglob[pert_idx]) with BN over 32 rows
__global__ __launch_bounds__(256) void kemb(const float* __restrict__ m2, const float* __restrict__ aP2,
                                            const float* __restrict__ bP2, const int* __restrict__ pidx,
                                            const float* __restrict__ Wm, const float* __restrict__ bv,
                                            const float* __restrict__ gg, const float* __restrict__ btv,
                                            float* __restrict__ emb) {
  int t = threadIdx.x, c = t & 63, bg = t >> 6;
  __shared__ float xin[2048], hmid[2048], sred[4][64], qred[4][64], asc[64], bsh[64];
  for (int idx = t; idx < 2048; idx += 256) {
    int b = idx >> 6, cc = idx & 63;
    xin[idx] = aP2[cc] * m2[pidx[b] * 64 + cc] + bP2[cc];
  }
  __syncthreads();
  float y[8];
  float ps = 0.f, pq = 0.f;
  for (int jb = 0; jb < 8; jb++) {
    int b = bg * 8 + jb;
    float a = bv[c];
    for (int k = 0; k < 64; k++) a += xin[b * 64 + k] * Wm[c * 64 + k];
    y[jb] = a; ps += a; pq += a * a;
  }
  sred[bg][c] = ps; qred[bg][c] = pq;
  __syncthreads();
  if (t < 64) {
    float s = sred[0][t] + sred[1][t] + sred[2][t] + sred[3][t];
    float q = qred[0][t] + qred[1][t] + qred[2][t] + qred[3][t];
    float mean = s * (1.f / 32.f), var = q * (1.f / 32.f) - mean * mean;
    float sc = gg[t] * rsqrtf(var + 1e-5f);
    asc[t] = sc; bsh[t] = btv[t] - mean * sc;
  }
  __syncthreads();
  for (int jb = 0; jb < 8; jb++) { int b = bg * 8 + jb; hmid[b * 64 + c] = fmaxf(asc[c] * y[jb] + bsh[c], 0.f); }
  __syncthreads();
  ps = 0.f; pq = 0.f;
  for (int jb = 0; jb < 8; jb++) {
    int b = bg * 8 + jb;
    float a = bv[64 + c];
    for (int k = 0; k < 64; k++) a += hmid[b * 64 + k] * Wm[4096 + c * 64 + k];
    y[jb] = a; ps += a; pq += a * a;
  }
  sred[bg][c] = ps; qred[bg][c] = pq;
  __syncthreads();
  if (t < 64) {
    float s = sred[0][t] + sred[1][t] + sred[2][t] + sred[3][t];
    float q = qred[0][t] + qred[1][t] + qred[2][t] + qred[3][t];
    float mean = s * (1.f / 32.f), var = q * (1.f / 32.f) - mean * mean;
    float sc = gg[64 + t] * rsqrtf(var + 1e-5f);
    asc[t] = sc; bsh[t] = btv[64 + t] - mean * sc;
  }
  __syncthreads();
  for (int jb = 0; jb < 8; jb++) { int b = bg * 8 + jb; emb[b * 64 + c] = asc[c] * y[jb] + bsh[c]; }
}

// final: out[b][g] = w1*iw2[g][0] + dot(cg2[b], iw2[g][1:65]) + ib2[g] + x[b][g]
__global__ __launch_bounds__(256) void kfinal(const float* __restrict__ w1, const float* __restrict__ cg2,
                                              const float* __restrict__ iw2, const float* __restrict__ ib2,
                                              const float* __restrict__ x, float* __restrict__ out) {
  __shared__ float iws[64 * 65], cgs[2048];
  int t = threadIdx.x;
  int g0 = blockIdx.x * 64;
  for (int idx = t; idx < 64 * 65; idx += 256) {
    int gi = g0 * 65 + idx;
    iws[idx] = (gi < Gn * 65) ? iw2[gi] : 0.f;
  }
  for (int idx = t; idx < 2048; idx += 256) cgs[idx] = cg2[idx];
  __syncthreads();
  int gl = t & 63, bg = t >> 6;
  int g = g0 + gl;
  if (g >= Gn) return;
  float bias = ib2[g];
  for (int jb = 0; jb < 8; jb++) {
    int b = bg * 8 + jb;
    float acc = w1[b * Gn + g] * iws[gl * 65] + bias;
    for (int k = 0; k < 64; k++) acc += cgs[b * 64 + k] * iws[gl * 65 + 1 + k];
    out[b * Gn + g] = acc + x[b * Gn + g];
  }
}

extern "C" void kernel_launch(void* const* d_in, const int* in_sizes, int n_in,
                              void* d_out, int out_size, void* d_ws, size_t ws_size,
                              hipStream_t stream) {
  (void)in_sizes; (void)n_in; (void)out_size;
  if (ws_size < WS_FLOATS * sizeof(float)) return;

  const float* x        = (const float*)d_in[0];
  const int*   pert_idx = (const int*)d_in[1];
  const int*   ei_co    = (const int*)d_in[2];
  const float* w_co     = (const float*)d_in[3];
  const int*   ei_go    = (const int*)d_in[4];
  const float* w_go     = (const float*)d_in[5];
  const int*   ei_bg    = (const int*)d_in[6];
  const float* w_bg     = (const float*)d_in[7];
  const float* gene_tab = (const float*)d_in[8];
  const float* pos_tab  = (const float*)d_in[9];
  const float* go_tab   = (const float*)d_in[10];
  const float* bg_tab   = (const float*)d_in[11];
  const float* bn_g     = (const float*)d_in[12];
  const float* bn_b     = (const float*)d_in[13];
  const float* sg_W     = (const float*)d_in[14];
  const float* sg_b     = (const float*)d_in[15];
  const float* mlp_W    = (const float*)d_in[16];
  const float* mlp_b    = (const float*)d_in[17];
  const float* mlp_g    = (const float*)d_in[18];
  const float* mlp_bt   = (const float*)d_in[19];
  const float* rec_W1   = (const float*)d_in[20];
  const float* rec_b1   = (const float*)d_in[21];
  const float* rec_g1   = (const float*)d_in[22];
  const float* rec_bt1  = (const float*)d_in[23];
  const float* rec_W2   = (const float*)d_in[24];
  const float* rec_b2   = (const float*)d_in[25];
  const float* rec_g2   = (const float*)d_in[26];
  const float* rec_bt2  = (const float*)d_in[27];
  const float* indv_w1  = (const float*)d_in[28];
  const float* indv_b1  = (const float*)d_in[29];
  const float* cg_W1    = (const float*)d_in[30];
  const float* cg_b1    = (const float*)d_in[31];
  const float* cg_g1    = (const float*)d_in[32];
  const float* cg_bt1   = (const float*)d_in[33];
  const float* cg_W2    = (const float*)d_in[34];
  const float* cg_b2    = (const float*)d_in[35];
  const float* cg_g2    = (const float*)d_in[36];
  const float* cg_bt2   = (const float*)d_in[37];
  const float* indv_w2  = (const float*)d_in[38];
  const float* indv_b2  = (const float*)d_in[39];

  float* W = (float*)d_ws;
  float* buf0 = W + oBUF0;
  float* buf1 = W + oBUF1;

  // CSR scratch lives in buf1 (consumed before t1 writes buf1)
  int*    co_cnt  = (int*)(buf1);                    // 160001
  int*    co_fill = (int*)(buf1 + 160064);
  int*    sbsum   = (int*)(buf1 + 320128);           // <=256 block sums
  float2* co_pack = (float2*)(buf1 + 400000);        // 1.6M float2
  int*    go_cnt  = (int*)(buf1 + 3700000);
  int*    go_fill = (int*)(buf1 + 3710000);
  float2* go_pack = (float2*)(buf1 + 3720000);
  int*    bg_cnt  = (int*)(buf1 + 4000000);
  int*    bg_fill = (int*)(buf1 + 4010000);
  float2* bg_pack = (float2*)(buf1 + 4020000);

  // --- phase 0: zero stats, renorm tables, fold small matrices ---
  kzero<<<8, 256, 0, stream>>>(W, 2048);
  krenorm<<<160, 256, 0, stream>>>(gene_tab, W + oRG, W + oSG, Gn);
  krenorm<<<160, 256, 0, stream>>>(pos_tab, W + oRP, nullptr, Gn);
  krenorm<<<160, 256, 0, stream>>>(go_tab, W + oRGO, nullptr, Pn);
  krenorm<<<160, 256, 0, stream>>>(bg_tab, W + oRBG, nullptr, Pn);
  kfin<<<1, 64, 0, stream>>>(W + oSG, bn_g, bn_b, W + oAG, W + oBG, 64, 1.f / Gn);
  ksmallmat<<<1, 256, 0, stream>>>(mlp_W + 8192, sg_W, 0.2f, mlp_b + 128, sg_b, nullptr, 0.2f, W + oM, W + oCvec);
  ksmallmat<<<1, 256, 0, stream>>>(mlp_W, sg_W + 4096, 1.f, nullptr, nullptr, nullptr, 0.f, W + oM1, nullptr);
  ksmallmat<<<1, 256, 0, stream>>>(mlp_W, sg_W + 8192, 1.f, mlp_b, sg_b + 64, sg_b + 128, 1.f, W + oM2, W + oCcP);
  gemm64k<false, true, true, false, false><<<79, 256, 0, stream>>>(
      W + oRG, nullptr, mlp_W + 8192, nullptr, W + oCvec, W + oAG, W + oBG, nullptr, 0, W + oQ, nullptr, Gn);

  // --- co graph: CSR build + gather ---
  kfill<<<(Nn + 255) / 256, 256, 0, stream>>>(W + oDEG, 1.f, Nn);
  kzero<<<(160001 + 255) / 256, 256, 0, stream>>>((float*)co_cnt, 160001);
  khistdeg<<<(ECO + 255) / 256, 256, 0, stream>>>(ei_co + ECO, w_co, co_cnt, W + oDEG, ECO);
  kdinv<<<(Nn + 255) / 256, 256, 0, stream>>>(W + oDEG, Nn);
  kscan1<<<157, 256, 0, stream>>>(co_cnt, sbsum, Nn);
  kscan2<<<1, 256, 0, stream>>>(sbsum, 157, co_cnt + Nn);
  kscan3<<<157, 256, 0, stream>>>(co_cnt, sbsum, Nn);
  kzero<<<(Nn + 255) / 256, 256, 0, stream>>>((float*)co_fill, Nn);
  kfillcsr<<<(ECO + 255) / 256, 256, 0, stream>>>(ei_co, ei_co + ECO, w_co, W + oDEG,
                                                  co_cnt, co_fill, co_pack, ECO, Gn);
  kgather<<<2048, 256, 0, stream>>>(co_cnt, co_pack, W + oDEG, W + oRP, buf0, Nn, Gn);

  // --- go graph ---
  kfill<<<(Pn + 255) / 256, 256, 0, stream>>>(W + oDGO, 1.f, Pn);
  kzero<<<(5001 + 255) / 256, 256, 0, stream>>>((float*)go_cnt, 5001);
  khistdeg<<<(EGG + 255) / 256, 256, 0, stream>>>(ei_go + EGG, w_go, go_cnt, W + oDGO, EGG);
  kdinv<<<(Pn + 255) / 256, 256, 0, stream>>>(W + oDGO, Pn);
  kscan1<<<5, 256, 0, stream>>>(go_cnt, sbsum, Pn);
  kscan2<<<1, 256, 0, stream>>>(sbsum, 5, go_cnt + Pn);
  kscan3<<<5, 256, 0, stream>>>(go_cnt, sbsum, Pn);
  kzero<<<(Pn + 255) / 256, 256, 0, stream>>>((float*)go_fill, Pn);
  kfillcsr<<<(EGG + 255) / 256, 256, 0, stream>>>(ei_go, ei_go + EGG, w_go, W + oDGO,
                                                  go_cnt, go_fill, go_pack, EGG, Pn);
  kgather<<<512, 256, 0, stream>>>(go_cnt, go_pack, W + oDGO, W + oRGO, W + oAGO, Pn, Pn);

  // --- bg graph ---
  kfill<<<(Pn + 255) / 256, 256, 0, stream>>>(W + oDBG, 1.f, Pn);
  kzero<<<(5001 + 255) / 256, 256, 0, stream>>>((float*)bg_cnt, 5001);
  khistdeg<<<(EGG + 255) / 256, 256, 0, stream>>>(ei_bg + EGG, w_bg, bg_cnt, W + oDBG, EGG);
  kdinv<<<(Pn + 255) / 256, 256, 0, stream>>>(W + oDBG, Pn);
  kscan1<<<5, 256, 0, stream>>>(bg_cnt, sbsum, Pn);
  kscan2<<<1, 256, 0, stream>>>(sbsum, 5, bg_cnt + Pn);
  kscan3<<<5, 256, 0, stream>>>(bg_cnt, sbsum, Pn);
  kzero<<<(Pn + 255) / 256, 256, 0, stream>>>((float*)bg_fill, Pn);
  kfillcsr<<<(EGG + 255) / 256, 256, 0, stream>>>(ei_bg, ei_bg + EGG, w_bg, W + oDBG,
                                                  bg_cnt, bg_fill, bg_pack, EGG, Pn);
  kgather<<<512, 256, 0, stream>>>(bg_cnt, bg_pack, W + oDBG, W + oRBG, W + oABG, Pn, Pn);

  // --- pert path (Pn rows) ---
  gemm64k<true, false, false, false, true><<<79, 256, 0, stream>>>(
      W + oAGO, W + oABG, W + oM1, W + oM2, W + oCcP, nullptr, nullptr, nullptr, 0, W + oM1B, W + oSP1, Pn);
  kfin<<<1, 64, 0, stream>>>(W + oSP1, mlp_g, mlp_bt, W + oAP1, W + oBP1, 64, 1.f / Pn);
  gemm64k<false, true, true, false, true><<<79, 256, 0, stream>>>(
      W + oM1B, nullptr, mlp_W + 4096, nullptr, mlp_b + 64, W + oAP1, W + oBP1, nullptr, 0, W + oM2B, W + oSP2, Pn);
  kfin<<<1, 64, 0, stream>>>(W + oSP2, mlp_g + 64, mlp_bt + 64, W + oAP2, W + oBP2, 64, 1.f / Pn);
  kemb<<<1, 256, 0, stream>>>(W + oM2B, W + oAP2, W + oBP2, pert_idx,
                              mlp_W + 16384, mlp_b + 256, mlp_g + 256, mlp_bt + 256, W + oEMB);

  // --- main N pipeline ---
  gemm_big<false, false, true, false><<<512, 256, 0, stream>>>(
      buf0, W + oM, W + oZERO, nullptr, nullptr, W + oQ, buf1, nullptr, W + oS1, 64);
  kfin<<<1, 64, 0, stream>>>(W + oS1, mlp_g + 128, mlp_bt + 128, W + oA1, W + oB1, 64, 1.f / Nn);
  gemm_big<true, false, false, false><<<512, 256, 0, stream>>>(
      buf1, mlp_W + 12288, mlp_b + 192, W + oA1, W + oB1, nullptr, buf0, nullptr, W + oS2, 64);
  kfin<<<1, 64, 0, stream>>>(W + oS2, mlp_g + 192, mlp_bt + 192, W + oA2, W + oB2, 64, 1.f / Nn);
  k7_kernel<<<512, 256, 0, stream>>>(buf0, W + oA2, W + oB2, W + oEMB, W + oS3, Nn, Gn);
  kfinS3e2<<<1, 256, 0, stream>>>(W + oS3, bn_g + 64, bn_b + 64, W + oA2, W + oB2, W + oEMB,
                                  W + oAvec, W + oE2, 1.f / Nn);
  gemm_big<true, true, false, true><<<512, 256, 0, stream>>>(
      buf0, rec_W1, rec_b1, W + oAvec, W + oE2, nullptr, nullptr, (u16*)buf1, W + oS4, 128);
  gemm_big<true, true, false, true><<<512, 256, 0, stream>>>(
      buf0, rec_W1 + 4096, rec_b1 + 64, W + oAvec, W + oE2, nullptr, nullptr, (u16*)buf1 + 64, W + oS4 + 64, 128);
  kfin<<<2, 64, 0, stream>>>(W + oS4, rec_g1, rec_bt1, W + oA4, W + oB4, 128, 1.f / Nn);
  gemm_k11<<<512, 256, 0, stream>>>((const u16*)buf1, rec_W2, rec_b2, W + oA4, W + oB4, buf0, W + oS5);
  kfin<<<1, 64, 0, stream>>>(W + oS5, rec_g2, rec_bt2, W + oA5, W + oB5, 64, 1.f / Nn);
  k13_kernel<<<(Nn * 16 + 255) / 256, 256, 0, stream>>>(buf0, W + oA5, W + oB5, indv_w1, indv_b1, W + oW1, Nn, Gn);
  // cross-gene state: split-K GEMM with fp32 atomics into bias-initialized cgraw
  kinitcg<<<8, 256, 0, stream>>>(cg_b1, W + oCGRAW);
  kcg1s<<<(Gn + 63) / 64, 256, 0, stream>>>(W + oW1, cg_W1, W + oCGRAW);
  kcg2<<<1, 256, 0, stream>>>(W + oCGRAW, cg_g1, cg_bt1, cg_W2, cg_b2, cg_g2, cg_bt2, W + oCG2);
  kfinal<<<(Gn + 63) / 64, 256, 0, stream>>>(W + oW1, W + oCG2, indv_w2, indv_b2, x, (float*)d_out);
}

// Round 4
// 1045.138 us; speedup vs baseline: 4.4851x; 1.1505x over previous
//
#include <hip/hip_runtime.h>

typedef unsigned int u32;
typedef unsigned short u16;

// Problem constants (fixed by the reference)
constexpr int Gn  = 5000;     // genes
constexpr int Bn  = 32;       // batch graphs
constexpr int Pn  = 5000;     // perts
constexpr int Nn  = Bn * Gn;  // 160000
constexpr int ECO = 1600000;
constexpr int EGG = 100000;
constexpr int NTILES = Nn / 128;  // 1250, exact

// ---- workspace layout (float offsets) ----
constexpr int oS1 = 0, oS2 = 128, oS3 = 256, oS4 = 384, oS5 = 640, oSG = 768, oSP1 = 896, oSP2 = 1024;
constexpr int oZERO = 1536;  // stays zero (bias for t1)
constexpr int oA1 = 2048, oB1 = 2112, oA2 = 2176, oB2 = 2240;
constexpr int oA4 = 2304, oB4 = 2432;            // 128 each
constexpr int oA5 = 2560, oB5 = 2624;
constexpr int oAG = 2688, oBG = 2752;
constexpr int oAP1 = 2816, oBP1 = 2880, oAP2 = 2944, oBP2 = 3008;
constexpr int oAvec = 3072, oCvec = 3136, oCcP = 3200;
constexpr int oM  = 4096, oM1 = 8192, oM2 = 12288;
constexpr int oE2 = 16384, oEMB = 18432, oCGRAW = 20480, oCG2 = 22528;
constexpr int oRG  = 24576;
constexpr int oRP  = oRG  + Gn * 64;
constexpr int oQ   = oRP  + Gn * 64;
constexpr int oRGO = oQ   + Gn * 64;
constexpr int oRBG = oRGO + Pn * 64;
constexpr int oAGO = oRBG + Pn * 64;
constexpr int oABG = oAGO + Pn * 64;
constexpr int oM1B = oABG + Pn * 64;
constexpr int oM2B = oM1B + Pn * 64;
constexpr int oDGO = oM2B + Pn * 64;
constexpr int oDBG = oDGO + Pn;
constexpr int oDEG = oDBG + Pn;
constexpr int oW1  = oDEG + Nn;
constexpr int oBUF0 = oW1 + Nn;
constexpr int oBUF1 = oBUF0 + Nn * 64;
constexpr size_t WS_FLOATS = (size_t)oBUF1 + (size_t)Nn * 64;  // ~95 MB

__device__ inline u16 f2bf(float f) {
  u32 u = __float_as_uint(f);
  u = (u + 0x7fffu + ((u >> 16) & 1u)) >> 16;
  return (u16)u;
}
__device__ inline float bflo(u32 v) { return __uint_as_float(v << 16); }
__device__ inline float bfhi(u32 v) { return __uint_as_float(v & 0xffff0000u); }

#define XC(v, kk) ((kk) == 0 ? (v).x : (kk) == 1 ? (v).y : (kk) == 2 ? (v).z : (v).w)

__global__ __launch_bounds__(256) void kzero(float* p, int n) {
  int i = blockIdx.x * 256 + threadIdx.x;
  if (i < n) p[i] = 0.f;
}

// row-wise L2 renorm (norm clipped to <=1); optional column stats of the output
__global__ __launch_bounds__(256) void krenorm(const float* __restrict__ in, float* __restrict__ out,
                                               float* __restrict__ stats, int rows) {
  int lane = threadIdx.x & 63, wv = threadIdx.x >> 6;
  int gw = blockIdx.x * 4 + wv, nw = gridDim.x * 4;
  float ps = 0.f, pq = 0.f;
  for (int r = gw; r < rows; r += nw) {
    float v = in[r * 64 + lane];
    float sq = v * v;
    for (int off = 32; off; off >>= 1) sq += __shfl_xor(sq, off, 64);
    float nn = sqrtf(sq);
    float s = fminf(1.f, 1.f / fmaxf(nn, 1e-12f));
    float o = v * s;
    out[r * 64 + lane] = o;
    ps += o; pq += o * o;
  }
  if (!stats) return;
  __shared__ float red[4][64], red2[4][64];
  red[wv][lane] = ps; red2[wv][lane] = pq;
  __syncthreads();
  if (wv == 0) {
    float s = red[0][lane] + red[1][lane] + red[2][lane] + red[3][lane];
    float q = red2[0][lane] + red2[1][lane] + red2[2][lane] + red2[3][lane];
    atomicAdd(&stats[lane], s);
    atomicAdd(&stats[64 + lane], q);
  }
}

// finalize BN: a = g*rsqrt(var+eps), b = bt - mean*a
__global__ void kfin(const float* __restrict__ stats, const float* __restrict__ g,
                     const float* __restrict__ bt, float* __restrict__ a, float* __restrict__ b,
                     int cols, float invn) {
  int c = blockIdx.x * 64 + threadIdx.x;
  if (c >= cols) return;
  float mean = stats[c] * invn;
  float var = stats[cols + c] * invn - mean * mean;
  float sc = g[c] * rsqrtf(var + 1e-5f);
  a[c] = sc;
  b[c] = bt[c] - mean * sc;
}

// Mout = alpha * A @ Bm  (64x64 each); optional cvec = bias + beta * A @ (bv1+bv2)
__global__ __launch_bounds__(256) void ksmallmat(const float* __restrict__ A, const float* __restrict__ Bm,
                                                 float alpha, const float* __restrict__ bias,
                                                 const float* __restrict__ bv1, const float* __restrict__ bv2,
                                                 float beta, float* __restrict__ Mout, float* __restrict__ cvec) {
  __shared__ float As[4096], Bs[4096];
  int t = threadIdx.x;
  for (int m = 0; m < 16; m++) { As[m * 256 + t] = A[m * 256 + t]; Bs[m * 256 + t] = Bm[m * 256 + t]; }
  __syncthreads();
  int j = t & 63, ig = t >> 6;
  for (int ii = 0; ii < 16; ii++) {
    int i = ig * 16 + ii;
    float acc = 0.f;
    for (int k = 0; k < 64; k++) acc += As[i * 64 + k] * Bs[k * 64 + j];
    Mout[i * 64 + j] = alpha * acc;
  }
  if (cvec && t < 64) {
    float acc = bias ? bias[t] : 0.f;
    for (int k = 0; k < 64; k++) {
      float bb = (bv1 ? bv1[k] : 0.f) + (bv2 ? bv2[k] : 0.f);
      acc += beta * As[t * 64 + k] * bb;
    }
    cvec[t] = acc;
  }
}

// histogram with ticket: one atomic per edge
__global__ __launch_bounds__(256) void khist(const int* __restrict__ dst, int* __restrict__ cnt,
                                             int* __restrict__ ticket, int E) {
  int e = blockIdx.x * 256 + threadIdx.x;
  if (e < E) ticket[e] = atomicAdd(&cnt[dst[e]], 1);
}

// ---- block scan (1024 elems/block) ----
__global__ __launch_bounds__(256) void kscan1(const int* __restrict__ cnt, int* __restrict__ bsum, int n) {
  __shared__ int sh[256];
  int b = blockIdx.x, t = threadIdx.x;
  int base = b * 1024 + t * 4;
  int s = 0;
#pragma unroll
  for (int j = 0; j < 4; j++) { int i = base + j; if (i < n) s += cnt[i]; }
  sh[t] = s; __syncthreads();
  for (int d = 128; d; d >>= 1) { if (t < d) sh[t] += sh[t + d]; __syncthreads(); }
  if (t == 0) bsum[b] = sh[0];
}
__global__ __launch_bounds__(256) void kscan2(int* bsum, int nb, int* off_n) {
  __shared__ int sh[256];
  int t = threadIdx.x;
  int v = (t < nb) ? bsum[t] : 0;
  sh[t] = v;
  __syncthreads();
  for (int d = 1; d < 256; d <<= 1) {
    int u = (t >= d) ? sh[t - d] : 0;
    __syncthreads();
    sh[t] += u;
    __syncthreads();
  }
  if (t < nb) bsum[t] = sh[t] - v;  // exclusive
  if (t == nb - 1 && off_n) *off_n = sh[t];
}
__global__ __launch_bounds__(256) void kscan3(int* __restrict__ cnt, const int* __restrict__ bsum, int n) {
  __shared__ int sh[256];
  int b = blockIdx.x, t = threadIdx.x;
  int base = b * 1024 + t * 4;
  int c0 = (base + 0 < n) ? cnt[base + 0] : 0;
  int c1 = (base + 1 < n) ? cnt[base + 1] : 0;
  int c2 = (base + 2 < n) ? cnt[base + 2] : 0;
  int c3 = (base + 3 < n) ? cnt[base + 3] : 0;
  int tot = c0 + c1 + c2 + c3;
  sh[t] = tot; __syncthreads();
  for (int d = 1; d < 256; d <<= 1) {
    int v = (t >= d) ? sh[t - d] : 0;
    __syncthreads();
    sh[t] += v;
    __syncthreads();
  }
  int excl = sh[t] - tot + bsum[b];
  if (base + 0 < n) cnt[base + 0] = excl;
  if (base + 1 < n) cnt[base + 1] = excl + c0;
  if (base + 2 < n) cnt[base + 2] = excl + c0 + c1;
  if (base + 3 < n) cnt[base + 3] = excl + c0 + c1 + c2;
}

// atomic-free CSR fill using tickets: pack[off[d]+ticket] = (w, src_full)
__global__ __launch_bounds__(256) void kfillt(const int* __restrict__ src, const int* __restrict__ dst,
                                              const float* __restrict__ w, const int* __restrict__ off,
                                              const int* __restrict__ ticket, float2* __restrict__ pack, int E) {
  int e = blockIdx.x * 256 + threadIdx.x;
  if (e >= E) return;
  int d = dst[e];
  int pos = off[d] + ticket[e];
  pack[pos] = make_float2(w[e], __int_as_float(src[e]));
}

// per-row: deg = 1 + sum(w) over CSR row; dinv = rsqrt(deg)
__global__ __launch_bounds__(256) void kdinvrow(const int* __restrict__ off, const float2* __restrict__ pack,
                                                float* __restrict__ dinv, int n) {
  int i = blockIdx.x * 256 + threadIdx.x;
  if (i >= n) return;
  int b0 = off[i], b1 = off[i + 1];
  float s = 1.f;
  for (int j = b0; j < b1; j++) s += pack[j].x;
  dinv[i] = rsqrtf(s);
}

// wave-per-row CSR gather: agg[i] = dinv[i]^2*tab[i%5000] + sum_j dinv[i]*w_j*dinv[s_j]*tab[s_j%5000]
template <bool OBF>
__global__ __launch_bounds__(256) void kgather(const int* __restrict__ off, const float2* __restrict__ pack,
                                               const float* __restrict__ dinv, const float* __restrict__ tab,
                                               float* __restrict__ aggf, u16* __restrict__ aggb, int n) {
  int lane = threadIdx.x & 63;
  int wv = blockIdx.x * 4 + (threadIdx.x >> 6);
  int nw = gridDim.x * 4;
  for (int i = wv; i < n; i += nw) {
    int b0 = off[i], b1 = off[i + 1];
    float di = dinv[i];
    int tr = i % Gn;
    float acc = di * di * tab[tr * 64 + lane];
    int j = b0;
    for (; j + 1 < b1; j += 2) {
      float2 p0 = pack[j], p1 = pack[j + 1];
      int s0 = __float_as_int(p0.y), s1 = __float_as_int(p1.y);
      float c0 = di * p0.x * dinv[s0];
      float c1 = di * p1.x * dinv[s1];
      acc += c0 * tab[(s0 % Gn) * 64 + lane];
      acc += c1 * tab[(s1 % Gn) * 64 + lane];
    }
    if (j < b1) {
      float2 p = pack[j];
      int s = __float_as_int(p.y);
      acc += di * p.x * dinv[s] * tab[(s % Gn) * 64 + lane];
    }
    if (OBF) aggb[(size_t)i * 64 + lane] = f2bf(acc);
    else aggf[(size_t)i * 64 + lane] = acc;
  }
}

// ===================== big-N tiled GEMM (128 rows x 64 cols, K=64), bf16 in/out =====================
template <bool PRE, bool EB, bool PERG>
__global__ __launch_bounds__(256, 3) void gemm_big(
    const u16* __restrict__ Xb, const float* __restrict__ Wg,
    const float* __restrict__ bias, const float* __restrict__ pa, const float* __restrict__ pb,
    const float* __restrict__ perg, u16* __restrict__ Ybf, int obpitch,
    float* __restrict__ stats, int sqoff) {
  __shared__ float xs[128 * 68];
  __shared__ float wt[64 * 68];
  __shared__ float sstat[128];
  int t = threadIdx.x, cg = t & 7, rg = t >> 3;
  for (int idx = t; idx < 4096; idx += 256) {
    int oc = idx >> 6, k = idx & 63;
    wt[k * 68 + oc] = Wg[idx];
  }
  float sS[8], sQ[8];
#pragma unroll
  for (int j = 0; j < 8; j++) { sS[j] = 0.f; sQ[j] = 0.f; }
  float bb[8];
  {
    float4 b0 = *(const float4*)&bias[cg * 8];
    float4 b1 = *(const float4*)&bias[cg * 8 + 4];
    bb[0] = b0.x; bb[1] = b0.y; bb[2] = b0.z; bb[3] = b0.w;
    bb[4] = b1.x; bb[5] = b1.y; bb[6] = b1.z; bb[7] = b1.w;
  }
  for (int tile = blockIdx.x; tile < NTILES; tile += gridDim.x) {
    int R0 = tile * 128;
    __syncthreads();
#pragma unroll
    for (int m = 0; m < 4; m++) {
      int f = m * 256 + t;
      int r = f >> 3, c8 = (f & 7) * 8;
      uint4 u = *(const uint4*)&Xb[(size_t)(R0 + r) * 64 + c8];
      float v[8] = {bflo(u.x), bfhi(u.x), bflo(u.y), bfhi(u.y),
                    bflo(u.z), bfhi(u.z), bflo(u.w), bfhi(u.w)};
      if (PRE) {
        float4 A0 = *(const float4*)&pa[c8];
        float4 A1 = *(const float4*)&pa[c8 + 4];
        const float* pbb = EB ? &pb[((R0 + r) / Gn) * 64] : pb;
        float4 B0 = *(const float4*)&pbb[c8];
        float4 B1 = *(const float4*)&pbb[c8 + 4];
        v[0] = fmaxf(fmaf(A0.x, v[0], B0.x), 0.f);
        v[1] = fmaxf(fmaf(A0.y, v[1], B0.y), 0.f);
        v[2] = fmaxf(fmaf(A0.z, v[2], B0.z), 0.f);
        v[3] = fmaxf(fmaf(A0.w, v[3], B0.w), 0.f);
        v[4] = fmaxf(fmaf(A1.x, v[4], B1.x), 0.f);
        v[5] = fmaxf(fmaf(A1.y, v[5], B1.y), 0.f);
        v[6] = fmaxf(fmaf(A1.z, v[6], B1.z), 0.f);
        v[7] = fmaxf(fmaf(A1.w, v[7], B1.w), 0.f);
      }
      *(float4*)&xs[r * 68 + c8] = make_float4(v[0], v[1], v[2], v[3]);
      *(float4*)&xs[r * 68 + c8 + 4] = make_float4(v[4], v[5], v[6], v[7]);
    }
    __syncthreads();
    float acc[4][8];
#pragma unroll
    for (int i = 0; i < 4; i++)
#pragma unroll
      for (int j = 0; j < 8; j++) acc[i][j] = 0.f;
#pragma unroll
    for (int kc = 0; kc < 16; kc++) {
      float4 x0 = *(const float4*)&xs[(rg * 4 + 0) * 68 + kc * 4];
      float4 x1 = *(const float4*)&xs[(rg * 4 + 1) * 68 + kc * 4];
      float4 x2 = *(const float4*)&xs[(rg * 4 + 2) * 68 + kc * 4];
      float4 x3 = *(const float4*)&xs[(rg * 4 + 3) * 68 + kc * 4];
#pragma unroll
      for (int kk = 0; kk < 4; kk++) {
        const float* wr = &wt[(kc * 4 + kk) * 68 + cg * 8];
        float4 w0 = *(const float4*)wr;
        float4 w1 = *(const float4*)(wr + 4);
        float wv[8] = {w0.x, w0.y, w0.z, w0.w, w1.x, w1.y, w1.z, w1.w};
        float a0 = XC(x0, kk), a1 = XC(x1, kk), a2 = XC(x2, kk), a3 = XC(x3, kk);
#pragma unroll
        for (int j = 0; j < 8; j++) {
          acc[0][j] = fmaf(a0, wv[j], acc[0][j]);
          acc[1][j] = fmaf(a1, wv[j], acc[1][j]);
          acc[2][j] = fmaf(a2, wv[j], acc[2][j]);
          acc[3][j] = fmaf(a3, wv[j], acc[3][j]);
        }
      }
    }
#pragma unroll
    for (int i = 0; i < 4; i++) {
      int grow = R0 + rg * 4 + i;
      float v[8];
#pragma unroll
      for (int j = 0; j < 8; j++) v[j] = acc[i][j] + bb[j];
      if (PERG) {
        int qr = grow % Gn;
        float4 q0 = *(const float4*)&perg[(size_t)qr * 64 + cg * 8];
        float4 q1 = *(const float4*)&perg[(size_t)qr * 64 + cg * 8 + 4];
        v[0] += q0.x; v[1] += q0.y; v[2] += q0.z; v[3] += q0.w;
        v[4] += q1.x; v[5] += q1.y; v[6] += q1.z; v[7] += q1.w;
      }
#pragma unroll
      for (int j = 0; j < 8; j++) { sS[j] += v[j]; sQ[j] += v[j] * v[j]; }
      uint4 o;
      o.x = (u32)f2bf(v[0]) | ((u32)f2bf(v[1]) << 16);
      o.y = (u32)f2bf(v[2]) | ((u32)f2bf(v[3]) << 16);
      o.z = (u32)f2bf(v[4]) | ((u32)f2bf(v[5]) << 16);
      o.w = (u32)f2bf(v[6]) | ((u32)f2bf(v[7]) << 16);
      *(uint4*)&Ybf[(size_t)grow * obpitch + cg * 8] = o;
    }
  }
  __syncthreads();
  for (int idx = t; idx < 128; idx += 256) sstat[idx] = 0.f;
  __syncthreads();
#pragma unroll
  for (int j = 0; j < 8; j++) {
    atomicAdd(&sstat[cg * 8 + j], sS[j]);
    atomicAdd(&sstat[64 + cg * 8 + j], sQ[j]);
  }
  __syncthreads();
  for (int idx = t; idx < 64; idx += 256) {
    atomicAdd(&stats[idx], sstat[idx]);
    atomicAdd(&stats[sqoff + idx], sstat[64 + idx]);
  }
}

// k11: r2 = relu(a4*r1+b4) @ W2^T + b2 ; K=128 (two staged halves), r1 bf16 pitch 128, out bf16 pitch 64
__global__ __launch_bounds__(256, 3) void gemm_k11(
    const u16* __restrict__ Xbf, const float* __restrict__ W2,
    const float* __restrict__ bias, const float* __restrict__ a4, const float* __restrict__ b4,
    u16* __restrict__ Ybf, float* __restrict__ stats) {
  __shared__ float xs[128 * 68];
  __shared__ float wt[64 * 68];
  __shared__ float sstat[128];
  int t = threadIdx.x, cg = t & 7, rg = t >> 3;
  float sS[8], sQ[8];
#pragma unroll
  for (int j = 0; j < 8; j++) { sS[j] = 0.f; sQ[j] = 0.f; }
  float bb[8];
  {
    float4 b0 = *(const float4*)&bias[cg * 8];
    float4 b1 = *(const float4*)&bias[cg * 8 + 4];
    bb[0] = b0.x; bb[1] = b0.y; bb[2] = b0.z; bb[3] = b0.w;
    bb[4] = b1.x; bb[5] = b1.y; bb[6] = b1.z; bb[7] = b1.w;
  }
  for (int tile = blockIdx.x; tile < NTILES; tile += gridDim.x) {
    int R0 = tile * 128;
    float acc[4][8];
#pragma unroll
    for (int i = 0; i < 4; i++)
#pragma unroll
      for (int j = 0; j < 8; j++) acc[i][j] = 0.f;
    for (int hh = 0; hh < 2; hh++) {
      __syncthreads();
      for (int idx = t; idx < 4096; idx += 256) {
        int oc = idx >> 6, kl = idx & 63;
        wt[kl * 68 + oc] = W2[oc * 128 + hh * 64 + kl];
      }
#pragma unroll
      for (int m = 0; m < 4; m++) {
        int f = m * 256 + t;
        int r = f >> 3, ch = f & 7;
        const uint4* p = (const uint4*)&Xbf[(size_t)(R0 + r) * 128 + hh * 64 + ch * 8];
        uint4 u = *p;
        int kb = hh * 64 + ch * 8;
        float4 A0 = *(const float4*)&a4[kb];
        float4 A1 = *(const float4*)&a4[kb + 4];
        float4 B0 = *(const float4*)&b4[kb];
        float4 B1 = *(const float4*)&b4[kb + 4];
        float4 v0, v1;
        v0.x = fmaxf(fmaf(A0.x, bflo(u.x), B0.x), 0.f);
        v0.y = fmaxf(fmaf(A0.y, bfhi(u.x), B0.y), 0.f);
        v0.z = fmaxf(fmaf(A0.z, bflo(u.y), B0.z), 0.f);
        v0.w = fmaxf(fmaf(A0.w, bfhi(u.y), B0.w), 0.f);
        v1.x = fmaxf(fmaf(A1.x, bflo(u.z), B1.x), 0.f);
        v1.y = fmaxf(fmaf(A1.y, bfhi(u.z), B1.y), 0.f);
        v1.z = fmaxf(fmaf(A1.z, bflo(u.w), B1.z), 0.f);
        v1.w = fmaxf(fmaf(A1.w, bfhi(u.w), B1.w), 0.f);
        *(float4*)&xs[r * 68 + ch * 8] = v0;
        *(float4*)&xs[r * 68 + ch * 8 + 4] = v1;
      }
      __syncthreads();
#pragma unroll
      for (int kc = 0; kc < 16; kc++) {
        float4 x0 = *(const float4*)&xs[(rg * 4 + 0) * 68 + kc * 4];
        float4 x1 = *(const float4*)&xs[(rg * 4 + 1) * 68 + kc * 4];
        float4 x2 = *(const float4*)&xs[(rg * 4 + 2) * 68 + kc * 4];
        float4 x3 = *(const float4*)&xs[(rg * 4 + 3) * 68 + kc * 4];
#pragma unroll
        for (int kk = 0; kk < 4; kk++) {
          const float* wr = &wt[(kc * 4 + kk) * 68 + cg * 8];
          float4 w0 = *(const float4*)wr;
          float4 w1 = *(const float4*)(wr + 4);
          float wv[8] = {w0.x, w0.y, w0.z, w0.w, w1.x, w1.y, w1.z, w1.w};
          float a0 = XC(x0, kk), a1 = XC(x1, kk), a2 = XC(x2, kk), a3 = XC(x3, kk);
#pragma unroll
          for (int j = 0; j < 8; j++) {
            acc[0][j] = fmaf(a0, wv[j], acc[0][j]);
            acc[1][j] = fmaf(a1, wv[j], acc[1][j]);
            acc[2][j] = fmaf(a2, wv[j], acc[2][j]);
            acc[3][j] = fmaf(a3, wv[j], acc[3][j]);
          }
        }
      }
    }
#pragma unroll
    for (int i = 0; i < 4; i++) {
      int grow = R0 + rg * 4 + i;
      float v[8];
#pragma unroll
      for (int j = 0; j < 8; j++) {
        v[j] = acc[i][j] + bb[j];
        sS[j] += v[j]; sQ[j] += v[j] * v[j];
      }
      uint4 o;
      o.x = (u32)f2bf(v[0]) | ((u32)f2bf(v[1]) << 16);
      o.y = (u32)f2bf(v[2]) | ((u32)f2bf(v[3]) << 16);
      o.z = (u32)f2bf(v[4]) | ((u32)f2bf(v[5]) << 16);
      o.w = (u32)f2bf(v[6]) | ((u32)f2bf(v[7]) << 16);
      *(uint4*)&Ybf[(size_t)grow * 64 + cg * 8] = o;
    }
  }
  __syncthreads();
  for (int idx = t; idx < 128; idx += 256) sstat[idx] = 0.f;
  __syncthreads();
#pragma unroll
  for (int j = 0; j < 8; j++) {
    atomicAdd(&sstat[cg * 8 + j], sS[j]);
    atomicAdd(&sstat[64 + cg * 8 + j], sQ[j]);
  }
  __syncthreads();
  for (int idx = t; idx < 128; idx += 256) atomicAdd(&stats[idx], sstat[idx]);
}

// ===================== small GEMM (Pn/Gn paths, fp32) =====================
template <bool TWO, bool PRE, bool PRELU, bool PERG, bool STATS>
__global__ __launch_bounds__(256) void gemm64k(
    const float* __restrict__ X, const float* __restrict__ Xb,
    const float* __restrict__ Wm, const float* __restrict__ Wb,
    const float* __restrict__ bias,
    const float* __restrict__ pa, const float* __restrict__ pb,
    const float* __restrict__ perg, int tabrows,
    float* __restrict__ Y, float* __restrict__ stats, int rows) {
  __shared__ float xs[4096];
  __shared__ float red[4][64], red2[4][64];
  int t = threadIdx.x, lane = t & 63, wv = t >> 6;
  int ntiles = (rows + 63) >> 6;
  float psum = 0.f, psq = 0.f;
  float bv = bias ? bias[lane] : 0.f;
  for (int tile = blockIdx.x; tile < ntiles; tile += gridDim.x) {
    int base = tile * 64;
    float acc[16];
#pragma unroll
    for (int j = 0; j < 16; j++) acc[j] = bv;
    for (int pass = 0; pass < (TWO ? 2 : 1); pass++) {
      const float* Xp = pass ? Xb : X;
      const float* Wp = pass ? Wb : Wm;
      __syncthreads();
#pragma unroll
      for (int m = 0; m < 16; m++) {
        int fl = m * 256 + t;
        int r = fl >> 6, c = fl & 63;
        int gr = base + r;
        float v = (gr < rows) ? Xp[gr * 64 + c] : 0.f;
        if (PRE) { v = pa[c] * v + pb[c]; if (PRELU) v = fmaxf(v, 0.f); }
        xs[fl] = v;
      }
      __syncthreads();
      float Wreg[64];
#pragma unroll
      for (int k = 0; k < 64; k++) Wreg[k] = Wp[lane * 64 + k];
#pragma unroll
      for (int j = 0; j < 16; j++) {
        int r = wv * 16 + j;
        const float4* xr = (const float4*)&xs[r * 64];
        float a = acc[j];
#pragma unroll
        for (int kk = 0; kk < 16; kk++) {
          float4 xv = xr[kk];
          a = fmaf(xv.x, Wreg[4 * kk + 0], a);
          a = fmaf(xv.y, Wreg[4 * kk + 1], a);
          a = fmaf(xv.z, Wreg[4 * kk + 2], a);
          a = fmaf(xv.w, Wreg[4 * kk + 3], a);
        }
        acc[j] = a;
      }
    }
#pragma unroll
    for (int j = 0; j < 16; j++) {
      int gr = base + wv * 16 + j;
      if (gr < rows) {
        float v = acc[j];
        if (PERG) v += perg[(gr % tabrows) * 64 + lane];
        Y[gr * 64 + lane] = v;
        if (STATS) { psum += v; psq += v * v; }
      }
    }
  }
  if (STATS) {
    __syncthreads();
    red[wv][lane] = psum; red2[wv][lane] = psq;
    __syncthreads();
    if (wv == 0) {
      float s = red[0][lane] + red[1][lane] + red[2][lane] + red[3][lane];
      float q = red2[0][lane] + red2[1][lane] + red2[2][lane] + red2[3][lane];
      atomicAdd(&stats[lane], s);
      atomicAdd(&stats[64 + lane], q);
    }
  }
}

// stats of u = a2*T2(bf16) + b2 + emb[row/G]  (no store); 8 elems/thread/iter
__global__ __launch_bounds__(256) void k7_kernel(const u16* __restrict__ T2, const float* __restrict__ a2,
                                                 const float* __restrict__ b2, const float* __restrict__ emb,
                                                 float* __restrict__ stats) {
  __shared__ float sstat[128];
  int t = threadIdx.x, cg = t & 7;
  float sS[8], sQ[8];
#pragma unroll
  for (int j = 0; j < 8; j++) { sS[j] = 0.f; sQ[j] = 0.f; }
  int c8 = cg * 8;
  float4 A0 = *(const float4*)&a2[c8];
  float4 A1 = *(const float4*)&a2[c8 + 4];
  float4 B0 = *(const float4*)&b2[c8];
  float4 B1 = *(const float4*)&b2[c8 + 4];
  int total8 = Nn * 8;
  int stride = gridDim.x * 256;
  for (int g8 = blockIdx.x * 256 + t; g8 < total8; g8 += stride) {
    int i = g8 >> 3;
    int b = i / Gn;
    uint4 u = *(const uint4*)&T2[(size_t)i * 64 + c8];
    float4 E0 = *(const float4*)&emb[b * 64 + c8];
    float4 E1 = *(const float4*)&emb[b * 64 + c8 + 4];
    float v[8];
    v[0] = fmaf(A0.x, bflo(u.x), B0.x) + E0.x;
    v[1] = fmaf(A0.y, bfhi(u.x), B0.y) + E0.y;
    v[2] = fmaf(A0.z, bflo(u.y), B0.z) + E0.z;
    v[3] = fmaf(A0.w, bfhi(u.y), B0.w) + E0.w;
    v[4] = fmaf(A1.x, bflo(u.z), B1.x) + E1.x;
    v[5] = fmaf(A1.y, bfhi(u.z), B1.y) + E1.y;
    v[6] = fmaf(A1.z, bflo(u.w), B1.z) + E1.z;
    v[7] = fmaf(A1.w, bfhi(u.w), B1.w) + E1.w;
#pragma unroll
    for (int j = 0; j < 8; j++) { sS[j] += v[j]; sQ[j] += v[j] * v[j]; }
  }
  for (int idx = t; idx < 128; idx += 256) sstat[idx] = 0.f;
  __syncthreads();
#pragma unroll
  for (int j = 0; j < 8; j++) {
    atomicAdd(&sstat[c8 + j], sS[j]);
    atomicAdd(&sstat[64 + c8 + j], sQ[j]);
  }
  __syncthreads();
  for (int idx = t; idx < 64; idx += 256) {
    atomicAdd(&stats[idx], sstat[idx]);
    atomicAdd(&stats[64 + idx], sstat[64 + idx]);
  }
}

// finalize S3 and build folded vectors: Avec = a3*a2, e2[b] = a3*(b2+emb[b]) + b3
__global__ __launch_bounds__(256) void kfinS3e2(const float* __restrict__ stats, const float* __restrict__ g,
                                                const float* __restrict__ bt, const float* __restrict__ a2,
                                                const float* __restrict__ b2, const float* __restrict__ emb,
                                                float* __restrict__ Avec, float* __restrict__ e2, float invn) {
  __shared__ float a3s[64], b3s[64];
  int t = threadIdx.x;
  if (t < 64) {
    float mean = stats[t] * invn;
    float var = stats[64 + t] * invn - mean * mean;
    float sc = g[t] * rsqrtf(var + 1e-5f);
    float sh = bt[t] - mean * sc;
    a3s[t] = sc; b3s[t] = sh;
    Avec[t] = sc * a2[t];
  }
  __syncthreads();
  for (int idx = t; idx < 2048; idx += 256) {
    int c = idx & 63;
    e2[idx] = a3s[c] * (b2[c] + emb[idx]) + b3s[c];
  }
}

// w1[i] = dot(a5*R2(bf16)+b5, indv_w1[i%G]) + indv_b1[i%G]
__global__ __launch_bounds__(256) void k13_kernel(const u16* __restrict__ R2, const float* __restrict__ a5,
                                                  const float* __restrict__ b5, const float* __restrict__ iw1,
                                                  const float* __restrict__ ib1, float* __restrict__ w1out,
                                                  int rows) {
  int t = blockIdx.x * 256 + threadIdx.x;
  int i = t >> 4, j = t & 15;
  if (i >= rows) return;
  int g = i % Gn;
  uint2 u = *(const uint2*)&R2[(size_t)i * 64 + j * 4];
  float rx = bflo(u.x), ry = bfhi(u.x), rz = bflo(u.y), rw = bfhi(u.y);
  float4 a = ((const float4*)a5)[j];
  float4 b = ((const float4*)b5)[j];
  float4 w = ((const float4*)iw1)[g * 16 + j];
  float p = (a.x * rx + b.x) * w.x + (a.y * ry + b.y) * w.y +
            (a.z * rz + b.z) * w.z + (a.w * rw + b.w) * w.w;
  for (int off = 8; off; off >>= 1) p += __shfl_xor(p, off, 64);
  if (j == 0) w1out[i] = p + ib1[g];
}

// init cgraw with bias
__global__ __launch_bounds__(256) void kinitcg(const float* __restrict__ cgb1, float* __restrict__ cgraw) {
  int idx = blockIdx.x * 256 + threadIdx.x;
  if (idx < Bn * 64) cgraw[idx] = cgb1[idx & 63];
}

// split-K GEMM: cgraw[b][col] += sum_{k in chunk} w1[b][k]*cgW1[col][k]
__global__ __launch_bounds__(256) void kcg1s(const float* __restrict__ w1, const float* __restrict__ cgW1,
                                             float* __restrict__ cgraw) {
  __shared__ float w1s[64 * 36];
  __shared__ float cgs[64 * 65];
  int t = threadIdx.x;
  int k0 = blockIdx.x * 64;
  int kmax = Gn - k0; if (kmax > 64) kmax = 64;
  for (int idx = t; idx < 2048; idx += 256) {
    int row = idx >> 6, k = idx & 63;
    w1s[k * 36 + row] = (k < kmax) ? w1[row * Gn + k0 + k] : 0.f;
  }
  for (int idx = t; idx < 4096; idx += 256) {
    int col = idx >> 6, k = idx & 63;
    cgs[k * 65 + col] = (k < kmax) ? cgW1[col * Gn + k0 + k] : 0.f;
  }
  __syncthreads();
  int col = t & 63, rg = t >> 6;
  float acc[8];
#pragma unroll
  for (int i = 0; i < 8; i++) acc[i] = 0.f;
  for (int k = 0; k < 64; k++) {
    float wk = cgs[k * 65 + col];
    const float* wr = &w1s[k * 36 + rg * 8];
    float4 r0 = *(const float4*)wr;
    float4 r1 = *(const float4*)(wr + 4);
    acc[0] = fmaf(r0.x, wk, acc[0]);
    acc[1] = fmaf(r0.y, wk, acc[1]);
    acc[2] = fmaf(r0.z, wk, acc[2]);
    acc[3] = fmaf(r0.w, wk, acc[3]);
    acc[4] = fmaf(r1.x, wk, acc[4]);
    acc[5] = fmaf(r1.y, wk, acc[5]);
    acc[6] = fmaf(r1.z, wk, acc[6]);
    acc[7] = fmaf(r1.w, wk, acc[7]);
  }
#pragma unroll
  for (int i = 0; i < 8; i++) atomicAdd(&cgraw[(rg * 8 + i) * 64 + col], acc[i]);
}

// single-block: cg2 = bn2(relu(bn1(cgraw)) @ W2^T + b2)   (BN over 32 rows)
__global__ __launch_bounds__(256) void kcg2(const float* __restrict__ cgraw, const float* __restrict__ g1,
                                            const float* __restrict__ bt1, const float* __restrict__ W2,
                                            const float* __restrict__ b2, const float* __restrict__ g2,
                                            const float* __restrict__ bt2, float* __restrict__ cg2out) {
  int t = threadIdx.x, c = t & 63, bg = t >> 6;
  __shared__ float hmid[2048], sred[4][64], qred[4][64], asc[64], bsh[64];
  float y[8];
  float ps = 0.f, pq = 0.f;
  for (int jb = 0; jb < 8; jb++) {
    int b = bg * 8 + jb;
    float v = cgraw[b * 64 + c];
    y[jb] = v; ps += v; pq += v * v;
  }
  sred[bg][c] = ps; qred[bg][c] = pq;
  __syncthreads();
  if (t < 64) {
    float s = sred[0][t] + sred[1][t] + sred[2][t] + sred[3][t];
    float q = qred[0][t] + qred[1][t] + qred[2][t] + qred[3][t];
    float mean = s * (1.f / 32.f), var = q * (1.f / 32.f) - mean * mean;
    float sc = g1[t] * rsqrtf(var + 1e-5f);
    asc[t] = sc; bsh[t] = bt1[t] - mean * sc;
  }
  __syncthreads();
  for (int jb = 0; jb < 8; jb++) { int b = bg * 8 + jb; hmid[b * 64 + c] = fmaxf(asc[c] * y[jb] + bsh[c], 0.f); }
  __syncthreads();
  ps = 0.f; pq = 0.f;
  for (int jb = 0; jb < 8; jb++) {
    int b = bg * 8 + jb;
    float a = b2[c];
    for (int k = 0; k < 64; k++) a += hmid[b * 64 + k] * W2[c * 64 + k];
    y[jb] = a; ps += a; pq += a * a;
  }
  sred[bg][c] = ps; qred[bg][c] = pq;
  __syncthreads();
  if (t < 64) {
    float s = sred[0][t] + sred[1][t] + sred[2][t] + sred[3][t];
    float q = qred[0][t] + qred[1][t] + qred[2][t] + qred[3][t];
    float mean = s * (1.f / 32.f), var = q * (1.f / 32.f) - mean * mean;
    float sc = g2[t] * rsqrtf(var + 1e-5f);
    asc[t] = sc; bsh[t] = bt2[t] - mean * sc;
  }
  __syncthreads();
  for (int jb = 0; jb < 8; jb++) { int b = bg * 8 + jb; cg2out[b * 64 + c] = asc[c] * y[jb] + bsh[c]; }
}

// single-block: emb = mlp3(pglob[pert_idx]) with BN over 32 rows
__global__ __launch_bounds__(256) void kemb(const float* __restrict__ m2, const float* __restrict__ aP2,
                                            const float* __restrict__ bP2, const int* __restrict__ pidx,
                                            const float* __restrict__ Wm, const float* __restrict__ bv,
                                            const float* __restrict__ gg, const float* __restrict__ btv,
                                            float* __restrict__ emb) {
  int t = threadIdx.x, c = t & 63, bg = t >> 6;
  __shared__ float xin[2048], hmid[2048], sred[4][64], qred[4][64], asc[64], bsh[64];
  for (int idx = t; idx < 2048; idx += 256) {
    int b = idx >> 6, cc = idx & 63;
    xin[idx] = aP2[cc] * m2[pidx[b] * 64 + cc] + bP2[cc];
  }
  __syncthreads();
  float y[8];
  float ps = 0.f, pq = 0.f;
  for (int jb = 0; jb < 8; jb++) {
    int b = bg * 8 + jb;
    float a = bv[c];
    for (int k = 0; k < 64; k++) a += xin[b * 64 + k] * Wm[c * 64 + k];
    y[jb] = a; ps += a; pq += a * a;
  }
  sred[bg][c] = ps; qred[bg][c] = pq;
  __syncthreads();
  if (t < 64) {
    float s = sred[0][t] + sred[1][t] + sred[2][t] + sred[3][t];
    float q = qred[0][t] + qred[1][t] + qred[2][t] + qred[3][t];
    float mean = s * (1.f / 32.f), var = q * (1.f / 32.f) - mean * mean;
    float sc = gg[t] * rsqrtf(var + 1e-5f);
    asc[t] = sc; bsh[t] = btv[t] - mean * sc;
  }
  __syncthreads();
  for (int jb = 0; jb < 8; jb++) { int b = bg * 8 + jb; hmid[b * 64 + c] = fmaxf(asc[c] * y[jb] + bsh[c], 0.f); }
  __syncthreads();
  ps = 0.f; pq = 0.f;
  for (int jb = 0; jb < 8; jb++) {
    int b = bg * 8 + jb;
    float a = bv[64 + c];
    for (int k = 0; k < 64; k++) a += hmid[b * 64 + k] * Wm[4096 + c * 64 + k];
    y[jb] = a; ps += a; pq += a * a;
  }
  sred[bg][c] = ps; qred[bg][c] = pq;
  __syncthreads();
  if (t < 64) {
    float s = sred[0][t] + sred[1][t] + sred[2][t] + sred[3][t];
    float q = qred[0][t] + qred[1][t] + qred[2][t] + qred[3][t];
    float mean = s * (1.f / 32.f), var = q * (1.f / 32.f) - mean * mean;
    float sc = gg[64 + t] * rsqrtf(var + 1e-5f);
    asc[t] = sc; bsh[t] = btv[64 + t] - mean * sc;
  }
  __syncthreads();
  for (int jb = 0; jb < 8; jb++) { int b = bg * 8 + jb; emb[b * 64 + c] = asc[c] * y[jb] + bsh[c]; }
}

// final: out[b][g] = w1*iw2[g][0] + dot(cg2[b], iw2[g][1:65]) + ib2[g] + x[b][g]
__global__ __launch_bounds__(256) void kfinal(const float* __restrict__ w1, const float* __restrict__ cg2,
                                              const float* __restrict__ iw2, const float* __restrict__ ib2,
                                              const float* __restrict__ x, float* __restrict__ out) {
  __shared__ float iws[64 * 65], cgs[2048];
  int t = threadIdx.x;
  int g0 = blockIdx.x * 64;
  for (int idx = t; idx < 64 * 65; idx += 256) {
    int gi = g0 * 65 + idx;
    iws[idx] = (gi < Gn * 65) ? iw2[gi] : 0.f;
  }
  for (int idx = t; idx < 2048; idx += 256) cgs[idx] = cg2[idx];
  __syncthreads();
  int gl = t & 63, bg = t >> 6;
  int g = g0 + gl;
  if (g >= Gn) return;
  float bias = ib2[g];
  for (int jb = 0; jb < 8; jb++) {
    int b = bg * 8 + jb;
    float acc = w1[b * Gn + g] * iws[gl * 65] + bias;
    for (int k = 0; k < 64; k++) acc += cgs[b * 64 + k] * iws[gl * 65 + 1 + k];
    out[b * Gn + g] = acc + x[b * Gn + g];
  }
}

extern "C" void kernel_launch(void* const* d_in, const int* in_sizes, int n_in,
                              void* d_out, int out_size, void* d_ws, size_t ws_size,
                              hipStream_t stream) {
  (void)in_sizes; (void)n_in; (void)out_size;
  if (ws_size < WS_FLOATS * sizeof(float)) return;

  const float* x        = (const float*)d_in[0];
  const int*   pert_idx = (const int*)d_in[1];
  const int*   ei_co    = (const int*)d_in[2];
  const float* w_co     = (const float*)d_in[3];
  const int*   ei_go    = (const int*)d_in[4];
  const float* w_go     = (const float*)d_in[5];
  const int*   ei_bg    = (const int*)d_in[6];
  const float* w_bg     = (const float*)d_in[7];
  const float* gene_tab = (const float*)d_in[8];
  const float* pos_tab  = (const float*)d_in[9];
  const float* go_tab   = (const float*)d_in[10];
  const float* bg_tab   = (const float*)d_in[11];
  const float* bn_g     = (const float*)d_in[12];
  const float* bn_b     = (const float*)d_in[13];
  const float* sg_W     = (const float*)d_in[14];
  const float* sg_b     = (const float*)d_in[15];
  const float* mlp_W    = (const float*)d_in[16];
  const float* mlp_b    = (const float*)d_in[17];
  const float* mlp_g    = (const float*)d_in[18];
  const float* mlp_bt   = (const float*)d_in[19];
  const float* rec_W1   = (const float*)d_in[20];
  const float* rec_b1   = (const float*)d_in[21];
  const float* rec_g1   = (const float*)d_in[22];
  const float* rec_bt1  = (const float*)d_in[23];
  const float* rec_W2   = (const float*)d_in[24];
  const float* rec_b2   = (const float*)d_in[25];
  const float* rec_g2   = (const float*)d_in[26];
  const float* rec_bt2  = (const float*)d_in[27];
  const float* indv_w1  = (const float*)d_in[28];
  const float* indv_b1  = (const float*)d_in[29];
  const float* cg_W1    = (const float*)d_in[30];
  const float* cg_b1    = (const float*)d_in[31];
  const float* cg_g1    = (const float*)d_in[32];
  const float* cg_bt1   = (const float*)d_in[33];
  const float* cg_W2    = (const float*)d_in[34];
  const float* cg_b2    = (const float*)d_in[35];
  const float* cg_g2    = (const float*)d_in[36];
  const float* cg_bt2   = (const float*)d_in[37];
  const float* indv_w2  = (const float*)d_in[38];
  const float* indv_b2  = (const float*)d_in[39];

  float* W = (float*)d_ws;
  float* buf0 = W + oBUF0;
  float* buf1 = W + oBUF1;

  // CSR scratch lives in buf1 (consumed before t1 writes buf1)
  int*    co_cnt    = (int*)(buf1);                  // 160001
  int*    sbsum     = (int*)(buf1 + 320128);         // <=256 block sums
  float2* co_pack   = (float2*)(buf1 + 400000);      // 1.6M float2
  int*    go_cnt    = (int*)(buf1 + 3700000);
  float2* go_pack   = (float2*)(buf1 + 3720000);
  int*    bg_cnt    = (int*)(buf1 + 4000000);
  float2* bg_pack   = (float2*)(buf1 + 4020000);
  int*    co_ticket = (int*)(buf1 + 4500000);        // 1.6M ints
  int*    go_ticket = (int*)(buf1 + 6200000);
  int*    bg_ticket = (int*)(buf1 + 6400000);

  // --- phase 0: zero stats, renorm tables, fold small matrices ---
  kzero<<<8, 256, 0, stream>>>(W, 2048);
  krenorm<<<160, 256, 0, stream>>>(gene_tab, W + oRG, W + oSG, Gn);
  krenorm<<<160, 256, 0, stream>>>(pos_tab, W + oRP, nullptr, Gn);
  krenorm<<<160, 256, 0, stream>>>(go_tab, W + oRGO, nullptr, Pn);
  krenorm<<<160, 256, 0, stream>>>(bg_tab, W + oRBG, nullptr, Pn);
  kfin<<<1, 64, 0, stream>>>(W + oSG, bn_g, bn_b, W + oAG, W + oBG, 64, 1.f / Gn);
  ksmallmat<<<1, 256, 0, stream>>>(mlp_W + 8192, sg_W, 0.2f, mlp_b + 128, sg_b, nullptr, 0.2f, W + oM, W + oCvec);
  ksmallmat<<<1, 256, 0, stream>>>(mlp_W, sg_W + 4096, 1.f, nullptr, nullptr, nullptr, 0.f, W + oM1, nullptr);
  ksmallmat<<<1, 256, 0, stream>>>(mlp_W, sg_W + 8192, 1.f, mlp_b, sg_b + 64, sg_b + 128, 1.f, W + oM2, W + oCcP);
  gemm64k<false, true, true, false, false><<<79, 256, 0, stream>>>(
      W + oRG, nullptr, mlp_W + 8192, nullptr, W + oCvec, W + oAG, W + oBG, nullptr, 0, W + oQ, nullptr, Gn);

  // --- co graph: ticket CSR build + gather (bf16 out) ---
  kzero<<<(160001 + 255) / 256, 256, 0, stream>>>((float*)co_cnt, 160001);
  khist<<<(ECO + 255) / 256, 256, 0, stream>>>(ei_co + ECO, co_cnt, co_ticket, ECO);
  kscan1<<<157, 256, 0, stream>>>(co_cnt, sbsum, Nn);
  kscan2<<<1, 256, 0, stream>>>(sbsum, 157, co_cnt + Nn);
  kscan3<<<157, 256, 0, stream>>>(co_cnt, sbsum, Nn);
  kfillt<<<(ECO + 255) / 256, 256, 0, stream>>>(ei_co, ei_co + ECO, w_co, co_cnt, co_ticket, co_pack, ECO);
  kdinvrow<<<(Nn + 255) / 256, 256, 0, stream>>>(co_cnt, co_pack, W + oDEG, Nn);
  kgather<true><<<2048, 256, 0, stream>>>(co_cnt, co_pack, W + oDEG, W + oRP, nullptr, (u16*)buf0, Nn);

  // --- go graph ---
  kzero<<<(5001 + 255) / 256, 256, 0, stream>>>((float*)go_cnt, 5001);
  khist<<<(EGG + 255) / 256, 256, 0, stream>>>(ei_go + EGG, go_cnt, go_ticket, EGG);
  kscan1<<<5, 256, 0, stream>>>(go_cnt, sbsum, Pn);
  kscan2<<<1, 256, 0, stream>>>(sbsum, 5, go_cnt + Pn);
  kscan3<<<5, 256, 0, stream>>>(go_cnt, sbsum, Pn);
  kfillt<<<(EGG + 255) / 256, 256, 0, stream>>>(ei_go, ei_go + EGG, w_go, go_cnt, go_ticket, go_pack, EGG);
  kdinvrow<<<(Pn + 255) / 256, 256, 0, stream>>>(go_cnt, go_pack, W + oDGO, Pn);
  kgather<false><<<512, 256, 0, stream>>>(go_cnt, go_pack, W + oDGO, W + oRGO, W + oAGO, nullptr, Pn);

  // --- bg graph ---
  kzero<<<(5001 + 255) / 256, 256, 0, stream>>>((float*)bg_cnt, 5001);
  khist<<<(EGG + 255) / 256, 256, 0, stream>>>(ei_bg + EGG, bg_cnt, bg_ticket, EGG);
  kscan1<<<5, 256, 0, stream>>>(bg_cnt, sbsum, Pn);
  kscan2<<<1, 256, 0, stream>>>(sbsum, 5, bg_cnt + Pn);
  kscan3<<<5, 256, 0, stream>>>(bg_cnt, sbsum, Pn);
  kfillt<<<(EGG + 255) / 256, 256, 0, stream>>>(ei_bg, ei_bg + EGG, w_bg, bg_cnt, bg_ticket, bg_pack, EGG);
  kdinvrow<<<(Pn + 255) / 256, 256, 0, stream>>>(bg_cnt, bg_pack, W + oDBG, Pn);
  kgather<false><<<512, 256, 0, stream>>>(bg_cnt, bg_pack, W + oDBG, W + oRBG, W + oABG, nullptr, Pn);

  // --- pert path (Pn rows, fp32) ---
  gemm64k<true, false, false, false, true><<<79, 256, 0, stream>>>(
      W + oAGO, W + oABG, W + oM1, W + oM2, W + oCcP, nullptr, nullptr, nullptr, 0, W + oM1B, W + oSP1, Pn);
  kfin<<<1, 64, 0, stream>>>(W + oSP1, mlp_g, mlp_bt, W + oAP1, W + oBP1, 64, 1.f / Pn);
  gemm64k<false, true, true, false, true><<<79, 256, 0, stream>>>(
      W + oM1B, nullptr, mlp_W + 4096, nullptr, mlp_b + 64, W + oAP1, W + oBP1, nullptr, 0, W + oM2B, W + oSP2, Pn);
  kfin<<<1, 64, 0, stream>>>(W + oSP2, mlp_g + 64, mlp_bt + 64, W + oAP2, W + oBP2, 64, 1.f / Pn);
  kemb<<<1, 256, 0, stream>>>(W + oM2B, W + oAP2, W + oBP2, pert_idx,
                              mlp_W + 16384, mlp_b + 256, mlp_g + 256, mlp_bt + 256, W + oEMB);

  // --- main N pipeline (bf16 intermediates) ---
  // t1 = agg@M^T + Q[g]; stats S1
  gemm_big<false, false, true><<<512, 256, 0, stream>>>(
      (const u16*)buf0, W + oM, W + oZERO, nullptr, nullptr, W + oQ, (u16*)buf1, 64, W + oS1, 64);
  kfin<<<1, 64, 0, stream>>>(W + oS1, mlp_g + 128, mlp_bt + 128, W + oA1, W + oB1, 64, 1.f / Nn);
  // t2 = relu(a1*t1+b1)@W11^T + b11; stats S2
  gemm_big<true, false, false><<<512, 256, 0, stream>>>(
      (const u16*)buf1, mlp_W + 12288, mlp_b + 192, W + oA1, W + oB1, nullptr, (u16*)buf0, 64, W + oS2, 64);
  kfin<<<1, 64, 0, stream>>>(W + oS2, mlp_g + 192, mlp_bt + 192, W + oA2, W + oB2, 64, 1.f / Nn);
  // stats of u = a2*t2+b2+emb[b]
  k7_kernel<<<512, 256, 0, stream>>>((const u16*)buf0, W + oA2, W + oB2, W + oEMB, W + oS3);
  kfinS3e2<<<1, 256, 0, stream>>>(W + oS3, bn_g + 64, bn_b + 64, W + oA2, W + oB2, W + oEMB,
                                  W + oAvec, W + oE2, 1.f / Nn);
  // r1 (two 64-col halves): base2 = relu(Avec*t2+e2[b]) in LDS; r1 bf16 pitch 128
  gemm_big<true, true, false><<<512, 256, 0, stream>>>(
      (const u16*)buf0, rec_W1, rec_b1, W + oAvec, W + oE2, nullptr, (u16*)buf1, 128, W + oS4, 128);
  gemm_big<true, true, false><<<512, 256, 0, stream>>>(
      (const u16*)buf0, rec_W1 + 4096, rec_b1 + 64, W + oAvec, W + oE2, nullptr, (u16*)buf1 + 64, 128, W + oS4 + 64, 128);
  kfin<<<2, 64, 0, stream>>>(W + oS4, rec_g1, rec_bt1, W + oA4, W + oB4, 128, 1.f / Nn);
  // r2 = relu(a4*r1+b4)@W2^T + b2; stats S5; bf16 out
  gemm_k11<<<512, 256, 0, stream>>>((const u16*)buf1, rec_W2, rec_b2, W + oA4, W + oB4, (u16*)buf0, W + oS5);
  kfin<<<1, 64, 0, stream>>>(W + oS5, rec_g2, rec_bt2, W + oA5, W + oB5, 64, 1.f / Nn);
  k13_kernel<<<(Nn * 16 + 255) / 256, 256, 0, stream>>>((const u16*)buf0, W + oA5, W + oB5, indv_w1, indv_b1,
                                                        W + oW1, Nn);
  // cross-gene state
  kinitcg<<<8, 256, 0, stream>>>(cg_b1, W + oCGRAW);
  kcg1s<<<(Gn + 63) / 64, 256, 0, stream>>>(W + oW1, cg_W1, W + oCGRAW);
  kcg2<<<1, 256, 0, stream>>>(W + oCGRAW, cg_g1, cg_bt1, cg_W2, cg_b2, cg_g2, cg_bt2, W + oCG2);
  kfinal<<<(Gn + 63) / 64, 256, 0, stream>>>(W + oW1, W + oCG2, indv_w2, indv_b2, x, (float*)d_out);
}

// Round 5
// 1036.654 us; speedup vs baseline: 4.5218x; 1.0082x over previous
//
#include <hip/hip_runtime.h>

typedef unsigned int u32;
typedef unsigned short u16;

// Problem constants (fixed by the reference)
constexpr int Gn  = 5000;     // genes
constexpr int Bn  = 32;       // batch graphs
constexpr int Pn  = 5000;     // perts
constexpr int Nn  = Bn * Gn;  // 160000
constexpr int ECO = 1600000;
constexpr int EGG = 100000;
constexpr int NTILES = Nn / 128;  // 1250, exact

// ---- workspace layout (float offsets) ----
constexpr int oS1 = 0, oS2 = 128, oS3 = 256, oS4 = 384, oS5 = 640, oSG = 768, oSP1 = 896, oSP2 = 1024;
constexpr int oZERO = 1536;  // stays zero (bias for t1)
constexpr int oA1 = 2048, oB1 = 2112, oA2 = 2176, oB2 = 2240;
constexpr int oA4 = 2304, oB4 = 2432;            // 128 each
constexpr int oA5 = 2560, oB5 = 2624;
constexpr int oAG = 2688, oBG = 2752;
constexpr int oAP1 = 2816, oBP1 = 2880, oAP2 = 2944, oBP2 = 3008;
constexpr int oAvec = 3072, oCvec = 3136, oCcP = 3200;
constexpr int oM  = 4096, oM1 = 8192, oM2 = 12288;
constexpr int oE2 = 16384, oEMB = 18432, oCGRAW = 20480, oCG2 = 22528;
constexpr int oRG  = 24576;
constexpr int oRP  = oRG  + Gn * 64;
constexpr int oQ   = oRP  + Gn * 64;
constexpr int oRGO = oQ   + Gn * 64;
constexpr int oRBG = oRGO + Pn * 64;
constexpr int oAGO = oRBG + Pn * 64;
constexpr int oABG = oAGO + Pn * 64;
constexpr int oM1B = oABG + Pn * 64;
constexpr int oM2B = oM1B + Pn * 64;
constexpr int oDGO = oM2B + Pn * 64;
constexpr int oDBG = oDGO + Pn;
constexpr int oDEG = oDBG + Pn;
constexpr int oW1  = oDEG + Nn;
constexpr int oBUF0 = oW1 + Nn;
constexpr int oBUF1 = oBUF0 + Nn * 64;
constexpr size_t WS_FLOATS = (size_t)oBUF1 + (size_t)Nn * 64;  // ~95 MB

__device__ inline u16 f2bf(float f) {
  u32 u = __float_as_uint(f);
  u = (u + 0x7fffu + ((u >> 16) & 1u)) >> 16;
  return (u16)u;
}
__device__ inline float bflo(u32 v) { return __uint_as_float(v << 16); }
__device__ inline float bfhi(u32 v) { return __uint_as_float(v & 0xffff0000u); }

#define XC(v, kk) ((kk) == 0 ? (v).x : (kk) == 1 ? (v).y : (kk) == 2 ? (v).z : (v).w)

__global__ __launch_bounds__(256) void kzero(float* p, int n) {
  int i = blockIdx.x * 256 + threadIdx.x;
  if (i < n) p[i] = 0.f;
}

// row-wise L2 renorm (norm clipped to <=1); optional column stats of the output
__global__ __launch_bounds__(256) void krenorm(const float* __restrict__ in, float* __restrict__ out,
                                               float* __restrict__ stats, int rows) {
  int lane = threadIdx.x & 63, wv = threadIdx.x >> 6;
  int gw = blockIdx.x * 4 + wv, nw = gridDim.x * 4;
  float ps = 0.f, pq = 0.f;
  for (int r = gw; r < rows; r += nw) {
    float v = in[r * 64 + lane];
    float sq = v * v;
    for (int off = 32; off; off >>= 1) sq += __shfl_xor(sq, off, 64);
    float nn = sqrtf(sq);
    float s = fminf(1.f, 1.f / fmaxf(nn, 1e-12f));
    float o = v * s;
    out[r * 64 + lane] = o;
    ps += o; pq += o * o;
  }
  if (!stats) return;
  __shared__ float red[4][64], red2[4][64];
  red[wv][lane] = ps; red2[wv][lane] = pq;
  __syncthreads();
  if (wv == 0) {
    float s = red[0][lane] + red[1][lane] + red[2][lane] + red[3][lane];
    float q = red2[0][lane] + red2[1][lane] + red2[2][lane] + red2[3][lane];
    atomicAdd(&stats[lane], s);
    atomicAdd(&stats[64 + lane], q);
  }
}

// finalize BN: a = g*rsqrt(var+eps), b = bt - mean*a
__global__ void kfin(const float* __restrict__ stats, const float* __restrict__ g,
                     const float* __restrict__ bt, float* __restrict__ a, float* __restrict__ b,
                     int cols, float invn) {
  int c = blockIdx.x * 64 + threadIdx.x;
  if (c >= cols) return;
  float mean = stats[c] * invn;
  float var = stats[cols + c] * invn - mean * mean;
  float sc = g[c] * rsqrtf(var + 1e-5f);
  a[c] = sc;
  b[c] = bt[c] - mean * sc;
}

// Mout = alpha * A @ Bm  (64x64 each); optional cvec = bias + beta * A @ (bv1+bv2)
__global__ __launch_bounds__(256) void ksmallmat(const float* __restrict__ A, const float* __restrict__ Bm,
                                                 float alpha, const float* __restrict__ bias,
                                                 const float* __restrict__ bv1, const float* __restrict__ bv2,
                                                 float beta, float* __restrict__ Mout, float* __restrict__ cvec) {
  __shared__ float As[4096], Bs[4096];
  int t = threadIdx.x;
  for (int m = 0; m < 16; m++) { As[m * 256 + t] = A[m * 256 + t]; Bs[m * 256 + t] = Bm[m * 256 + t]; }
  __syncthreads();
  int j = t & 63, ig = t >> 6;
  for (int ii = 0; ii < 16; ii++) {
    int i = ig * 16 + ii;
    float acc = 0.f;
    for (int k = 0; k < 64; k++) acc += As[i * 64 + k] * Bs[k * 64 + j];
    Mout[i * 64 + j] = alpha * acc;
  }
  if (cvec && t < 64) {
    float acc = bias ? bias[t] : 0.f;
    for (int k = 0; k < 64; k++) {
      float bb = (bv1 ? bv1[k] : 0.f) + (bv2 ? bv2[k] : 0.f);
      acc += beta * As[t * 64 + k] * bb;
    }
    cvec[t] = acc;
  }
}

// histogram with ticket: one atomic per edge
__global__ __launch_bounds__(256) void khist(const int* __restrict__ dst, int* __restrict__ cnt,
                                             int* __restrict__ ticket, int E) {
  int e = blockIdx.x * 256 + threadIdx.x;
  if (e < E) ticket[e] = atomicAdd(&cnt[dst[e]], 1);
}

// ---- block scan (1024 elems/block) ----
__global__ __launch_bounds__(256) void kscan1(const int* __restrict__ cnt, int* __restrict__ bsum, int n) {
  __shared__ int sh[256];
  int b = blockIdx.x, t = threadIdx.x;
  int base = b * 1024 + t * 4;
  int s = 0;
#pragma unroll
  for (int j = 0; j < 4; j++) { int i = base + j; if (i < n) s += cnt[i]; }
  sh[t] = s; __syncthreads();
  for (int d = 128; d; d >>= 1) { if (t < d) sh[t] += sh[t + d]; __syncthreads(); }
  if (t == 0) bsum[b] = sh[0];
}
__global__ __launch_bounds__(256) void kscan2(int* bsum, int nb, int* off_n) {
  __shared__ int sh[256];
  int t = threadIdx.x;
  int v = (t < nb) ? bsum[t] : 0;
  sh[t] = v;
  __syncthreads();
  for (int d = 1; d < 256; d <<= 1) {
    int u = (t >= d) ? sh[t - d] : 0;
    __syncthreads();
    sh[t] += u;
    __syncthreads();
  }
  if (t < nb) bsum[t] = sh[t] - v;  // exclusive
  if (t == nb - 1 && off_n) *off_n = sh[t];
}
__global__ __launch_bounds__(256) void kscan3(int* __restrict__ cnt, const int* __restrict__ bsum, int n) {
  __shared__ int sh[256];
  int b = blockIdx.x, t = threadIdx.x;
  int base = b * 1024 + t * 4;
  int c0 = (base + 0 < n) ? cnt[base + 0] : 0;
  int c1 = (base + 1 < n) ? cnt[base + 1] : 0;
  int c2 = (base + 2 < n) ? cnt[base + 2] : 0;
  int c3 = (base + 3 < n) ? cnt[base + 3] : 0;
  int tot = c0 + c1 + c2 + c3;
  sh[t] = tot; __syncthreads();
  for (int d = 1; d < 256; d <<= 1) {
    int v = (t >= d) ? sh[t - d] : 0;
    __syncthreads();
    sh[t] += v;
    __syncthreads();
  }
  int excl = sh[t] - tot + bsum[b];
  if (base + 0 < n) cnt[base + 0] = excl;
  if (base + 1 < n) cnt[base + 1] = excl + c0;
  if (base + 2 < n) cnt[base + 2] = excl + c0 + c1;
  if (base + 3 < n) cnt[base + 3] = excl + c0 + c1 + c2;
}

// atomic-free CSR fill using tickets: pack[off[d]+ticket] = (w, src_full)
__global__ __launch_bounds__(256) void kfillt(const int* __restrict__ src, const int* __restrict__ dst,
                                              const float* __restrict__ w, const int* __restrict__ off,
                                              const int* __restrict__ ticket, float2* __restrict__ pack, int E) {
  int e = blockIdx.x * 256 + threadIdx.x;
  if (e >= E) return;
  int d = dst[e];
  int pos = off[d] + ticket[e];
  pack[pos] = make_float2(w[e], __int_as_float(src[e]));
}

// per-row: deg = 1 + sum(w) over CSR row; dinv = rsqrt(deg)
__global__ __launch_bounds__(256) void kdinvrow(const int* __restrict__ off, const float2* __restrict__ pack,
                                                float* __restrict__ dinv, int n) {
  int i = blockIdx.x * 256 + threadIdx.x;
  if (i >= n) return;
  int b0 = off[i], b1 = off[i + 1];
  float s = 1.f;
  for (int j = b0; j < b1; j++) s += pack[j].x;
  dinv[i] = rsqrtf(s);
}

// wave-per-row CSR gather with cooperative pack load + shuffle broadcast:
// agg[i] = di*( di*tab[i%Gn] + sum_j (w_j*dinv[s_j]) * tab[s_j%Gn] )
template <bool OBF>
__global__ __launch_bounds__(256) void kgather(const int* __restrict__ off, const float2* __restrict__ pack,
                                               const float* __restrict__ dinv, const float* __restrict__ tab,
                                               float* __restrict__ aggf, u16* __restrict__ aggb, int n) {
  int lane = threadIdx.x & 63;
  int wv = blockIdx.x * 4 + (threadIdx.x >> 6);
  int nw = gridDim.x * 4;
  for (int i = wv; i < n; i += nw) {
    int b0 = off[i], b1 = off[i + 1];
    float di = dinv[i];
    float acc = di * tab[(i % Gn) * 64 + lane];
    for (int base = b0; base < b1; base += 64) {
      int m = b1 - base; if (m > 64) m = 64;
      float cj = 0.f; int idxj = 0;
      if (lane < m) {
        float2 p = pack[base + lane];         // coalesced: one load per edge (not per lane)
        int s = __float_as_int(p.y);
        cj = p.x * dinv[s];                   // per-edge coefficient, computed once
        idxj = (s % Gn) * 64;                 // per-edge table offset, computed once
      }
      int j = 0;
      for (; j + 1 < m; j += 2) {
        float c0 = __shfl(cj, j, 64);     int i0 = __shfl(idxj, j, 64);
        float c1 = __shfl(cj, j + 1, 64); int i1 = __shfl(idxj, j + 1, 64);
        float t0 = tab[i0 + lane];
        float t1 = tab[i1 + lane];
        acc = fmaf(c0, t0, acc);
        acc = fmaf(c1, t1, acc);
      }
      if (j < m) {
        float c0 = __shfl(cj, j, 64); int i0 = __shfl(idxj, j, 64);
        acc = fmaf(c0, tab[i0 + lane], acc);
      }
    }
    acc *= di;
    if (OBF) aggb[(size_t)i * 64 + lane] = f2bf(acc);
    else aggf[(size_t)i * 64 + lane] = acc;
  }
}

// ===================== big-N tiled GEMM (128 rows x 64 cols, K=64), bf16 in/out =====================
template <bool PRE, bool EB, bool PERG>
__global__ __launch_bounds__(256, 3) void gemm_big(
    const u16* __restrict__ Xb, const float* __restrict__ Wg,
    const float* __restrict__ bias, const float* __restrict__ pa, const float* __restrict__ pb,
    const float* __restrict__ perg, u16* __restrict__ Ybf, int obpitch,
    float* __restrict__ stats, int sqoff) {
  __shared__ float xs[128 * 68];
  __shared__ float wt[64 * 68];
  __shared__ float sstat[128];
  int t = threadIdx.x, cg = t & 7, rg = t >> 3;
  for (int idx = t; idx < 4096; idx += 256) {
    int oc = idx >> 6, k = idx & 63;
    wt[k * 68 + oc] = Wg[idx];
  }
  float sS[8], sQ[8];
#pragma unroll
  for (int j = 0; j < 8; j++) { sS[j] = 0.f; sQ[j] = 0.f; }
  float bb[8];
  {
    float4 b0 = *(const float4*)&bias[cg * 8];
    float4 b1 = *(const float4*)&bias[cg * 8 + 4];
    bb[0] = b0.x; bb[1] = b0.y; bb[2] = b0.z; bb[3] = b0.w;
    bb[4] = b1.x; bb[5] = b1.y; bb[6] = b1.z; bb[7] = b1.w;
  }
  for (int tile = blockIdx.x; tile < NTILES; tile += gridDim.x) {
    int R0 = tile * 128;
    __syncthreads();
#pragma unroll
    for (int m = 0; m < 4; m++) {
      int f = m * 256 + t;
      int r = f >> 3, c8 = (f & 7) * 8;
      uint4 u = *(const uint4*)&Xb[(size_t)(R0 + r) * 64 + c8];
      float v[8] = {bflo(u.x), bfhi(u.x), bflo(u.y), bfhi(u.y),
                    bflo(u.z), bfhi(u.z), bflo(u.w), bfhi(u.w)};
      if (PRE) {
        float4 A0 = *(const float4*)&pa[c8];
        float4 A1 = *(const float4*)&pa[c8 + 4];
        const float* pbb = EB ? &pb[((R0 + r) / Gn) * 64] : pb;
        float4 B0 = *(const float4*)&pbb[c8];
        float4 B1 = *(const float4*)&pbb[c8 + 4];
        v[0] = fmaxf(fmaf(A0.x, v[0], B0.x), 0.f);
        v[1] = fmaxf(fmaf(A0.y, v[1], B0.y), 0.f);
        v[2] = fmaxf(fmaf(A0.z, v[2], B0.z), 0.f);
        v[3] = fmaxf(fmaf(A0.w, v[3], B0.w), 0.f);
        v[4] = fmaxf(fmaf(A1.x, v[4], B1.x), 0.f);
        v[5] = fmaxf(fmaf(A1.y, v[5], B1.y), 0.f);
        v[6] = fmaxf(fmaf(A1.z, v[6], B1.z), 0.f);
        v[7] = fmaxf(fmaf(A1.w, v[7], B1.w), 0.f);
      }
      *(float4*)&xs[r * 68 + c8] = make_float4(v[0], v[1], v[2], v[3]);
      *(float4*)&xs[r * 68 + c8 + 4] = make_float4(v[4], v[5], v[6], v[7]);
    }
    __syncthreads();
    float acc[4][8];
#pragma unroll
    for (int i = 0; i < 4; i++)
#pragma unroll
      for (int j = 0; j < 8; j++) acc[i][j] = 0.f;
#pragma unroll
    for (int kc = 0; kc < 16; kc++) {
      float4 x0 = *(const float4*)&xs[(rg * 4 + 0) * 68 + kc * 4];
      float4 x1 = *(const float4*)&xs[(rg * 4 + 1) * 68 + kc * 4];
      float4 x2 = *(const float4*)&xs[(rg * 4 + 2) * 68 + kc * 4];
      float4 x3 = *(const float4*)&xs[(rg * 4 + 3) * 68 + kc * 4];
#pragma unroll
      for (int kk = 0; kk < 4; kk++) {
        const float* wr = &wt[(kc * 4 + kk) * 68 + cg * 8];
        float4 w0 = *(const float4*)wr;
        float4 w1 = *(const float4*)(wr + 4);
        float wv[8] = {w0.x, w0.y, w0.z, w0.w, w1.x, w1.y, w1.z, w1.w};
        float a0 = XC(x0, kk), a1 = XC(x1, kk), a2 = XC(x2, kk), a3 = XC(x3, kk);
#pragma unroll
        for (int j = 0; j < 8; j++) {
          acc[0][j] = fmaf(a0, wv[j], acc[0][j]);
          acc[1][j] = fmaf(a1, wv[j], acc[1][j]);
          acc[2][j] = fmaf(a2, wv[j], acc[2][j]);
          acc[3][j] = fmaf(a3, wv[j], acc[3][j]);
        }
      }
    }
#pragma unroll
    for (int i = 0; i < 4; i++) {
      int grow = R0 + rg * 4 + i;
      float v[8];
#pragma unroll
      for (int j = 0; j < 8; j++) v[j] = acc[i][j] + bb[j];
      if (PERG) {
        int qr = grow % Gn;
        float4 q0 = *(const float4*)&perg[(size_t)qr * 64 + cg * 8];
        float4 q1 = *(const float4*)&perg[(size_t)qr * 64 + cg * 8 + 4];
        v[0] += q0.x; v[1] += q0.y; v[2] += q0.z; v[3] += q0.w;
        v[4] += q1.x; v[5] += q1.y; v[6] += q1.z; v[7] += q1.w;
      }
#pragma unroll
      for (int j = 0; j < 8; j++) { sS[j] += v[j]; sQ[j] += v[j] * v[j]; }
      uint4 o;
      o.x = (u32)f2bf(v[0]) | ((u32)f2bf(v[1]) << 16);
      o.y = (u32)f2bf(v[2]) | ((u32)f2bf(v[3]) << 16);
      o.z = (u32)f2bf(v[4]) | ((u32)f2bf(v[5]) << 16);
      o.w = (u32)f2bf(v[6]) | ((u32)f2bf(v[7]) << 16);
      *(uint4*)&Ybf[(size_t)grow * obpitch + cg * 8] = o;
    }
  }
  __syncthreads();
  for (int idx = t; idx < 128; idx += 256) sstat[idx] = 0.f;
  __syncthreads();
#pragma unroll
  for (int j = 0; j < 8; j++) {
    atomicAdd(&sstat[cg * 8 + j], sS[j]);
    atomicAdd(&sstat[64 + cg * 8 + j], sQ[j]);
  }
  __syncthreads();
  for (int idx = t; idx < 64; idx += 256) {
    atomicAdd(&stats[idx], sstat[idx]);
    atomicAdd(&stats[sqoff + idx], sstat[64 + idx]);
  }
}

// r1 merged: base2 = relu(Avec*t2 + e2[b]) staged once; both 64-col halves of
// r1 = base2@W1^T + b1 computed per tile (wt restaged per half — W1 is L2-hot,
// ~2.4 tiles/block). Output bf16 pitch 128; stats 128 cols (sums[0:128], sq[128:256]).
__global__ __launch_bounds__(256, 3) void gemm_r1(
    const u16* __restrict__ Xb, const float* __restrict__ W1, const float* __restrict__ b1,
    const float* __restrict__ pa, const float* __restrict__ pb,
    u16* __restrict__ Ybf, float* __restrict__ stats) {
  __shared__ float xs[128 * 68];
  __shared__ float wt[64 * 68];
  __shared__ float sstat[256];
  int t = threadIdx.x, cg = t & 7, rg = t >> 3;
  float sS[2][8], sQ[2][8];
#pragma unroll
  for (int h = 0; h < 2; h++)
#pragma unroll
    for (int j = 0; j < 8; j++) { sS[h][j] = 0.f; sQ[h][j] = 0.f; }
  float bb[2][8];
#pragma unroll
  for (int h = 0; h < 2; h++) {
    float4 b0 = *(const float4*)&b1[h * 64 + cg * 8];
    float4 b1v = *(const float4*)&b1[h * 64 + cg * 8 + 4];
    bb[h][0] = b0.x; bb[h][1] = b0.y; bb[h][2] = b0.z; bb[h][3] = b0.w;
    bb[h][4] = b1v.x; bb[h][5] = b1v.y; bb[h][6] = b1v.z; bb[h][7] = b1v.w;
  }
  for (int tile = blockIdx.x; tile < NTILES; tile += gridDim.x) {
    int R0 = tile * 128;
    __syncthreads();
    // stage xs (relu(Avec*x + e2[b]))
#pragma unroll
    for (int m = 0; m < 4; m++) {
      int f = m * 256 + t;
      int r = f >> 3, c8 = (f & 7) * 8;
      uint4 u = *(const uint4*)&Xb[(size_t)(R0 + r) * 64 + c8];
      float v[8] = {bflo(u.x), bfhi(u.x), bflo(u.y), bfhi(u.y),
                    bflo(u.z), bfhi(u.z), bflo(u.w), bfhi(u.w)};
      float4 A0 = *(const float4*)&pa[c8];
      float4 A1 = *(const float4*)&pa[c8 + 4];
      const float* pbb = &pb[((R0 + r) / Gn) * 64];
      float4 B0 = *(const float4*)&pbb[c8];
      float4 B1 = *(const float4*)&pbb[c8 + 4];
      v[0] = fmaxf(fmaf(A0.x, v[0], B0.x), 0.f);
      v[1] = fmaxf(fmaf(A0.y, v[1], B0.y), 0.f);
      v[2] = fmaxf(fmaf(A0.z, v[2], B0.z), 0.f);
      v[3] = fmaxf(fmaf(A0.w, v[3], B0.w), 0.f);
      v[4] = fmaxf(fmaf(A1.x, v[4], B1.x), 0.f);
      v[5] = fmaxf(fmaf(A1.y, v[5], B1.y), 0.f);
      v[6] = fmaxf(fmaf(A1.z, v[6], B1.z), 0.f);
      v[7] = fmaxf(fmaf(A1.w, v[7], B1.w), 0.f);
      *(float4*)&xs[r * 68 + c8] = make_float4(v[0], v[1], v[2], v[3]);
      *(float4*)&xs[r * 68 + c8 + 4] = make_float4(v[4], v[5], v[6], v[7]);
    }
    for (int hh = 0; hh < 2; hh++) {
      // stage wt for this half (wt[k][oc] = W1[(hh*64+oc)*64+k])
      for (int idx = t; idx < 4096; idx += 256) {
        int oc = idx >> 6, k = idx & 63;
        wt[k * 68 + oc] = W1[(hh * 64 + oc) * 64 + k];
      }
      __syncthreads();
      float acc[4][8];
#pragma unroll
      for (int i = 0; i < 4; i++)
#pragma unroll
        for (int j = 0; j < 8; j++) acc[i][j] = 0.f;
#pragma unroll
      for (int kc = 0; kc < 16; kc++) {
        float4 x0 = *(const float4*)&xs[(rg * 4 + 0) * 68 + kc * 4];
        float4 x1 = *(const float4*)&xs[(rg * 4 + 1) * 68 + kc * 4];
        float4 x2 = *(const float4*)&xs[(rg * 4 + 2) * 68 + kc * 4];
        float4 x3 = *(const float4*)&xs[(rg * 4 + 3) * 68 + kc * 4];
#pragma unroll
        for (int kk = 0; kk < 4; kk++) {
          const float* wr = &wt[(kc * 4 + kk) * 68 + cg * 8];
          float4 w0 = *(const float4*)wr;
          float4 w1 = *(const float4*)(wr + 4);
          float wv[8] = {w0.x, w0.y, w0.z, w0.w, w1.x, w1.y, w1.z, w1.w};
          float a0 = XC(x0, kk), a1 = XC(x1, kk), a2 = XC(x2, kk), a3 = XC(x3, kk);
#pragma unroll
          for (int j = 0; j < 8; j++) {
            acc[0][j] = fmaf(a0, wv[j], acc[0][j]);
            acc[1][j] = fmaf(a1, wv[j], acc[1][j]);
            acc[2][j] = fmaf(a2, wv[j], acc[2][j]);
            acc[3][j] = fmaf(a3, wv[j], acc[3][j]);
          }
        }
      }
#pragma unroll
      for (int i = 0; i < 4; i++) {
        int grow = R0 + rg * 4 + i;
        float v[8];
#pragma unroll
        for (int j = 0; j < 8; j++) {
          v[j] = acc[i][j] + bb[hh][j];
          sS[hh][j] += v[j]; sQ[hh][j] += v[j] * v[j];
        }
        uint4 o;
        o.x = (u32)f2bf(v[0]) | ((u32)f2bf(v[1]) << 16);
        o.y = (u32)f2bf(v[2]) | ((u32)f2bf(v[3]) << 16);
        o.z = (u32)f2bf(v[4]) | ((u32)f2bf(v[5]) << 16);
        o.w = (u32)f2bf(v[6]) | ((u32)f2bf(v[7]) << 16);
        *(uint4*)&Ybf[(size_t)grow * 128 + hh * 64 + cg * 8] = o;
      }
      __syncthreads();  // done reading wt before next half/tile restages
    }
  }
  for (int idx = t; idx < 256; idx += 256) sstat[idx] = 0.f;
  __syncthreads();
#pragma unroll
  for (int h = 0; h < 2; h++)
#pragma unroll
    for (int j = 0; j < 8; j++) {
      atomicAdd(&sstat[h * 64 + cg * 8 + j], sS[h][j]);
      atomicAdd(&sstat[128 + h * 64 + cg * 8 + j], sQ[h][j]);
    }
  __syncthreads();
  for (int idx = t; idx < 256, idx < 256; idx += 256) atomicAdd(&stats[idx], sstat[idx]);
}

// k11: r2 = relu(a4*r1+b4) @ W2^T + b2 ; K=128 (two staged halves), r1 bf16 pitch 128, out bf16 pitch 64
__global__ __launch_bounds__(256, 3) void gemm_k11(
    const u16* __restrict__ Xbf, const float* __restrict__ W2,
    const float* __restrict__ bias, const float* __restrict__ a4, const float* __restrict__ b4,
    u16* __restrict__ Ybf, float* __restrict__ stats) {
  __shared__ float xs[128 * 68];
  __shared__ float wt[64 * 68];
  __shared__ float sstat[128];
  int t = threadIdx.x, cg = t & 7, rg = t >> 3;
  float sS[8], sQ[8];
#pragma unroll
  for (int j = 0; j < 8; j++) { sS[j] = 0.f; sQ[j] = 0.f; }
  float bb[8];
  {
    float4 b0 = *(const float4*)&bias[cg * 8];
    float4 b1 = *(const float4*)&bias[cg * 8 + 4];
    bb[0] = b0.x; bb[1] = b0.y; bb[2] = b0.z; bb[3] = b0.w;
    bb[4] = b1.x; bb[5] = b1.y; bb[6] = b1.z; bb[7] = b1.w;
  }
  for (int tile = blockIdx.x; tile < NTILES; tile += gridDim.x) {
    int R0 = tile * 128;
    float acc[4][8];
#pragma unroll
    for (int i = 0; i < 4; i++)
#pragma unroll
      for (int j = 0; j < 8; j++) acc[i][j] = 0.f;
    for (int hh = 0; hh < 2; hh++) {
      __syncthreads();
      for (int idx = t; idx < 4096; idx += 256) {
        int oc = idx >> 6, kl = idx & 63;
        wt[kl * 68 + oc] = W2[oc * 128 + hh * 64 + kl];
      }
#pragma unroll
      for (int m = 0; m < 4; m++) {
        int f = m * 256 + t;
        int r = f >> 3, ch = f & 7;
        const uint4* p = (const uint4*)&Xbf[(size_t)(R0 + r) * 128 + hh * 64 + ch * 8];
        uint4 u = *p;
        int kb = hh * 64 + ch * 8;
        float4 A0 = *(const float4*)&a4[kb];
        float4 A1 = *(const float4*)&a4[kb + 4];
        float4 B0 = *(const float4*)&b4[kb];
        float4 B1 = *(const float4*)&b4[kb + 4];
        float4 v0, v1;
        v0.x = fmaxf(fmaf(A0.x, bflo(u.x), B0.x), 0.f);
        v0.y = fmaxf(fmaf(A0.y, bfhi(u.x), B0.y), 0.f);
        v0.z = fmaxf(fmaf(A0.z, bflo(u.y), B0.z), 0.f);
        v0.w = fmaxf(fmaf(A0.w, bfhi(u.y), B0.w), 0.f);
        v1.x = fmaxf(fmaf(A1.x, bflo(u.z), B1.x), 0.f);
        v1.y = fmaxf(fmaf(A1.y, bfhi(u.z), B1.y), 0.f);
        v1.z = fmaxf(fmaf(A1.z, bflo(u.w), B1.z), 0.f);
        v1.w = fmaxf(fmaf(A1.w, bfhi(u.w), B1.w), 0.f);
        *(float4*)&xs[r * 68 + ch * 8] = v0;
        *(float4*)&xs[r * 68 + ch * 8 + 4] = v1;
      }
      __syncthreads();
#pragma unroll
      for (int kc = 0; kc < 16; kc++) {
        float4 x0 = *(const float4*)&xs[(rg * 4 + 0) * 68 + kc * 4];
        float4 x1 = *(const float4*)&xs[(rg * 4 + 1) * 68 + kc * 4];
        float4 x2 = *(const float4*)&xs[(rg * 4 + 2) * 68 + kc * 4];
        float4 x3 = *(const float4*)&xs[(rg * 4 + 3) * 68 + kc * 4];
#pragma unroll
        for (int kk = 0; kk < 4; kk++) {
          const float* wr = &wt[(kc * 4 + kk) * 68 + cg * 8];
          float4 w0 = *(const float4*)wr;
          float4 w1 = *(const float4*)(wr + 4);
          float wv[8] = {w0.x, w0.y, w0.z, w0.w, w1.x, w1.y, w1.z, w1.w};
          float a0 = XC(x0, kk), a1 = XC(x1, kk), a2 = XC(x2, kk), a3 = XC(x3, kk);
#pragma unroll
          for (int j = 0; j < 8; j++) {
            acc[0][j] = fmaf(a0, wv[j], acc[0][j]);
            acc[1][j] = fmaf(a1, wv[j], acc[1][j]);
            acc[2][j] = fmaf(a2, wv[j], acc[2][j]);
            acc[3][j] = fmaf(a3, wv[j], acc[3][j]);
          }
        }
      }
    }
#pragma unroll
    for (int i = 0; i < 4; i++) {
      int grow = R0 + rg * 4 + i;
      float v[8];
#pragma unroll
      for (int j = 0; j < 8; j++) {
        v[j] = acc[i][j] + bb[j];
        sS[j] += v[j]; sQ[j] += v[j] * v[j];
      }
      uint4 o;
      o.x = (u32)f2bf(v[0]) | ((u32)f2bf(v[1]) << 16);
      o.y = (u32)f2bf(v[2]) | ((u32)f2bf(v[3]) << 16);
      o.z = (u32)f2bf(v[4]) | ((u32)f2bf(v[5]) << 16);
      o.w = (u32)f2bf(v[6]) | ((u32)f2bf(v[7]) << 16);
      *(uint4*)&Ybf[(size_t)grow * 64 + cg * 8] = o;
    }
  }
  __syncthreads();
  for (int idx = t; idx < 128; idx += 256) sstat[idx] = 0.f;
  __syncthreads();
#pragma unroll
  for (int j = 0; j < 8; j++) {
    atomicAdd(&sstat[cg * 8 + j], sS[j]);
    atomicAdd(&sstat[64 + cg * 8 + j], sQ[j]);
  }
  __syncthreads();
  for (int idx = t; idx < 128; idx += 256) atomicAdd(&stats[idx], sstat[idx]);
}

// ===================== small GEMM (Pn/Gn paths, fp32) =====================
template <bool TWO, bool PRE, bool PRELU, bool PERG, bool STATS>
__global__ __launch_bounds__(256) void gemm64k(
    const float* __restrict__ X, const float* __restrict__ Xb,
    const float* __restrict__ Wm, const float* __restrict__ Wb,
    const float* __restrict__ bias,
    const float* __restrict__ pa, const float* __restrict__ pb,
    const float* __restrict__ perg, int tabrows,
    float* __restrict__ Y, float* __restrict__ stats, int rows) {
  __shared__ float xs[4096];
  __shared__ float red[4][64], red2[4][64];
  int t = threadIdx.x, lane = t & 63, wv = t >> 6;
  int ntiles = (rows + 63) >> 6;
  float psum = 0.f, psq = 0.f;
  float bv = bias ? bias[lane] : 0.f;
  for (int tile = blockIdx.x; tile < ntiles; tile += gridDim.x) {
    int base = tile * 64;
    float acc[16];
#pragma unroll
    for (int j = 0; j < 16; j++) acc[j] = bv;
    for (int pass = 0; pass < (TWO ? 2 : 1); pass++) {
      const float* Xp = pass ? Xb : X;
      const float* Wp = pass ? Wb : Wm;
      __syncthreads();
#pragma unroll
      for (int m = 0; m < 16; m++) {
        int fl = m * 256 + t;
        int r = fl >> 6, c = fl & 63;
        int gr = base + r;
        float v = (gr < rows) ? Xp[gr * 64 + c] : 0.f;
        if (PRE) { v = pa[c] * v + pb[c]; if (PRELU) v = fmaxf(v, 0.f); }
        xs[fl] = v;
      }
      __syncthreads();
      float Wreg[64];
#pragma unroll
      for (int k = 0; k < 64; k++) Wreg[k] = Wp[lane * 64 + k];
#pragma unroll
      for (int j = 0; j < 16; j++) {
        int r = wv * 16 + j;
        const float4* xr = (const float4*)&xs[r * 64];
        float a = acc[j];
#pragma unroll
        for (int kk = 0; kk < 16; kk++) {
          float4 xv = xr[kk];
          a = fmaf(xv.x, Wreg[4 * kk + 0], a);
          a = fmaf(xv.y, Wreg[4 * kk + 1], a);
          a = fmaf(xv.z, Wreg[4 * kk + 2], a);
          a = fmaf(xv.w, Wreg[4 * kk + 3], a);
        }
        acc[j] = a;
      }
    }
#pragma unroll
    for (int j = 0; j < 16; j++) {
      int gr = base + wv * 16 + j;
      if (gr < rows) {
        float v = acc[j];
        if (PERG) v += perg[(gr % tabrows) * 64 + lane];
        Y[gr * 64 + lane] = v;
        if (STATS) { psum += v; psq += v * v; }
      }
    }
  }
  if (STATS) {
    __syncthreads();
    red[wv][lane] = psum; red2[wv][lane] = psq;
    __syncthreads();
    if (wv == 0) {
      float s = red[0][lane] + red[1][lane] + red[2][lane] + red[3][lane];
      float q = red2[0][lane] + red2[1][lane] + red2[2][lane] + red2[3][lane];
      atomicAdd(&stats[lane], s);
      atomicAdd(&stats[64 + lane], q);
    }
  }
}

// stats of u = a2*T2(bf16) + b2 + emb[row/G]  (no store); 8 elems/thread/iter
__global__ __launch_bounds__(256) void k7_kernel(const u16* __restrict__ T2, const float* __restrict__ a2,
                                                 const float* __restrict__ b2, const float* __restrict__ emb,
                                                 float* __restrict__ stats) {
  __shared__ float sstat[128];
  int t = threadIdx.x, cg = t & 7;
  float sS[8], sQ[8];
#pragma unroll
  for (int j = 0; j < 8; j++) { sS[j] = 0.f; sQ[j] = 0.f; }
  int c8 = cg * 8;
  float4 A0 = *(const float4*)&a2[c8];
  float4 A1 = *(const float4*)&a2[c8 + 4];
  float4 B0 = *(const float4*)&b2[c8];
  float4 B1 = *(const float4*)&b2[c8 + 4];
  int total8 = Nn * 8;
  int stride = gridDim.x * 256;
  for (int g8 = blockIdx.x * 256 + t; g8 < total8; g8 += stride) {
    int i = g8 >> 3;
    int b = i / Gn;
    uint4 u = *(const uint4*)&T2[(size_t)i * 64 + c8];
    float4 E0 = *(const float4*)&emb[b * 64 + c8];
    float4 E1 = *(const float4*)&emb[b * 64 + c8 + 4];
    float v[8];
    v[0] = fmaf(A0.x, bflo(u.x), B0.x) + E0.x;
    v[1] = fmaf(A0.y, bfhi(u.x), B0.y) + E0.y;
    v[2] = fmaf(A0.z, bflo(u.y), B0.z) + E0.z;
    v[3] = fmaf(A0.w, bfhi(u.y), B0.w) + E0.w;
    v[4] = fmaf(A1.x, bflo(u.z), B1.x) + E1.x;
    v[5] = fmaf(A1.y, bfhi(u.z), B1.y) + E1.y;
    v[6] = fmaf(A1.z, bflo(u.w), B1.z) + E1.z;
    v[7] = fmaf(A1.w, bfhi(u.w), B1.w) + E1.w;
#pragma unroll
    for (int j = 0; j < 8; j++) { sS[j] += v[j]; sQ[j] += v[j] * v[j]; }
  }
  for (int idx = t; idx < 128; idx += 256) sstat[idx] = 0.f;
  __syncthreads();
#pragma unroll
  for (int j = 0; j < 8; j++) {
    atomicAdd(&sstat[c8 + j], sS[j]);
    atomicAdd(&sstat[64 + c8 + j], sQ[j]);
  }
  __syncthreads();
  for (int idx = t; idx < 64; idx += 256) {
    atomicAdd(&stats[idx], sstat[idx]);
    atomicAdd(&stats[64 + idx], sstat[64 + idx]);
  }
}

// finalize S3 and build folded vectors: Avec = a3*a2, e2[b] = a3*(b2+emb[b]) + b3
__global__ __launch_bounds__(256) void kfinS3e2(const float* __restrict__ stats, const float* __restrict__ g,
                                                const float* __restrict__ bt, const float* __restrict__ a2,
                                                const float* __restrict__ b2, const float* __restrict__ emb,
                                                float* __restrict__ Avec, float* __restrict__ e2, float invn) {
  __shared__ float a3s[64], b3s[64];
  int t = threadIdx.x;
  if (t < 64) {
    float mean = stats[t] * invn;
    float var = stats[64 + t] * invn - mean * mean;
    float sc = g[t] * rsqrtf(var + 1e-5f);
    float sh = bt[t] - mean * sc;
    a3s[t] = sc; b3s[t] = sh;
    Avec[t] = sc * a2[t];
  }
  __syncthreads();
  for (int idx = t; idx < 2048; idx += 256) {
    int c = idx & 63;
    e2[idx] = a3s[c] * (b2[c] + emb[idx]) + b3s[c];
  }
}

// w1[i] = dot(a5*R2(bf16)+b5, indv_w1[i%G]) + indv_b1[i%G]
__global__ __launch_bounds__(256) void k13_kernel(const u16* __restrict__ R2, const float* __restrict__ a5,
                                                  const float* __restrict__ b5, const float* __restrict__ iw1,
                                                  const float* __restrict__ ib1, float* __restrict__ w1out,
                                                  int rows) {
  int t = blockIdx.x * 256 + threadIdx.x;
  int i = t >> 4, j = t & 15;
  if (i >= rows) return;
  int g = i % Gn;
  uint2 u = *(const uint2*)&R2[(size_t)i * 64 + j * 4];
  float rx = bflo(u.x), ry = bfhi(u.x), rz = bflo(u.y), rw = bfhi(u.y);
  float4 a = ((const float4*)a5)[j];
  float4 b = ((const float4*)b5)[j];
  float4 w = ((const float4*)iw1)[g * 16 + j];
  float p = (a.x * rx + b.x) * w.x + (a.y * ry + b.y) * w.y +
            (a.z * rz + b.z) * w.z + (a.w * rw + b.w) * w.w;
  for (int off = 8; off; off >>= 1) p += __shfl_xor(p, off, 64);
  if (j == 0) w1out[i] = p + ib1[g];
}

// init cgraw with bias
__global__ __launch_bounds__(256) void kinitcg(const float* __restrict__ cgb1, float* __restrict__ cgraw) {
  int idx = blockIdx.x * 256 + threadIdx.x;
  if (idx < Bn * 64) cgraw[idx] = cgb1[idx & 63];
}

// split-K GEMM: cgraw[b][col] += sum_{k in chunk} w1[b][k]*cgW1[col][k]
__global__ __launch_bounds__(256) void kcg1s(const float* __restrict__ w1, const float* __restrict__ cgW1,
                                             float* __restrict__ cgraw) {
  __shared__ float w1s[64 * 36];
  __shared__ float cgs[64 * 65];
  int t = threadIdx.x;
  int k0 = blockIdx.x * 64;
  int kmax = Gn - k0; if (kmax > 64) kmax = 64;
  for (int idx = t; idx < 2048; idx += 256) {
    int row = idx >> 6, k = idx & 63;
    w1s[k * 36 + row] = (k < kmax) ? w1[row * Gn + k0 + k] : 0.f;
  }
  for (int idx = t; idx < 4096; idx += 256) {
    int col = idx >> 6, k = idx & 63;
    cgs[k * 65 + col] = (k < kmax) ? cgW1[col * Gn + k0 + k] : 0.f;
  }
  __syncthreads();
  int col = t & 63, rg = t >> 6;
  float acc[8];
#pragma unroll
  for (int i = 0; i < 8; i++) acc[i] = 0.f;
  for (int k = 0; k < 64; k++) {
    float wk = cgs[k * 65 + col];
    const float* wr = &w1s[k * 36 + rg * 8];
    float4 r0 = *(const float4*)wr;
    float4 r1 = *(const float4*)(wr + 4);
    acc[0] = fmaf(r0.x, wk, acc[0]);
    acc[1] = fmaf(r0.y, wk, acc[1]);
    acc[2] = fmaf(r0.z, wk, acc[2]);
    acc[3] = fmaf(r0.w, wk, acc[3]);
    acc[4] = fmaf(r1.x, wk, acc[4]);
    acc[5] = fmaf(r1.y, wk, acc[5]);
    acc[6] = fmaf(r1.z, wk, acc[6]);
    acc[7] = fmaf(r1.w, wk, acc[7]);
  }
#pragma unroll
  for (int i = 0; i < 8; i++) atomicAdd(&cgraw[(rg * 8 + i) * 64 + col], acc[i]);
}

// single-block: cg2 = bn2(relu(bn1(cgraw)) @ W2^T + b2)   (BN over 32 rows)
__global__ __launch_bounds__(256) void kcg2(const float* __restrict__ cgraw, const float* __restrict__ g1,
                                            const float* __restrict__ bt1, const float* __restrict__ W2,
                                            const float* __restrict__ b2, const float* __restrict__ g2,
                                            const float* __restrict__ bt2, float* __restrict__ cg2out) {
  int t = threadIdx.x, c = t & 63, bg = t >> 6;
  __shared__ float hmid[2048], sred[4][64], qred[4][64], asc[64], bsh[64];
  float y[8];
  float ps = 0.f, pq = 0.f;
  for (int jb = 0; jb < 8; jb++) {
    int b = bg * 8 + jb;
    float v = cgraw[b * 64 + c];
    y[jb] = v; ps += v; pq += v * v;
  }
  sred[bg][c] = ps; qred[bg][c] = pq;
  __syncthreads();
  if (t < 64) {
    float s = sred[0][t] + sred[1][t] + sred[2][t] + sred[3][t];
    float q = qred[0][t] + qred[1][t] + qred[2][t] + qred[3][t];
    float mean = s * (1.f / 32.f), var = q * (1.f / 32.f) - mean * mean;
    float sc = g1[t] * rsqrtf(var + 1e-5f);
    asc[t] = sc; bsh[t] = bt1[t] - mean * sc;
  }
  __syncthreads();
  for (int jb = 0; jb < 8; jb++) { int b = bg * 8 + jb; hmid[b * 64 + c] = fmaxf(asc[c] * y[jb] + bsh[c], 0.f); }
  __syncthreads();
  ps = 0.f; pq = 0.f;
  for (int jb = 0; jb < 8; jb++) {
    int b = bg * 8 + jb;
    float a = b2[c];
    for (int k = 0; k < 64; k++) a += hmid[b * 64 + k] * W2[c * 64 + k];
    y[jb] = a; ps += a; pq += a * a;
  }
  sred[bg][c] = ps; qred[bg][c] = pq;
  __syncthreads();
  if (t < 64) {
    float s = sred[0][t] + sred[1][t] + sred[2][t] + sred[3][t];
    float q = qred[0][t] + qred[1][t] + qred[2][t] + qred[3][t];
    float mean = s * (1.f / 32.f), var = q * (1.f / 32.f) - mean * mean;
    float sc = g2[t] * rsqrtf(var + 1e-5f);
    asc[t] = sc; bsh[t] = bt2[t] - mean * sc;
  }
  __syncthreads();
  for (int jb = 0; jb < 8; jb++) { int b = bg * 8 + jb; cg2out[b * 64 + c] = asc[c] * y[jb] + bsh[c]; }
}

// single-block: emb = mlp3(pglob[pert_idx]) with BN over 32 rows
__global__ __launch_bounds__(256) void kemb(const float* __restrict__ m2, const float* __restrict__ aP2,
                                            const float* __restrict__ bP2, const int* __restrict__ pidx,
                                            const float* __restrict__ Wm, const float* __restrict__ bv,
                                            const float* __restrict__ gg, const float* __restrict__ btv,
                                            float* __restrict__ emb) {
  int t = threadIdx.x, c = t & 63, bg = t >> 6;
  __shared__ float xin[2048], hmid[2048], sred[4][64], qred[4][64], asc[64], bsh[64];
  for (int idx = t; idx < 2048; idx += 256) {
    int b = idx >> 6, cc = idx & 63;
    xin[idx] = aP2[cc] * m2[pidx[b] * 64 + cc] + bP2[cc];
  }
  __syncthreads();
  float y[8];
  float ps = 0.f, pq = 0.f;
  for (int jb = 0; jb < 8; jb++) {
    int b = bg * 8 + jb;
    float a = bv[c];
    for (int k = 0; k < 64; k++) a += xin[b * 64 + k] * Wm[c * 64 + k];
    y[jb] = a; ps += a; pq += a * a;
  }
  sred[bg][c] = ps; qred[bg][c] = pq;
  __syncthreads();
  if (t < 64) {
    float s = sred[0][t] + sred[1][t] + sred[2][t] + sred[3][t];
    float q = qred[0][t] + qred[1][t] + qred[2][t] + qred[3][t];
    float mean = s * (1.f / 32.f), var = q * (1.f / 32.f) - mean * mean;
    float sc = gg[t] * rsqrtf(var + 1e-5f);
    asc[t] = sc; bsh[t] = btv[t] - mean * sc;
  }
  __syncthreads();
  for (int jb = 0; jb < 8; jb++) { int b = bg * 8 + jb; hmid[b * 64 + c] = fmaxf(asc[c] * y[jb] + bsh[c], 0.f); }
  __syncthreads();
  ps = 0.f; pq = 0.f;
  for (int jb = 0; jb < 8; jb++) {
    int b = bg * 8 + jb;
    float a = bv[64 + c];
    for (int k = 0; k < 64; k++) a += hmid[b * 64 + k] * Wm[4096 + c * 64 + k];
    y[jb] = a; ps += a; pq += a * a;
  }
  sred[bg][c] = ps; qred[bg][c] = pq;
  __syncthreads();
  if (t < 64) {
    float s = sred[0][t] + sred[1][t] + sred[2][t] + sred[3][t];
    float q = qred[0][t] + qred[1][t] + qred[2][t] + qred[3][t];
    float mean = s * (1.f / 32.f), var = q * (1.f / 32.f) - mean * mean;
    float sc = gg[64 + t] * rsqrtf(var + 1e-5f);
    asc[t] = sc; bsh[t] = btv[64 + t] - mean * sc;
  }
  __syncthreads();
  for (int jb = 0; jb < 8; jb++) { int b = bg * 8 + jb; emb[b * 64 + c] = asc[c] * y[jb] + bsh[c]; }
}

// final: out[b][g] = w1*iw2[g][0] + dot(cg2[b], iw2[g][1:65]) + ib2[g] + x[b][g]
__global__ __launch_bounds__(256) void kfinal(const float* __restrict__ w1, const float* __restrict__ cg2,
                                              const float* __restrict__ iw2, const float* __restrict__ ib2,
                                              const float* __restrict__ x, float* __restrict__ out) {
  __shared__ float iws[64 * 65], cgs[2048];
  int t = threadIdx.x;
  int g0 = blockIdx.x * 64;
  for (int idx = t; idx < 64 * 65; idx += 256) {
    int gi = g0 * 65 + idx;
    iws[idx] = (gi < Gn * 65) ? iw2[gi] : 0.f;
  }
  for (int idx = t; idx < 2048; idx += 256) cgs[idx] = cg2[idx];
  __syncthreads();
  int gl = t & 63, bg = t >> 6;
  int g = g0 + gl;
  if (g >= Gn) return;
  float bias = ib2[g];
  for (int jb = 0; jb < 8; jb++) {
    int b = bg * 8 + jb;
    float acc = w1[b * Gn + g] * iws[gl * 65] + bias;
    for (int k = 0; k < 64; k++) acc += cgs[b * 64 + k] * iws[gl * 65 + 1 + k];
    out[b * Gn + g] = acc + x[b * Gn + g];
  }
}

extern "C" void kernel_launch(void* const* d_in, const int* in_sizes, int n_in,
                              void* d_out, int out_size, void* d_ws, size_t ws_size,
                              hipStream_t stream) {
  (void)in_sizes; (void)n_in; (void)out_size;
  if (ws_size < WS_FLOATS * sizeof(float)) return;

  const float* x        = (const float*)d_in[0];
  const int*   pert_idx = (const int*)d_in[1];
  const int*   ei_co    = (const int*)d_in[2];
  const float* w_co     = (const float*)d_in[3];
  const int*   ei_go    = (const int*)d_in[4];
  const float* w_go     = (const float*)d_in[5];
  const int*   ei_bg    = (const int*)d_in[6];
  const float* w_bg     = (const float*)d_in[7];
  const float* gene_tab = (const float*)d_in[8];
  const float* pos_tab  = (const float*)d_in[9];
  const float* go_tab   = (const float*)d_in[10];
  const float* bg_tab   = (const float*)d_in[11];
  const float* bn_g     = (const float*)d_in[12];
  const float* bn_b     = (const float*)d_in[13];
  const float* sg_W     = (const float*)d_in[14];
  const float* sg_b     = (const float*)d_in[15];
  const float* mlp_W    = (const float*)d_in[16];
  const float* mlp_b    = (const float*)d_in[17];
  const float* mlp_g    = (const float*)d_in[18];
  const float* mlp_bt   = (const float*)d_in[19];
  const float* rec_W1   = (const float*)d_in[20];
  const float* rec_b1   = (const float*)d_in[21];
  const float* rec_g1   = (const float*)d_in[22];
  const float* rec_bt1  = (const float*)d_in[23];
  const float* rec_W2   = (const float*)d_in[24];
  const float* rec_b2   = (const float*)d_in[25];
  const float* rec_g2   = (const float*)d_in[26];
  const float* rec_bt2  = (const float*)d_in[27];
  const float* indv_w1  = (const float*)d_in[28];
  const float* indv_b1  = (const float*)d_in[29];
  const float* cg_W1    = (const float*)d_in[30];
  const float* cg_b1    = (const float*)d_in[31];
  const float* cg_g1    = (const float*)d_in[32];
  const float* cg_bt1   = (const float*)d_in[33];
  const float* cg_W2    = (const float*)d_in[34];
  const float* cg_b2    = (const float*)d_in[35];
  const float* cg_g2    = (const float*)d_in[36];
  const float* cg_bt2   = (const float*)d_in[37];
  const float* indv_w2  = (const float*)d_in[38];
  const float* indv_b2  = (const float*)d_in[39];

  float* W = (float*)d_ws;
  float* buf0 = W + oBUF0;
  float* buf1 = W + oBUF1;

  // CSR scratch lives in buf1 (consumed before t1 writes buf1)
  int*    co_cnt    = (int*)(buf1);                  // 160001
  int*    sbsum     = (int*)(buf1 + 320128);         // <=256 block sums
  float2* co_pack   = (float2*)(buf1 + 400000);      // 1.6M float2
  int*    go_cnt    = (int*)(buf1 + 3700000);
  float2* go_pack   = (float2*)(buf1 + 3720000);
  int*    bg_cnt    = (int*)(buf1 + 4000000);
  float2* bg_pack   = (float2*)(buf1 + 4020000);
  int*    co_ticket = (int*)(buf1 + 4500000);        // 1.6M ints
  int*    go_ticket = (int*)(buf1 + 6200000);
  int*    bg_ticket = (int*)(buf1 + 6400000);

  // --- phase 0: zero stats, renorm tables, fold small matrices ---
  kzero<<<8, 256, 0, stream>>>(W, 2048);
  krenorm<<<160, 256, 0, stream>>>(gene_tab, W + oRG, W + oSG, Gn);
  krenorm<<<160, 256, 0, stream>>>(pos_tab, W + oRP, nullptr, Gn);
  krenorm<<<160, 256, 0, stream>>>(go_tab, W + oRGO, nullptr, Pn);
  krenorm<<<160, 256, 0, stream>>>(bg_tab, W + oRBG, nullptr, Pn);
  kfin<<<1, 64, 0, stream>>>(W + oSG, bn_g, bn_b, W + oAG, W + oBG, 64, 1.f / Gn);
  ksmallmat<<<1, 256, 0, stream>>>(mlp_W + 8192, sg_W, 0.2f, mlp_b + 128, sg_b, nullptr, 0.2f, W + oM, W + oCvec);
  ksmallmat<<<1, 256, 0, stream>>>(mlp_W, sg_W + 4096, 1.f, nullptr, nullptr, nullptr, 0.f, W + oM1, nullptr);
  ksmallmat<<<1, 256, 0, stream>>>(mlp_W, sg_W + 8192, 1.f, mlp_b, sg_b + 64, sg_b + 128, 1.f, W + oM2, W + oCcP);
  gemm64k<false, true, true, false, false><<<79, 256, 0, stream>>>(
      W + oRG, nullptr, mlp_W + 8192, nullptr, W + oCvec, W + oAG, W + oBG, nullptr, 0, W + oQ, nullptr, Gn);

  // --- co graph: ticket CSR build + gather (bf16 out) ---
  kzero<<<(160001 + 255) / 256, 256, 0, stream>>>((float*)co_cnt, 160001);
  khist<<<(ECO + 255) / 256, 256, 0, stream>>>(ei_co + ECO, co_cnt, co_ticket, ECO);
  kscan1<<<157, 256, 0, stream>>>(co_cnt, sbsum, Nn);
  kscan2<<<1, 256, 0, stream>>>(sbsum, 157, co_cnt + Nn);
  kscan3<<<157, 256, 0, stream>>>(co_cnt, sbsum, Nn);
  kfillt<<<(ECO + 255) / 256, 256, 0, stream>>>(ei_co, ei_co + ECO, w_co, co_cnt, co_ticket, co_pack, ECO);
  kdinvrow<<<(Nn + 255) / 256, 256, 0, stream>>>(co_cnt, co_pack, W + oDEG, Nn);
  kgather<true><<<2048, 256, 0, stream>>>(co_cnt, co_pack, W + oDEG, W + oRP, nullptr, (u16*)buf0, Nn);

  // --- go graph ---
  kzero<<<(5001 + 255) / 256, 256, 0, stream>>>((float*)go_cnt, 5001);
  khist<<<(EGG + 255) / 256, 256, 0, stream>>>(ei_go + EGG, go_cnt, go_ticket, EGG);
  kscan1<<<5, 256, 0, stream>>>(go_cnt, sbsum, Pn);
  kscan2<<<1, 256, 0, stream>>>(sbsum, 5, go_cnt + Pn);
  kscan3<<<5, 256, 0, stream>>>(go_cnt, sbsum, Pn);
  kfillt<<<(EGG + 255) / 256, 256, 0, stream>>>(ei_go, ei_go + EGG, w_go, go_cnt, go_ticket, go_pack, EGG);
  kdinvrow<<<(Pn + 255) / 256, 256, 0, stream>>>(go_cnt, go_pack, W + oDGO, Pn);
  kgather<false><<<512, 256, 0, stream>>>(go_cnt, go_pack, W + oDGO, W + oRGO, W + oAGO, nullptr, Pn);

  // --- bg graph ---
  kzero<<<(5001 + 255) / 256, 256, 0, stream>>>((float*)bg_cnt, 5001);
  khist<<<(EGG + 255) / 256, 256, 0, stream>>>(ei_bg + EGG, bg_cnt, bg_ticket, EGG);
  kscan1<<<5, 256, 0, stream>>>(bg_cnt, sbsum, Pn);
  kscan2<<<1, 256, 0, stream>>>(sbsum, 5, bg_cnt + Pn);
  kscan3<<<5, 256, 0, stream>>>(bg_cnt, sbsum, Pn);
  kfillt<<<(EGG + 255) / 256, 256, 0, stream>>>(ei_bg, ei_bg + EGG, w_bg, bg_cnt, bg_ticket, bg_pack, EGG);
  kdinvrow<<<(Pn + 255) / 256, 256, 0, stream>>>(bg_cnt, bg_pack, W + oDBG, Pn);
  kgather<false><<<512, 256, 0, stream>>>(bg_cnt, bg_pack, W + oDBG, W + oRBG, W + oABG, nullptr, Pn);

  // --- pert path (Pn rows, fp32) ---
  gemm64k<true, false, false, false, true><<<79, 256, 0, stream>>>(
      W + oAGO, W + oABG, W + oM1, W + oM2, W + oCcP, nullptr, nullptr, nullptr, 0, W + oM1B, W + oSP1, Pn);
  kfin<<<1, 64, 0, stream>>>(W + oSP1, mlp_g, mlp_bt, W + oAP1, W + oBP1, 64, 1.f / Pn);
  gemm64k<false, true, true, false, true><<<79, 256, 0, stream>>>(
      W + oM1B, nullptr, mlp_W + 4096, nullptr, mlp_b + 64, W + oAP1, W + oBP1, nullptr, 0, W + oM2B, W + oSP2, Pn);
  kfin<<<1, 64, 0, stream>>>(W + oSP2, mlp_g + 64, mlp_bt + 64, W + oAP2, W + oBP2, 64, 1.f / Pn);
  kemb<<<1, 256, 0, stream>>>(W + oM2B, W + oAP2, W + oBP2, pert_idx,
                              mlp_W + 16384, mlp_b + 256, mlp_g + 256, mlp_bt + 256, W + oEMB);

  // --- main N pipeline (bf16 intermediates) ---
  // t1 = agg@M^T + Q[g]; stats S1
  gemm_big<false, false, true><<<512, 256, 0, stream>>>(
      (const u16*)buf0, W + oM, W + oZERO, nullptr, nullptr, W + oQ, (u16*)buf1, 64, W + oS1, 64);
  kfin<<<1, 64, 0, stream>>>(W + oS1, mlp_g + 128, mlp_bt + 128, W + oA1, W + oB1, 64, 1.f / Nn);
  // t2 = relu(a1*t1+b1)@W11^T + b11; stats S2
  gemm_big<true, false, false><<<512, 256, 0, stream>>>(
      (const u16*)buf1, mlp_W + 12288, mlp_b + 192, W + oA1, W + oB1, nullptr, (u16*)buf0, 64, W + oS2, 64);
  kfin<<<1, 64, 0, stream>>>(W + oS2, mlp_g + 192, mlp_bt + 192, W + oA2, W + oB2, 64, 1.f / Nn);
  // stats of u = a2*t2+b2+emb[b]
  k7_kernel<<<512, 256, 0, stream>>>((const u16*)buf0, W + oA2, W + oB2, W + oEMB, W + oS3);
  kfinS3e2<<<1, 256, 0, stream>>>(W + oS3, bn_g + 64, bn_b + 64, W + oA2, W + oB2, W + oEMB,
                                  W + oAvec, W + oE2, 1.f / Nn);
  // r1 merged (both halves, t2 read once): r1 bf16 pitch 128; stats S4 (128)
  gemm_r1<<<512, 256, 0, stream>>>(
      (const u16*)buf0, rec_W1, rec_b1, W + oAvec, W + oE2, (u16*)buf1, W + oS4);
  kfin<<<2, 64, 0, stream>>>(W + oS4, rec_g1, rec_bt1, W + oA4, W + oB4, 128, 1.f / Nn);
  // r2 = relu(a4*r1+b4)@W2^T + b2; stats S5; bf16 out
  gemm_k11<<<512, 256, 0, stream>>>((const u16*)buf1, rec_W2, rec_b2, W + oA4, W + oB4, (u16*)buf0, W + oS5);
  kfin<<<1, 64, 0, stream>>>(W + oS5, rec_g2, rec_bt2, W + oA5, W + oB5, 64, 1.f / Nn);
  k13_kernel<<<(Nn * 16 + 255) / 256, 256, 0, stream>>>((const u16*)buf0, W + oA5, W + oB5, indv_w1, indv_b1,
                                                        W + oW1, Nn);
  // cross-gene state
  kinitcg<<<8, 256, 0, stream>>>(cg_b1, W + oCGRAW);
  kcg1s<<<(Gn + 63) / 64, 256, 0, stream>>>(W + oW1, cg_W1, W + oCGRAW);
  kcg2<<<1, 256, 0, stream>>>(W + oCGRAW, cg_g1, cg_bt1, cg_W2, cg_b2, cg_g2, cg_bt2, W + oCG2);
  kfinal<<<(Gn + 63) / 64, 256, 0, stream>>>(W + oW1, W + oCG2, indv_w2, indv_b2, x, (float*)d_out);
}